// Round 1
// baseline (3153.736 us; speedup 1.0000x reference)
//
#include <hip/hip_runtime.h>
#include <hip/hip_bf16.h>
#include <math.h>

#define H 128

typedef __bf16 bf16x8 __attribute__((ext_vector_type(8)));
typedef float f32x4 __attribute__((ext_vector_type(4)));
typedef __hip_bfloat16 bf16;

static __device__ __forceinline__ float bf2f(bf16 v){ return __bfloat162float(v); }
static __device__ __forceinline__ bf16 f2bf(float v){ return __float2bfloat16(v); }

// ---------------------------------------------------------------------------
// Weight prep: build transposed bf16 weight blocks [Ncol][128] + bias vectors.
// Protein table blocks (8): 0:pp f dst(+bf) 1:pp f src 2:pp s dst(+bs) 3:pp s src
//                           4:lp f dst(+bf) 5:lp s dst(+bs) 6:pl f src 7:pl s src
// Ligand table blocks (4):  0:lp f src 1:lp s src 2:pl f dst(+bf) 3:pl s dst(+bs)
// ---------------------------------------------------------------------------
__global__ void prep_wp(const float* __restrict__ Wf, const float* __restrict__ Ws,
                        const float* __restrict__ bfv, const float* __restrict__ bsv,
                        bf16* __restrict__ Wt, float* __restrict__ Bias){
  int idx = blockIdx.x*blockDim.x + threadIdx.x;   // l*1024 + b*128 + c
  if (idx >= 4*8*128) return;
  int c = idx & 127; int b = (idx>>7) & 7; int l = idx >> 10;
  const int rel_t[8]  = {0,0,0,0,1,1,2,2};
  const int off_t[8]  = {0,128,0,128,0,0,128,128};
  const int ws_t[8]   = {0,0,1,1,0,1,0,1};
  const int bias_t[8] = {1,0,2,0,1,2,0,0};
  int rel = rel_t[b];
  const float* W = ws_t[b] ? Ws : Wf;
  const float* base = W + ((size_t)(l*3+rel)*272 + off_t[b])*H + c;
  bf16* out = Wt + ((size_t)l*1024 + b*128 + c)*H;
  for (int k=0;k<128;k++) out[k] = f2bf(base[(size_t)k*H]);
  float bias = 0.f;
  if (bias_t[b]==1) bias = bfv[(l*3+rel)*H + c];
  else if (bias_t[b]==2) bias = bsv[(l*3+rel)*H + c];
  Bias[l*1024 + b*128 + c] = bias;
}

__global__ void prep_wl(const float* __restrict__ Wf, const float* __restrict__ Ws,
                        const float* __restrict__ bfv, const float* __restrict__ bsv,
                        bf16* __restrict__ Wt, float* __restrict__ Bias){
  int idx = blockIdx.x*blockDim.x + threadIdx.x;   // l*512 + b*128 + c
  if (idx >= 4*4*128) return;
  int c = idx & 127; int b = (idx>>7) & 3; int l = idx >> 9;
  const int rel_t[4]  = {1,1,2,2};
  const int off_t[4]  = {128,128,0,0};
  const int ws_t[4]   = {0,1,0,1};
  const int bias_t[4] = {0,0,1,2};
  int rel = rel_t[b];
  const float* W = ws_t[b] ? Ws : Wf;
  const float* base = W + ((size_t)(l*3+rel)*272 + off_t[b])*H + c;
  bf16* out = Wt + ((size_t)l*512 + b*128 + c)*H;
  for (int k=0;k<128;k++) out[k] = f2bf(base[(size_t)k*H]);
  float bias = 0.f;
  if (bias_t[b]==1) bias = bfv[(l*3+rel)*H + c];
  else if (bias_t[b]==2) bias = bsv[(l*3+rel)*H + c];
  Bias[l*512 + b*128 + c] = bias;
}

// ---------------------------------------------------------------------------
// CSR build
// ---------------------------------------------------------------------------
__global__ void hist_k(const int* __restrict__ dst, int E, int* __restrict__ counts){
  int e = blockIdx.x*blockDim.x + threadIdx.x;
  if (e < E) atomicAdd(&counts[dst[e]], 1);
}

#define SCAN_T 1024
__global__ void scan_k(const int* __restrict__ counts, int n,
                       int* __restrict__ row_ptr, int* __restrict__ cursor){
  __shared__ int tmp[SCAN_T];
  __shared__ int carry_s;
  int tid = threadIdx.x;
  if (tid == 0) carry_s = 0;
  __syncthreads();
  for (int base=0; base<n; base+=SCAN_T){
    int i = base + tid;
    int v = (i < n) ? counts[i] : 0;
    tmp[tid] = v;
    __syncthreads();
    for (int off=1; off<SCAN_T; off<<=1){
      int t = (tid >= off) ? tmp[tid-off] : 0;
      __syncthreads();
      tmp[tid] += t;
      __syncthreads();
    }
    int incl = tmp[tid];
    int carry = carry_s;
    if (i < n){ int ex = carry + incl - v; row_ptr[i] = ex; cursor[i] = ex; }
    __syncthreads();
    if (tid == SCAN_T-1) carry_s = carry + incl;
    __syncthreads();
  }
  if (tid == 0) row_ptr[n] = carry_s;
}

__global__ void fill_k(const int* __restrict__ src, const int* __restrict__ dst,
                       const float* __restrict__ ea, int E, int* __restrict__ cursor,
                       int* __restrict__ csr_src, float* __restrict__ csr_d){
  int e = blockIdx.x*blockDim.x + threadIdx.x;
  if (e < E){
    int p = atomicAdd(&cursor[dst[e]], 1);
    csr_src[p] = src[e];
    csr_d[p] = ea[e];
  }
}

// ---------------------------------------------------------------------------
// Node embedding: x @ W[6,128] + b  (fp32 out + bf16 copy)
// ---------------------------------------------------------------------------
__global__ void embed_k(const float* __restrict__ Xin, const float* __restrict__ W,
                        const float* __restrict__ b, float* __restrict__ Xout,
                        bf16* __restrict__ Xbf, int N){
  int idx = blockIdx.x*blockDim.x + threadIdx.x;
  if (idx >= N*H) return;
  int n = idx >> 7, c = idx & 127;
  float acc = b[c];
  #pragma unroll
  for (int k=0;k<6;k++) acc += Xin[n*6+k] * W[k*H+c];
  Xout[idx] = acc;
  Xbf[idx] = f2bf(acc);
}

// ---------------------------------------------------------------------------
// Table GEMM: Out[M,N] = bf16(X[M,128] @ Wt[N,128]^T + Bias) — MFMA 16x16x32
// wave per 16x16 tile; A/B frags both contiguous 16B loads (NT layout).
// ---------------------------------------------------------------------------
__global__ void gemm_tables(const bf16* __restrict__ X, const bf16* __restrict__ Wt,
                            const float* __restrict__ Bias, bf16* __restrict__ Out,
                            int M, int N){
  int wid = (int)((blockIdx.x*(size_t)blockDim.x + threadIdx.x) >> 6);
  int n_tiles = N >> 4;
  int total = (M >> 4) * n_tiles;
  if (wid >= total) return;
  int m0 = (wid / n_tiles) << 4;
  int n0 = (wid % n_tiles) << 4;
  int lane = threadIdx.x & 63;
  int lr = lane & 15, lq = lane >> 4;
  const bf16x8* A = (const bf16x8*)(const void*)(X + (size_t)(m0+lr)*H);
  const bf16x8* B = (const bf16x8*)(const void*)(Wt + (size_t)(n0+lr)*H);
  f32x4 acc = {0.f,0.f,0.f,0.f};
  #pragma unroll
  for (int t=0;t<4;t++)
    acc = __builtin_amdgcn_mfma_f32_16x16x32_bf16(A[t*4+lq], B[t*4+lq], acc, 0, 0, 0);
  int col = n0 + lr;
  float bias = Bias[col];
  #pragma unroll
  for (int r=0;r<4;r++){
    int row = m0 + lq*4 + r;
    Out[(size_t)row*N + col] = f2bf(acc[r] + bias);
  }
}

// ---------------------------------------------------------------------------
// Helpers for node update
// ---------------------------------------------------------------------------
static __device__ __forceinline__ void ln_stats(float v, float* sm, int tid,
                                                float& mu, float& var){
  float s = v, q = v*v;
  #pragma unroll
  for (int o=32;o>=1;o>>=1){ s += __shfl_xor(s,o,64); q += __shfl_xor(q,o,64); }
  __syncthreads();
  if ((tid & 63) == 0){ sm[(tid>>6)*2] = s; sm[(tid>>6)*2+1] = q; }
  __syncthreads();
  float S = sm[0] + sm[2], Q = sm[1] + sm[3];
  mu = S * (1.f/128.f);
  var = Q * (1.f/128.f) - mu*mu;
}

static __device__ __forceinline__ float act_msg(float f, float s){
  float sig = 1.f / (1.f + __expf(-f));
  float sp  = fmaxf(s, 0.f) + log1pf(__expf(-fabsf(s)));
  return sig * sp;
}

#define BN_RSQ 0.9999950000374997f   /* 1/sqrt(1+1e-5) */

// ---------------------------------------------------------------------------
// Protein node update: aggregate pp + lp relations, dual epilogue, sum.
// ---------------------------------------------------------------------------
__global__ void __launch_bounds__(128) node_update_p(
    const bf16* __restrict__ P, const bf16* __restrict__ Lg,
    const float* __restrict__ xp,
    const int* __restrict__ pp_rp, const int* __restrict__ pp_src, const float* __restrict__ pp_d,
    const int* __restrict__ lp_rp, const int* __restrict__ lp_src, const float* __restrict__ lp_d,
    const float* __restrict__ Wf, const float* __restrict__ Ws,
    const float* __restrict__ bn_w, const float* __restrict__ bn_b,
    const float* __restrict__ ln_w, const float* __restrict__ ln_b,
    float* __restrict__ xp_out, bf16* __restrict__ xp_bf, int layer)
{
  __shared__ float sm[4];
  int node = blockIdx.x;
  int c = threadIdx.x;
  int k16 = c & 15;
  float x = xp[(size_t)node*H + c];
  float o1, o2;
  // ---- relation pp (rel 0) ----
  {
    int pr = layer*3 + 0;
    const float* Wfe = Wf + ((size_t)pr*272 + 256)*H + c;
    const float* Wse = Ws + ((size_t)pr*272 + 256)*H + c;
    float wf[16], wsv[16];
    #pragma unroll
    for (int k=0;k<16;k++){ wf[k] = Wfe[k*H]; wsv[k] = Wse[k*H]; }
    float fd = bf2f(P[(size_t)node*1024 + 0*H + c]);
    float sd = bf2f(P[(size_t)node*1024 + 2*H + c]);
    float acc = 0.f;
    int e0 = pp_rp[node], e1 = pp_rp[node+1];
    for (int i=e0;i<e1;i++){
      int s = pp_src[i];
      float dd = pp_d[i];
      float t = dd - (8.0f/15.0f)*(float)k16;
      float rb = __expf(-1.7578125f * t * t);
      float rf = 0.f, rs = 0.f;
      #pragma unroll
      for (int k=0;k<16;k++){ float r = __shfl(rb, k, 64); rf += r*wf[k]; rs += r*wsv[k]; }
      float f  = fd + bf2f(P[(size_t)s*1024 + 1*H + c]) + rf;
      float sv = sd + bf2f(P[(size_t)s*1024 + 3*H + c]) + rs;
      acc += act_msg(f, sv);
    }
    float v = acc * (bn_w[pr*H+c] * BN_RSQ) + bn_b[pr*H+c] + x;
    float mu, var; ln_stats(v, sm, c, mu, var);
    float ln = (v-mu)*rsqrtf(var+1e-5f)*ln_w[pr*H+c] + ln_b[pr*H+c];
    o1 = fmaxf(ln, 0.f) + x;
  }
  // ---- relation lp (rel 1) ----
  {
    int pr = layer*3 + 1;
    const float* Wfe = Wf + ((size_t)pr*272 + 256)*H + c;
    const float* Wse = Ws + ((size_t)pr*272 + 256)*H + c;
    float wf[16], wsv[16];
    #pragma unroll
    for (int k=0;k<16;k++){ wf[k] = Wfe[k*H]; wsv[k] = Wse[k*H]; }
    float fd = bf2f(P[(size_t)node*1024 + 4*H + c]);
    float sd = bf2f(P[(size_t)node*1024 + 5*H + c]);
    float acc = 0.f;
    int e0 = lp_rp[node], e1 = lp_rp[node+1];
    for (int i=e0;i<e1;i++){
      int s = lp_src[i];
      float dd = lp_d[i];
      float t = dd - (8.0f/15.0f)*(float)k16;
      float rb = __expf(-1.7578125f * t * t);
      float rf = 0.f, rs = 0.f;
      #pragma unroll
      for (int k=0;k<16;k++){ float r = __shfl(rb, k, 64); rf += r*wf[k]; rs += r*wsv[k]; }
      float f  = fd + bf2f(Lg[(size_t)s*512 + 0*H + c]) + rf;
      float sv = sd + bf2f(Lg[(size_t)s*512 + 1*H + c]) + rs;
      acc += act_msg(f, sv);
    }
    float v = acc * (bn_w[pr*H+c] * BN_RSQ) + bn_b[pr*H+c] + x;
    float mu, var; ln_stats(v, sm, c, mu, var);
    float ln = (v-mu)*rsqrtf(var+1e-5f)*ln_w[pr*H+c] + ln_b[pr*H+c];
    o2 = fmaxf(ln, 0.f) + x;
  }
  float out = o1 + o2;
  xp_out[(size_t)node*H + c] = out;
  xp_bf[(size_t)node*H + c] = f2bf(out);
}

// ---------------------------------------------------------------------------
// Ligand node update: aggregate pl relation only.
// ---------------------------------------------------------------------------
__global__ void __launch_bounds__(128) node_update_l(
    const bf16* __restrict__ P, const bf16* __restrict__ Lg,
    const float* __restrict__ xl,
    const int* __restrict__ pl_rp, const int* __restrict__ pl_src, const float* __restrict__ pl_d,
    const float* __restrict__ Wf, const float* __restrict__ Ws,
    const float* __restrict__ bn_w, const float* __restrict__ bn_b,
    const float* __restrict__ ln_w, const float* __restrict__ ln_b,
    float* __restrict__ xl_out, bf16* __restrict__ xl_bf, int layer)
{
  __shared__ float sm[4];
  int node = blockIdx.x;
  int c = threadIdx.x;
  int k16 = c & 15;
  float x = xl[(size_t)node*H + c];
  int pr = layer*3 + 2;
  const float* Wfe = Wf + ((size_t)pr*272 + 256)*H + c;
  const float* Wse = Ws + ((size_t)pr*272 + 256)*H + c;
  float wf[16], wsv[16];
  #pragma unroll
  for (int k=0;k<16;k++){ wf[k] = Wfe[k*H]; wsv[k] = Wse[k*H]; }
  float fd = bf2f(Lg[(size_t)node*512 + 2*H + c]);
  float sd = bf2f(Lg[(size_t)node*512 + 3*H + c]);
  float acc = 0.f;
  int e0 = pl_rp[node], e1 = pl_rp[node+1];
  for (int i=e0;i<e1;i++){
    int s = pl_src[i];
    float dd = pl_d[i];
    float t = dd - (8.0f/15.0f)*(float)k16;
    float rb = __expf(-1.7578125f * t * t);
    float rf = 0.f, rs = 0.f;
    #pragma unroll
    for (int k=0;k<16;k++){ float r = __shfl(rb, k, 64); rf += r*wf[k]; rs += r*wsv[k]; }
    float f  = fd + bf2f(P[(size_t)s*1024 + 6*H + c]) + rf;
    float sv = sd + bf2f(P[(size_t)s*1024 + 7*H + c]) + rs;
    acc += act_msg(f, sv);
  }
  float v = acc * (bn_w[pr*H+c] * BN_RSQ) + bn_b[pr*H+c] + x;
  float mu, var; ln_stats(v, sm, c, mu, var);
  float ln = (v-mu)*rsqrtf(var+1e-5f)*ln_w[pr*H+c] + ln_b[pr*H+c];
  float out = fmaxf(ln, 0.f) + x;
  xl_out[(size_t)node*H + c] = out;
  xl_bf[(size_t)node*H + c] = f2bf(out);
}

// ---------------------------------------------------------------------------
// Final: LN(xp) @ fc_w[128,21] + fc_b
// ---------------------------------------------------------------------------
__global__ void __launch_bounds__(128) final_k(const float* __restrict__ xp,
    const float* __restrict__ lnw, const float* __restrict__ lnb,
    const float* __restrict__ fcw, const float* __restrict__ fcb,
    float* __restrict__ out, int N){
  __shared__ float sm[4];
  __shared__ float lnv[128];
  int node = blockIdx.x, c = threadIdx.x;
  float v = xp[(size_t)node*H + c];
  float mu, var; ln_stats(v, sm, c, mu, var);
  float ln = (v-mu)*rsqrtf(var+1e-5f)*lnw[c] + lnb[c];
  lnv[c] = ln;
  __syncthreads();
  if (c < 21){
    float a = fcb[c];
    #pragma unroll 4
    for (int i=0;i<128;i++) a += lnv[i]*fcw[i*21+c];
    out[(size_t)node*21 + c] = a;
  }
}

// ---------------------------------------------------------------------------
extern "C" void kernel_launch(void* const* d_in, const int* in_sizes, int n_in,
                              void* d_out, int out_size, void* d_ws, size_t ws_size,
                              hipStream_t stream){
  const float* x_protein = (const float*)d_in[0];
  const float* x_ligand  = (const float*)d_in[1];
  const int*   ei_pp = (const int*)d_in[2];
  const float* ea_pp = (const float*)d_in[3];
  const int*   ei_lp = (const int*)d_in[4];
  const float* ea_lp = (const float*)d_in[5];
  const int*   ei_pl = (const int*)d_in[6];
  const float* ea_pl = (const float*)d_in[7];
  const float* Wp  = (const float*)d_in[8];
  const float* bp  = (const float*)d_in[9];
  const float* Wl  = (const float*)d_in[10];
  const float* bl  = (const float*)d_in[11];
  const float* Wf  = (const float*)d_in[12];
  const float* bfv = (const float*)d_in[13];
  const float* Wsv = (const float*)d_in[14];
  const float* bsv = (const float*)d_in[15];
  const float* bn_w = (const float*)d_in[16];
  const float* bn_b = (const float*)d_in[17];
  const float* ln_w = (const float*)d_in[18];
  const float* ln_b = (const float*)d_in[19];
  const float* lno_w = (const float*)d_in[20];
  const float* lno_b = (const float*)d_in[21];
  const float* fc_w = (const float*)d_in[22];
  const float* fc_b = (const float*)d_in[23];

  int NP  = in_sizes[0]/6, NL = in_sizes[1]/6;
  int EPP = in_sizes[3], ELP = in_sizes[5], EPL = in_sizes[7];

  char* ws = (char*)d_ws;
  size_t off = 0;
  auto alloc = [&](size_t bytes)->void*{
    void* p = ws + off; off = (off + bytes + 255) & ~(size_t)255; return p;
  };

  float* xpA = (float*)alloc((size_t)NP*H*4);
  float* xpB = (float*)alloc((size_t)NP*H*4);
  float* xlA = (float*)alloc((size_t)NL*H*4);
  float* xlB = (float*)alloc((size_t)NL*H*4);
  bf16* xp_bf = (bf16*)alloc((size_t)NP*H*2);
  bf16* xl_bf = (bf16*)alloc((size_t)NL*H*2);
  bf16* Ptab  = (bf16*)alloc((size_t)NP*1024*2);
  bf16* Lgtab = (bf16*)alloc((size_t)NL*512*2);
  bf16* Wt_p  = (bf16*)alloc((size_t)4*1024*H*2);
  bf16* Wt_l  = (bf16*)alloc((size_t)4*512*H*2);
  float* Bias_p = (float*)alloc((size_t)4*1024*4);
  float* Bias_l = (float*)alloc((size_t)4*512*4);
  int* counts = (int*)alloc((size_t)(2*NP+NL)*4);   // pp | lp | pl contiguous
  int* rp_pp  = (int*)alloc((size_t)(NP+1)*4);
  int* cur_pp = (int*)alloc((size_t)NP*4);
  int* rp_lp  = (int*)alloc((size_t)(NP+1)*4);
  int* cur_lp = (int*)alloc((size_t)NP*4);
  int* rp_pl  = (int*)alloc((size_t)(NL+1)*4);
  int* cur_pl = (int*)alloc((size_t)NL*4);
  int*   csrc_pp = (int*)alloc((size_t)EPP*4);
  float* cd_pp   = (float*)alloc((size_t)EPP*4);
  int*   csrc_lp = (int*)alloc((size_t)ELP*4);
  float* cd_lp   = (float*)alloc((size_t)ELP*4);
  int*   csrc_pl = (int*)alloc((size_t)EPL*4);
  float* cd_pl   = (float*)alloc((size_t)EPL*4);
  (void)ws_size; (void)n_in; (void)out_size;

  // --- weight prep ---
  prep_wp<<<(4096+255)/256, 256, 0, stream>>>(Wf, Wsv, bfv, bsv, Wt_p, Bias_p);
  prep_wl<<<(2048+255)/256, 256, 0, stream>>>(Wf, Wsv, bfv, bsv, Wt_l, Bias_l);

  // --- CSR build ---
  hipMemsetAsync(counts, 0, (size_t)(2*NP+NL)*4, stream);
  int* cnt_pp = counts; int* cnt_lp = counts + NP; int* cnt_pl = counts + 2*NP;
  hist_k<<<(EPP+255)/256, 256, 0, stream>>>(ei_pp + EPP, EPP, cnt_pp);
  hist_k<<<(ELP+255)/256, 256, 0, stream>>>(ei_lp + ELP, ELP, cnt_lp);
  hist_k<<<(EPL+255)/256, 256, 0, stream>>>(ei_pl + EPL, EPL, cnt_pl);
  scan_k<<<1, SCAN_T, 0, stream>>>(cnt_pp, NP, rp_pp, cur_pp);
  scan_k<<<1, SCAN_T, 0, stream>>>(cnt_lp, NP, rp_lp, cur_lp);
  scan_k<<<1, SCAN_T, 0, stream>>>(cnt_pl, NL, rp_pl, cur_pl);
  fill_k<<<(EPP+255)/256, 256, 0, stream>>>(ei_pp, ei_pp + EPP, ea_pp, EPP, cur_pp, csrc_pp, cd_pp);
  fill_k<<<(ELP+255)/256, 256, 0, stream>>>(ei_lp, ei_lp + ELP, ea_lp, ELP, cur_lp, csrc_lp, cd_lp);
  fill_k<<<(EPL+255)/256, 256, 0, stream>>>(ei_pl, ei_pl + EPL, ea_pl, EPL, cur_pl, csrc_pl, cd_pl);

  // --- embeddings ---
  embed_k<<<((size_t)NP*H+255)/256, 256, 0, stream>>>(x_protein, Wp, bp, xpA, xp_bf, NP);
  embed_k<<<((size_t)NL*H+255)/256, 256, 0, stream>>>(x_ligand,  Wl, bl, xlA, xl_bf, NL);

  // --- layers ---
  float* xp_cur = xpA; float* xp_nxt = xpB;
  float* xl_cur = xlA; float* xl_nxt = xlB;
  for (int l=0; l<4; l++){
    size_t wavesP = ((size_t)(NP>>4)) * (1024>>4);
    size_t wavesL = ((size_t)(NL>>4)) * (512>>4);
    gemm_tables<<<(wavesP*64+255)/256, 256, 0, stream>>>(xp_bf, Wt_p + (size_t)l*1024*H,
                                                         Bias_p + l*1024, Ptab, NP, 1024);
    gemm_tables<<<(wavesL*64+255)/256, 256, 0, stream>>>(xl_bf, Wt_l + (size_t)l*512*H,
                                                         Bias_l + l*512, Lgtab, NL, 512);
    node_update_p<<<NP, 128, 0, stream>>>(Ptab, Lgtab, xp_cur,
        rp_pp, csrc_pp, cd_pp, rp_lp, csrc_lp, cd_lp,
        Wf, Wsv, bn_w, bn_b, ln_w, ln_b, xp_nxt, xp_bf, l);
    node_update_l<<<NL, 128, 0, stream>>>(Ptab, Lgtab, xl_cur,
        rp_pl, csrc_pl, cd_pl,
        Wf, Wsv, bn_w, bn_b, ln_w, ln_b, xl_nxt, xl_bf, l);
    float* t;
    t = xp_cur; xp_cur = xp_nxt; xp_nxt = t;
    t = xl_cur; xl_cur = xl_nxt; xl_nxt = t;
  }

  // --- output head ---
  final_k<<<NP, 128, 0, stream>>>(xp_cur, lno_w, lno_b, fc_w, fc_b, (float*)d_out, NP);
}

// Round 2
// 1944.662 us; speedup vs baseline: 1.6217x; 1.6217x over previous
//
#include <hip/hip_runtime.h>
#include <hip/hip_bf16.h>
#include <math.h>

#define H 128

typedef __bf16 bf16x8 __attribute__((ext_vector_type(8)));
typedef float f32x4 __attribute__((ext_vector_type(4)));
typedef __hip_bfloat16 bf16;
typedef unsigned int uint32;

static __device__ __forceinline__ float bf2f(bf16 v){ return __bfloat162float(v); }
static __device__ __forceinline__ bf16 f2bf(float v){ return __float2bfloat16(v); }
static __device__ __forceinline__ float u2f_lo(uint32 v){ return __uint_as_float(v << 16); }
static __device__ __forceinline__ float u2f_hi(uint32 v){ return __uint_as_float(v & 0xffff0000u); }

// ---------------------------------------------------------------------------
// Protein node-table layout PT[node][1024] (bf16):
//   [0,256)    pp-src interleaved pairs {f_c, s_c}   (gathered by pp edges)
//   [256,512)  pl-src interleaved pairs {f_c, s_c}   (gathered by pl edges)
//   [512,640)  pp f_dst (+bias bf)   [640,768)  pp s_dst (+bs)
//   [768,896)  lp f_dst (+bf)        [896,1024) lp s_dst (+bs)
// Ligand node-table LT[node][512]:
//   [0,256)    lp-src interleaved pairs {f_c, s_c}   (gathered by lp edges)
//   [256,384)  pl f_dst (+bf)        [384,512)  pl s_dst (+bs)
// ---------------------------------------------------------------------------
__global__ void prep_wp(const float* __restrict__ Wf, const float* __restrict__ Ws,
                        const float* __restrict__ bfv, const float* __restrict__ bsv,
                        bf16* __restrict__ Wt, float* __restrict__ Bias){
  int idx = blockIdx.x*blockDim.x + threadIdx.x;   // l*1024 + r
  if (idx >= 4*1024) return;
  int r = idx & 1023; int l = idx >> 10;
  int rel, c, row0; const float* W; float bias = 0.f;
  if (r < 256)      { rel=0; c=r>>1;        row0=128; W = (r&1)?Ws:Wf; }
  else if (r < 512) { rel=2; c=(r-256)>>1;  row0=128; W = (r&1)?Ws:Wf; }
  else if (r < 640) { rel=0; c=r-512; row0=0; W=Wf; bias = bfv[(l*3+rel)*H+c]; }
  else if (r < 768) { rel=0; c=r-640; row0=0; W=Ws; bias = bsv[(l*3+rel)*H+c]; }
  else if (r < 896) { rel=1; c=r-768; row0=0; W=Wf; bias = bfv[(l*3+rel)*H+c]; }
  else              { rel=1; c=r-896; row0=0; W=Ws; bias = bsv[(l*3+rel)*H+c]; }
  const float* base = W + ((size_t)(l*3+rel)*272 + row0)*H + c;
  bf16* out = Wt + (size_t)idx*H;
  for (int k=0;k<128;k++) out[k] = f2bf(base[(size_t)k*H]);
  Bias[idx] = bias;
}

__global__ void prep_wl(const float* __restrict__ Wf, const float* __restrict__ Ws,
                        const float* __restrict__ bfv, const float* __restrict__ bsv,
                        bf16* __restrict__ Wt, float* __restrict__ Bias){
  int idx = blockIdx.x*blockDim.x + threadIdx.x;   // l*512 + r
  if (idx >= 4*512) return;
  int r = idx & 511; int l = idx >> 9;
  int rel, c, row0; const float* W; float bias = 0.f;
  if (r < 256)      { rel=1; c=r>>1;   row0=128; W = (r&1)?Ws:Wf; }
  else if (r < 384) { rel=2; c=r-256; row0=0; W=Wf; bias = bfv[(l*3+rel)*H+c]; }
  else              { rel=2; c=r-384; row0=0; W=Ws; bias = bsv[(l*3+rel)*H+c]; }
  const float* base = W + ((size_t)(l*3+rel)*272 + row0)*H + c;
  bf16* out = Wt + (size_t)idx*H;
  for (int k=0;k<128;k++) out[k] = f2bf(base[(size_t)k*H]);
  Bias[idx] = bias;
}

// ---------------------------------------------------------------------------
// RBF lookup table: T2[pr][b][4c+{0..3}] = {f_b, s_b, f_{b+1}, s_{b+1}} (bf16)
// 12 rel-layers x 1025 bins x 1KB rows = 12.6 MB (L2-resident).
// rf(d,c) ~ lerp over bins of width 8/1024.
// ---------------------------------------------------------------------------
__global__ void build_rbf_tab(const float* __restrict__ Wf, const float* __restrict__ Ws,
                              bf16* __restrict__ T2){
  int idx = blockIdx.x*blockDim.x + threadIdx.x;   // pr*1025*128 + b*128 + c
  if (idx >= 12*1025*128) return;
  int c = idx & 127;
  int b = (idx >> 7) % 1025;
  int pr = idx / (1025*128);
  float d0 = (float)b * 0.0078125f;
  float d1 = d0 + 0.0078125f;
  const float* wf = Wf + ((size_t)pr*272 + 256)*H + c;
  const float* ws = Ws + ((size_t)pr*272 + 256)*H + c;
  float f0=0.f, s0=0.f, f1=0.f, s1=0.f;
  #pragma unroll
  for (int k=0;k<16;k++){
    float o = 0.533333333f*(float)k;
    float t0 = d0 - o, t1 = d1 - o;
    float r0 = __expf(-1.7578125f*t0*t0);
    float r1 = __expf(-1.7578125f*t1*t1);
    float wfk = wf[(size_t)k*H], wsk = ws[(size_t)k*H];
    f0 += r0*wfk; s0 += r0*wsk; f1 += r1*wfk; s1 += r1*wsk;
  }
  bf16* o = T2 + ((size_t)(pr*1025 + b))*512 + 4*c;
  o[0]=f2bf(f0); o[1]=f2bf(s0); o[2]=f2bf(f1); o[3]=f2bf(s1);
}

// ---------------------------------------------------------------------------
// CSR build
// ---------------------------------------------------------------------------
__global__ void hist_k(const int* __restrict__ dst, int E, int* __restrict__ counts){
  int e = blockIdx.x*blockDim.x + threadIdx.x;
  if (e < E) atomicAdd(&counts[dst[e]], 1);
}

#define SCAN_T 1024
__global__ void scan_k(const int* __restrict__ counts, int n,
                       int* __restrict__ row_ptr, int* __restrict__ cursor){
  __shared__ int tmp[SCAN_T];
  __shared__ int carry_s;
  int tid = threadIdx.x;
  if (tid == 0) carry_s = 0;
  __syncthreads();
  for (int base=0; base<n; base+=SCAN_T){
    int i = base + tid;
    int v = (i < n) ? counts[i] : 0;
    tmp[tid] = v;
    __syncthreads();
    for (int off=1; off<SCAN_T; off<<=1){
      int t = (tid >= off) ? tmp[tid-off] : 0;
      __syncthreads();
      tmp[tid] += t;
      __syncthreads();
    }
    int incl = tmp[tid];
    int carry = carry_s;
    if (i < n){ int ex = carry + incl - v; row_ptr[i] = ex; cursor[i] = ex; }
    __syncthreads();
    if (tid == SCAN_T-1) carry_s = carry + incl;
    __syncthreads();
  }
  if (tid == 0) row_ptr[n] = carry_s;
}

__global__ void fill_k(const int* __restrict__ src, const int* __restrict__ dst,
                       const float* __restrict__ ea, int E, int* __restrict__ cursor,
                       int* __restrict__ csr_src, float* __restrict__ csr_d){
  int e = blockIdx.x*blockDim.x + threadIdx.x;
  if (e < E){
    int p = atomicAdd(&cursor[dst[e]], 1);
    csr_src[p] = src[e];
    csr_d[p] = ea[e];
  }
}

// ---------------------------------------------------------------------------
// Node embedding: x @ W[6,128] + b  (fp32 out + bf16 copy)
// ---------------------------------------------------------------------------
__global__ void embed_k(const float* __restrict__ Xin, const float* __restrict__ W,
                        const float* __restrict__ b, float* __restrict__ Xout,
                        bf16* __restrict__ Xbf, int N){
  int idx = blockIdx.x*blockDim.x + threadIdx.x;
  if (idx >= N*H) return;
  int n = idx >> 7, c = idx & 127;
  float acc = b[c];
  #pragma unroll
  for (int k=0;k<6;k++) acc += Xin[n*6+k] * W[k*H+c];
  Xout[idx] = acc;
  Xbf[idx] = f2bf(acc);
}

// ---------------------------------------------------------------------------
// Table GEMM: Out[M,N] = bf16(X[M,128] @ Wt[N,128]^T + Bias) — MFMA 16x16x32
// ---------------------------------------------------------------------------
__global__ void gemm_tables(const bf16* __restrict__ X, const bf16* __restrict__ Wt,
                            const float* __restrict__ Bias, bf16* __restrict__ Out,
                            int M, int N){
  int wid = (int)((blockIdx.x*(size_t)blockDim.x + threadIdx.x) >> 6);
  int n_tiles = N >> 4;
  int total = (M >> 4) * n_tiles;
  if (wid >= total) return;
  int m0 = (wid / n_tiles) << 4;
  int n0 = (wid % n_tiles) << 4;
  int lane = threadIdx.x & 63;
  int lr = lane & 15, lq = lane >> 4;
  const bf16x8* A = (const bf16x8*)(const void*)(X + (size_t)(m0+lr)*H);
  const bf16x8* B = (const bf16x8*)(const void*)(Wt + (size_t)(n0+lr)*H);
  f32x4 acc = {0.f,0.f,0.f,0.f};
  #pragma unroll
  for (int t=0;t<4;t++)
    acc = __builtin_amdgcn_mfma_f32_16x16x32_bf16(A[t*4+lq], B[t*4+lq], acc, 0, 0, 0);
  int col = n0 + lr;
  float bias = Bias[col];
  #pragma unroll
  for (int r=0;r<4;r++){
    int row = m0 + lq*4 + r;
    Out[(size_t)row*N + col] = f2bf(acc[r] + bias);
  }
}

// ---------------------------------------------------------------------------
// Helpers for node update
// ---------------------------------------------------------------------------
static __device__ __forceinline__ void ln_stats(float v, float* sm, int tid,
                                                float& mu, float& var){
  float s = v, q = v*v;
  #pragma unroll
  for (int o=32;o>=1;o>>=1){ s += __shfl_xor(s,o,64); q += __shfl_xor(q,o,64); }
  __syncthreads();
  if ((tid & 63) == 0){ sm[(tid>>6)*2] = s; sm[(tid>>6)*2+1] = q; }
  __syncthreads();
  float S = sm[0] + sm[2], Q = sm[1] + sm[3];
  mu = S * (1.f/128.f);
  var = Q * (1.f/128.f) - mu*mu;
}

static __device__ __forceinline__ float act_msg(float f, float s){
  float sig = __builtin_amdgcn_rcpf(1.f + __expf(-f));
  float sp  = fmaxf(s, 0.f) + __logf(1.f + __expf(-fabsf(s)));
  return sig * sp;
}

#define BN_RSQ 0.9999950000374997f   /* 1/sqrt(1+1e-5) */

// ---------------------------------------------------------------------------
// Protein node update: aggregate pp + lp relations, dual epilogue, sum.
// ---------------------------------------------------------------------------
__global__ void __launch_bounds__(128) node_update_p(
    const bf16* __restrict__ PT, const bf16* __restrict__ LT,
    const float* __restrict__ xp,
    const int* __restrict__ pp_rp, const int* __restrict__ pp_src, const float* __restrict__ pp_d,
    const int* __restrict__ lp_rp, const int* __restrict__ lp_src, const float* __restrict__ lp_d,
    const bf16* __restrict__ T2,
    const float* __restrict__ bn_w, const float* __restrict__ bn_b,
    const float* __restrict__ ln_w, const float* __restrict__ ln_b,
    float* __restrict__ xp_out, bf16* __restrict__ xp_bf, int layer)
{
  __shared__ float sm[4];
  int node = blockIdx.x;
  int c = threadIdx.x;
  float x = xp[(size_t)node*H + c];
  const uint32* PTu = (const uint32*)(const void*)PT;
  const uint32* LTu = (const uint32*)(const void*)LT;
  float o1, o2;
  // ---- relation pp ----
  {
    int pr = layer*3 + 0;
    float fd = bf2f(PT[(size_t)node*1024 + 512 + c]);
    float sd = bf2f(PT[(size_t)node*1024 + 640 + c]);
    const uint2* Tb = (const uint2*)(const void*)(T2 + (size_t)pr*1025*512);
    float acc = 0.f;
    int e0 = pp_rp[node], e1 = pp_rp[node+1];
    for (int i=e0;i<e1;i++){
      int s = pp_src[i];
      float dd = pp_d[i];
      float bfl = dd * 128.0f;
      int b = (int)bfl; b = (b > 1023) ? 1023 : b;
      float fr = bfl - (float)b;
      uint32 g = PTu[(size_t)s*512 + c];
      uint2 t = Tb[(size_t)b*128 + c];
      float f0 = u2f_lo(t.x), s0 = u2f_hi(t.x);
      float f1 = u2f_lo(t.y), s1 = u2f_hi(t.y);
      float f  = fd + u2f_lo(g) + f0 + fr*(f1-f0);
      float sv = sd + u2f_hi(g) + s0 + fr*(s1-s0);
      acc += act_msg(f, sv);
    }
    float v = acc * (bn_w[pr*H+c] * BN_RSQ) + bn_b[pr*H+c] + x;
    float mu, var; ln_stats(v, sm, c, mu, var);
    float ln = (v-mu)*rsqrtf(var+1e-5f)*ln_w[pr*H+c] + ln_b[pr*H+c];
    o1 = fmaxf(ln, 0.f) + x;
  }
  // ---- relation lp ----
  {
    int pr = layer*3 + 1;
    float fd = bf2f(PT[(size_t)node*1024 + 768 + c]);
    float sd = bf2f(PT[(size_t)node*1024 + 896 + c]);
    const uint2* Tb = (const uint2*)(const void*)(T2 + (size_t)pr*1025*512);
    float acc = 0.f;
    int e0 = lp_rp[node], e1 = lp_rp[node+1];
    for (int i=e0;i<e1;i++){
      int s = lp_src[i];
      float dd = lp_d[i];
      float bfl = dd * 128.0f;
      int b = (int)bfl; b = (b > 1023) ? 1023 : b;
      float fr = bfl - (float)b;
      uint32 g = LTu[(size_t)s*256 + c];
      uint2 t = Tb[(size_t)b*128 + c];
      float f0 = u2f_lo(t.x), s0 = u2f_hi(t.x);
      float f1 = u2f_lo(t.y), s1 = u2f_hi(t.y);
      float f  = fd + u2f_lo(g) + f0 + fr*(f1-f0);
      float sv = sd + u2f_hi(g) + s0 + fr*(s1-s0);
      acc += act_msg(f, sv);
    }
    float v = acc * (bn_w[pr*H+c] * BN_RSQ) + bn_b[pr*H+c] + x;
    float mu, var; ln_stats(v, sm, c, mu, var);
    float ln = (v-mu)*rsqrtf(var+1e-5f)*ln_w[pr*H+c] + ln_b[pr*H+c];
    o2 = fmaxf(ln, 0.f) + x;
  }
  float out = o1 + o2;
  xp_out[(size_t)node*H + c] = out;
  xp_bf[(size_t)node*H + c] = f2bf(out);
}

// ---------------------------------------------------------------------------
// Ligand node update: aggregate pl relation only.
// ---------------------------------------------------------------------------
__global__ void __launch_bounds__(128) node_update_l(
    const bf16* __restrict__ PT, const bf16* __restrict__ LT,
    const float* __restrict__ xl,
    const int* __restrict__ pl_rp, const int* __restrict__ pl_src, const float* __restrict__ pl_d,
    const bf16* __restrict__ T2,
    const float* __restrict__ bn_w, const float* __restrict__ bn_b,
    const float* __restrict__ ln_w, const float* __restrict__ ln_b,
    float* __restrict__ xl_out, bf16* __restrict__ xl_bf, int layer)
{
  __shared__ float sm[4];
  int node = blockIdx.x;
  int c = threadIdx.x;
  float x = xl[(size_t)node*H + c];
  const uint32* PTu = (const uint32*)(const void*)PT;
  int pr = layer*3 + 2;
  float fd = bf2f(LT[(size_t)node*512 + 256 + c]);
  float sd = bf2f(LT[(size_t)node*512 + 384 + c]);
  const uint2* Tb = (const uint2*)(const void*)(T2 + (size_t)pr*1025*512);
  float acc = 0.f;
  int e0 = pl_rp[node], e1 = pl_rp[node+1];
  for (int i=e0;i<e1;i++){
    int s = pl_src[i];
    float dd = pl_d[i];
    float bfl = dd * 128.0f;
    int b = (int)bfl; b = (b > 1023) ? 1023 : b;
    float fr = bfl - (float)b;
    uint32 g = PTu[(size_t)s*512 + 128 + c];
    uint2 t = Tb[(size_t)b*128 + c];
    float f0 = u2f_lo(t.x), s0 = u2f_hi(t.x);
    float f1 = u2f_lo(t.y), s1 = u2f_hi(t.y);
    float f  = fd + u2f_lo(g) + f0 + fr*(f1-f0);
    float sv = sd + u2f_hi(g) + s0 + fr*(s1-s0);
    acc += act_msg(f, sv);
  }
  float v = acc * (bn_w[pr*H+c] * BN_RSQ) + bn_b[pr*H+c] + x;
  float mu, var; ln_stats(v, sm, c, mu, var);
  float ln = (v-mu)*rsqrtf(var+1e-5f)*ln_w[pr*H+c] + ln_b[pr*H+c];
  float out = fmaxf(ln, 0.f) + x;
  xl_out[(size_t)node*H + c] = out;
  xl_bf[(size_t)node*H + c] = f2bf(out);
}

// ---------------------------------------------------------------------------
// Final: LN(xp) @ fc_w[128,21] + fc_b
// ---------------------------------------------------------------------------
__global__ void __launch_bounds__(128) final_k(const float* __restrict__ xp,
    const float* __restrict__ lnw, const float* __restrict__ lnb,
    const float* __restrict__ fcw, const float* __restrict__ fcb,
    float* __restrict__ out, int N){
  __shared__ float sm[4];
  __shared__ float lnv[128];
  int node = blockIdx.x, c = threadIdx.x;
  float v = xp[(size_t)node*H + c];
  float mu, var; ln_stats(v, sm, c, mu, var);
  float ln = (v-mu)*rsqrtf(var+1e-5f)*lnw[c] + lnb[c];
  lnv[c] = ln;
  __syncthreads();
  if (c < 21){
    float a = fcb[c];
    #pragma unroll 4
    for (int i=0;i<128;i++) a += lnv[i]*fcw[i*21+c];
    out[(size_t)node*21 + c] = a;
  }
}

// ---------------------------------------------------------------------------
extern "C" void kernel_launch(void* const* d_in, const int* in_sizes, int n_in,
                              void* d_out, int out_size, void* d_ws, size_t ws_size,
                              hipStream_t stream){
  const float* x_protein = (const float*)d_in[0];
  const float* x_ligand  = (const float*)d_in[1];
  const int*   ei_pp = (const int*)d_in[2];
  const float* ea_pp = (const float*)d_in[3];
  const int*   ei_lp = (const int*)d_in[4];
  const float* ea_lp = (const float*)d_in[5];
  const int*   ei_pl = (const int*)d_in[6];
  const float* ea_pl = (const float*)d_in[7];
  const float* Wp  = (const float*)d_in[8];
  const float* bp  = (const float*)d_in[9];
  const float* Wl  = (const float*)d_in[10];
  const float* bl  = (const float*)d_in[11];
  const float* Wf  = (const float*)d_in[12];
  const float* bfv = (const float*)d_in[13];
  const float* Wsv = (const float*)d_in[14];
  const float* bsv = (const float*)d_in[15];
  const float* bn_w = (const float*)d_in[16];
  const float* bn_b = (const float*)d_in[17];
  const float* ln_w = (const float*)d_in[18];
  const float* ln_b = (const float*)d_in[19];
  const float* lno_w = (const float*)d_in[20];
  const float* lno_b = (const float*)d_in[21];
  const float* fc_w = (const float*)d_in[22];
  const float* fc_b = (const float*)d_in[23];

  int NP  = in_sizes[0]/6, NL = in_sizes[1]/6;
  int EPP = in_sizes[3], ELP = in_sizes[5], EPL = in_sizes[7];

  char* ws = (char*)d_ws;
  size_t off = 0;
  auto alloc = [&](size_t bytes)->void*{
    void* p = ws + off; off = (off + bytes + 255) & ~(size_t)255; return p;
  };

  float* xpA = (float*)alloc((size_t)NP*H*4);
  float* xpB = (float*)alloc((size_t)NP*H*4);
  float* xlA = (float*)alloc((size_t)NL*H*4);
  float* xlB = (float*)alloc((size_t)NL*H*4);
  bf16* xp_bf = (bf16*)alloc((size_t)NP*H*2);
  bf16* xl_bf = (bf16*)alloc((size_t)NL*H*2);
  bf16* PT    = (bf16*)alloc((size_t)NP*1024*2);
  bf16* LT    = (bf16*)alloc((size_t)NL*512*2);
  bf16* Wt_p  = (bf16*)alloc((size_t)4*1024*H*2);
  bf16* Wt_l  = (bf16*)alloc((size_t)4*512*H*2);
  float* Bias_p = (float*)alloc((size_t)4*1024*4);
  float* Bias_l = (float*)alloc((size_t)4*512*4);
  bf16* T2    = (bf16*)alloc((size_t)12*1025*512*2);
  int* counts = (int*)alloc((size_t)(2*NP+NL)*4);
  int* rp_pp  = (int*)alloc((size_t)(NP+1)*4);
  int* cur_pp = (int*)alloc((size_t)NP*4);
  int* rp_lp  = (int*)alloc((size_t)(NP+1)*4);
  int* cur_lp = (int*)alloc((size_t)NP*4);
  int* rp_pl  = (int*)alloc((size_t)(NL+1)*4);
  int* cur_pl = (int*)alloc((size_t)NL*4);
  int*   csrc_pp = (int*)alloc((size_t)EPP*4);
  float* cd_pp   = (float*)alloc((size_t)EPP*4);
  int*   csrc_lp = (int*)alloc((size_t)ELP*4);
  float* cd_lp   = (float*)alloc((size_t)ELP*4);
  int*   csrc_pl = (int*)alloc((size_t)EPL*4);
  float* cd_pl   = (float*)alloc((size_t)EPL*4);
  (void)ws_size; (void)n_in; (void)out_size;

  // --- weight prep + RBF table ---
  prep_wp<<<(4096+255)/256, 256, 0, stream>>>(Wf, Wsv, bfv, bsv, Wt_p, Bias_p);
  prep_wl<<<(2048+255)/256, 256, 0, stream>>>(Wf, Wsv, bfv, bsv, Wt_l, Bias_l);
  build_rbf_tab<<<(12*1025*128+255)/256, 256, 0, stream>>>(Wf, Wsv, T2);

  // --- CSR build ---
  hipMemsetAsync(counts, 0, (size_t)(2*NP+NL)*4, stream);
  int* cnt_pp = counts; int* cnt_lp = counts + NP; int* cnt_pl = counts + 2*NP;
  hist_k<<<(EPP+255)/256, 256, 0, stream>>>(ei_pp + EPP, EPP, cnt_pp);
  hist_k<<<(ELP+255)/256, 256, 0, stream>>>(ei_lp + ELP, ELP, cnt_lp);
  hist_k<<<(EPL+255)/256, 256, 0, stream>>>(ei_pl + EPL, EPL, cnt_pl);
  scan_k<<<1, SCAN_T, 0, stream>>>(cnt_pp, NP, rp_pp, cur_pp);
  scan_k<<<1, SCAN_T, 0, stream>>>(cnt_lp, NP, rp_lp, cur_lp);
  scan_k<<<1, SCAN_T, 0, stream>>>(cnt_pl, NL, rp_pl, cur_pl);
  fill_k<<<(EPP+255)/256, 256, 0, stream>>>(ei_pp, ei_pp + EPP, ea_pp, EPP, cur_pp, csrc_pp, cd_pp);
  fill_k<<<(ELP+255)/256, 256, 0, stream>>>(ei_lp, ei_lp + ELP, ea_lp, ELP, cur_lp, csrc_lp, cd_lp);
  fill_k<<<(EPL+255)/256, 256, 0, stream>>>(ei_pl, ei_pl + EPL, ea_pl, EPL, cur_pl, csrc_pl, cd_pl);

  // --- embeddings ---
  embed_k<<<((size_t)NP*H+255)/256, 256, 0, stream>>>(x_protein, Wp, bp, xpA, xp_bf, NP);
  embed_k<<<((size_t)NL*H+255)/256, 256, 0, stream>>>(x_ligand,  Wl, bl, xlA, xl_bf, NL);

  // --- layers ---
  float* xp_cur = xpA; float* xp_nxt = xpB;
  float* xl_cur = xlA; float* xl_nxt = xlB;
  for (int l=0; l<4; l++){
    size_t wavesP = ((size_t)(NP>>4)) * (1024>>4);
    size_t wavesL = ((size_t)(NL>>4)) * (512>>4);
    gemm_tables<<<(wavesP*64+255)/256, 256, 0, stream>>>(xp_bf, Wt_p + (size_t)l*1024*H,
                                                         Bias_p + l*1024, PT, NP, 1024);
    gemm_tables<<<(wavesL*64+255)/256, 256, 0, stream>>>(xl_bf, Wt_l + (size_t)l*512*H,
                                                         Bias_l + l*512, LT, NL, 512);
    node_update_p<<<NP, 128, 0, stream>>>(PT, LT, xp_cur,
        rp_pp, csrc_pp, cd_pp, rp_lp, csrc_lp, cd_lp, T2,
        bn_w, bn_b, ln_w, ln_b, xp_nxt, xp_bf, l);
    node_update_l<<<NL, 128, 0, stream>>>(PT, LT, xl_cur,
        rp_pl, csrc_pl, cd_pl, T2,
        bn_w, bn_b, ln_w, ln_b, xl_nxt, xl_bf, l);
    float* t;
    t = xp_cur; xp_cur = xp_nxt; xp_nxt = t;
    t = xl_cur; xl_cur = xl_nxt; xl_nxt = t;
  }

  // --- output head ---
  final_k<<<NP, 128, 0, stream>>>(xp_cur, lno_w, lno_b, fc_w, fc_b, (float*)d_out, NP);
}

// Round 3
// 1683.353 us; speedup vs baseline: 1.8735x; 1.1552x over previous
//
#include <hip/hip_runtime.h>
#include <hip/hip_bf16.h>
#include <math.h>

#define H 128

typedef __bf16 bf16x8 __attribute__((ext_vector_type(8)));
typedef float f32x4 __attribute__((ext_vector_type(4)));
typedef __hip_bfloat16 bf16;
typedef unsigned int uint32;

static __device__ __forceinline__ float bf2f(bf16 v){ return __bfloat162float(v); }
static __device__ __forceinline__ bf16 f2bf(float v){ return __float2bfloat16(v); }
static __device__ __forceinline__ float u2f_lo(uint32 v){ return __uint_as_float(v << 16); }
static __device__ __forceinline__ float u2f_hi(uint32 v){ return __uint_as_float(v & 0xffff0000u); }

// ---------------------------------------------------------------------------
// Protein node-table layout PT[node][1024] (bf16):
//   [0,256)    pp-src interleaved pairs {f_c, s_c}   (gathered by pp edges)
//   [256,512)  pl-src interleaved pairs {f_c, s_c}   (gathered by pl edges)
//   [512,640)  pp f_dst (+bias bf)   [640,768)  pp s_dst (+bs)
//   [768,896)  lp f_dst (+bf)        [896,1024) lp s_dst (+bs)
// Ligand node-table LT[node][512]:
//   [0,256)    lp-src interleaved pairs {f_c, s_c}   (gathered by lp edges)
//   [256,384)  pl f_dst (+bf)        [384,512)  pl s_dst (+bs)
// ---------------------------------------------------------------------------
__global__ void prep_wp(const float* __restrict__ Wf, const float* __restrict__ Ws,
                        const float* __restrict__ bfv, const float* __restrict__ bsv,
                        bf16* __restrict__ Wt, float* __restrict__ Bias){
  int idx = blockIdx.x*blockDim.x + threadIdx.x;   // l*1024 + r
  if (idx >= 4*1024) return;
  int r = idx & 1023; int l = idx >> 10;
  int rel, c, row0; const float* W; float bias = 0.f;
  if (r < 256)      { rel=0; c=r>>1;        row0=128; W = (r&1)?Ws:Wf; }
  else if (r < 512) { rel=2; c=(r-256)>>1;  row0=128; W = (r&1)?Ws:Wf; }
  else if (r < 640) { rel=0; c=r-512; row0=0; W=Wf; bias = bfv[(l*3+rel)*H+c]; }
  else if (r < 768) { rel=0; c=r-640; row0=0; W=Ws; bias = bsv[(l*3+rel)*H+c]; }
  else if (r < 896) { rel=1; c=r-768; row0=0; W=Wf; bias = bfv[(l*3+rel)*H+c]; }
  else              { rel=1; c=r-896; row0=0; W=Ws; bias = bsv[(l*3+rel)*H+c]; }
  const float* base = W + ((size_t)(l*3+rel)*272 + row0)*H + c;
  bf16* out = Wt + (size_t)idx*H;
  for (int k=0;k<128;k++) out[k] = f2bf(base[(size_t)k*H]);
  Bias[idx] = bias;
}

__global__ void prep_wl(const float* __restrict__ Wf, const float* __restrict__ Ws,
                        const float* __restrict__ bfv, const float* __restrict__ bsv,
                        bf16* __restrict__ Wt, float* __restrict__ Bias){
  int idx = blockIdx.x*blockDim.x + threadIdx.x;   // l*512 + r
  if (idx >= 4*512) return;
  int r = idx & 511; int l = idx >> 9;
  int rel, c, row0; const float* W; float bias = 0.f;
  if (r < 256)      { rel=1; c=r>>1;   row0=128; W = (r&1)?Ws:Wf; }
  else if (r < 384) { rel=2; c=r-256; row0=0; W=Wf; bias = bfv[(l*3+rel)*H+c]; }
  else              { rel=2; c=r-384; row0=0; W=Ws; bias = bsv[(l*3+rel)*H+c]; }
  const float* base = W + ((size_t)(l*3+rel)*272 + row0)*H + c;
  bf16* out = Wt + (size_t)idx*H;
  for (int k=0;k<128;k++) out[k] = f2bf(base[(size_t)k*H]);
  Bias[idx] = bias;
}

// ---------------------------------------------------------------------------
// RBF lookup table: T2[pr][b][4c+{0..3}] = {f_b, s_b, f_{b+1}, s_{b+1}} (bf16)
// ---------------------------------------------------------------------------
__global__ void build_rbf_tab(const float* __restrict__ Wf, const float* __restrict__ Ws,
                              bf16* __restrict__ T2){
  int idx = blockIdx.x*blockDim.x + threadIdx.x;   // pr*1025*128 + b*128 + c
  if (idx >= 12*1025*128) return;
  int c = idx & 127;
  int b = (idx >> 7) % 1025;
  int pr = idx / (1025*128);
  float d0 = (float)b * 0.0078125f;
  float d1 = d0 + 0.0078125f;
  const float* wf = Wf + ((size_t)pr*272 + 256)*H + c;
  const float* ws = Ws + ((size_t)pr*272 + 256)*H + c;
  float f0=0.f, s0=0.f, f1=0.f, s1=0.f;
  #pragma unroll
  for (int k=0;k<16;k++){
    float o = 0.533333333f*(float)k;
    float t0 = d0 - o, t1 = d1 - o;
    float r0 = __expf(-1.7578125f*t0*t0);
    float r1 = __expf(-1.7578125f*t1*t1);
    float wfk = wf[(size_t)k*H], wsk = ws[(size_t)k*H];
    f0 += r0*wfk; s0 += r0*wsk; f1 += r1*wfk; s1 += r1*wsk;
  }
  bf16* o = T2 + ((size_t)(pr*1025 + b))*512 + 4*c;
  o[0]=f2bf(f0); o[1]=f2bf(s0); o[2]=f2bf(f1); o[3]=f2bf(s1);
}

// ---------------------------------------------------------------------------
// CSR build
// ---------------------------------------------------------------------------
__global__ void hist_k(const int* __restrict__ dst, int E, int* __restrict__ counts){
  int e = blockIdx.x*blockDim.x + threadIdx.x;
  if (e < E) atomicAdd(&counts[dst[e]], 1);
}

#define SCAN_T 1024
__global__ void scan_k(const int* __restrict__ counts, int n,
                       int* __restrict__ row_ptr, int* __restrict__ cursor){
  __shared__ int tmp[SCAN_T];
  __shared__ int carry_s;
  int tid = threadIdx.x;
  if (tid == 0) carry_s = 0;
  __syncthreads();
  for (int base=0; base<n; base+=SCAN_T){
    int i = base + tid;
    int v = (i < n) ? counts[i] : 0;
    tmp[tid] = v;
    __syncthreads();
    for (int off=1; off<SCAN_T; off<<=1){
      int t = (tid >= off) ? tmp[tid-off] : 0;
      __syncthreads();
      tmp[tid] += t;
      __syncthreads();
    }
    int incl = tmp[tid];
    int carry = carry_s;
    if (i < n){ int ex = carry + incl - v; row_ptr[i] = ex; cursor[i] = ex; }
    __syncthreads();
    if (tid == SCAN_T-1) carry_s = carry + incl;
    __syncthreads();
  }
  if (tid == 0) row_ptr[n] = carry_s;
}

__global__ void fill_k(const int* __restrict__ src, const int* __restrict__ dst,
                       const float* __restrict__ ea, int E, int* __restrict__ cursor,
                       int* __restrict__ csr_src, float* __restrict__ csr_d){
  int e = blockIdx.x*blockDim.x + threadIdx.x;
  if (e < E){
    int p = atomicAdd(&cursor[dst[e]], 1);
    csr_src[p] = src[e];
    csr_d[p] = ea[e];
  }
}

// ---------------------------------------------------------------------------
// Node embedding: x @ W[6,128] + b  (fp32 out + bf16 copy)
// ---------------------------------------------------------------------------
__global__ void embed_k(const float* __restrict__ Xin, const float* __restrict__ W,
                        const float* __restrict__ b, float* __restrict__ Xout,
                        bf16* __restrict__ Xbf, int N){
  int idx = blockIdx.x*blockDim.x + threadIdx.x;
  if (idx >= N*H) return;
  int n = idx >> 7, c = idx & 127;
  float acc = b[c];
  #pragma unroll
  for (int k=0;k<6;k++) acc += Xin[n*6+k] * W[k*H+c];
  Xout[idx] = acc;
  Xbf[idx] = f2bf(acc);
}

// ---------------------------------------------------------------------------
// Table GEMM v2: Out[M,N] = bf16(X[M,128] @ Wt[N,128]^T + Bias)
// Block = 4 waves = one 16-row strip. Wave w covers cols [w*N/4,(w+1)*N/4).
// A-frags loaded once per wave (16x reuse); 16 independent n-tile iterations
// give ILP; weights are L2-resident.
// ---------------------------------------------------------------------------
__global__ void __launch_bounds__(256) gemm_tables(
    const bf16* __restrict__ X, const bf16* __restrict__ Wt,
    const float* __restrict__ Bias, bf16* __restrict__ Out,
    int M, int N){
  int strip = blockIdx.x;
  int m0 = strip << 4;
  int lane = threadIdx.x & 63;
  int wave = threadIdx.x >> 6;
  int lr = lane & 15, lq = lane >> 4;
  const bf16x8* A = (const bf16x8*)(const void*)(X + (size_t)(m0+lr)*H);
  bf16x8 a0 = A[0+lq], a1 = A[4+lq], a2 = A[8+lq], a3 = A[12+lq];
  int ncols = N >> 2;
  int n_end = (wave+1) * ncols;
  #pragma unroll 4
  for (int n0 = wave*ncols; n0 < n_end; n0 += 16){
    const bf16x8* B = (const bf16x8*)(const void*)(Wt + (size_t)(n0+lr)*H);
    f32x4 acc = {0.f,0.f,0.f,0.f};
    acc = __builtin_amdgcn_mfma_f32_16x16x32_bf16(a0, B[0+lq], acc, 0, 0, 0);
    acc = __builtin_amdgcn_mfma_f32_16x16x32_bf16(a1, B[4+lq], acc, 0, 0, 0);
    acc = __builtin_amdgcn_mfma_f32_16x16x32_bf16(a2, B[8+lq], acc, 0, 0, 0);
    acc = __builtin_amdgcn_mfma_f32_16x16x32_bf16(a3, B[12+lq], acc, 0, 0, 0);
    int col = n0 + lr;
    float bias = Bias[col];
    #pragma unroll
    for (int r=0;r<4;r++){
      int row = m0 + lq*4 + r;
      Out[(size_t)row*N + col] = f2bf(acc[r] + bias);
    }
  }
}

// ---------------------------------------------------------------------------
// Helpers for node update
// ---------------------------------------------------------------------------
static __device__ __forceinline__ void ln_stats(float v, float* sm, int tid,
                                                float& mu, float& var){
  float s = v, q = v*v;
  #pragma unroll
  for (int o=32;o>=1;o>>=1){ s += __shfl_xor(s,o,64); q += __shfl_xor(q,o,64); }
  __syncthreads();
  if ((tid & 63) == 0){ sm[(tid>>6)*2] = s; sm[(tid>>6)*2+1] = q; }
  __syncthreads();
  float S = sm[0] + sm[2], Q = sm[1] + sm[3];
  mu = S * (1.f/128.f);
  var = Q * (1.f/128.f) - mu*mu;
}

static __device__ __forceinline__ float act_msg(float f, float s){
  float sig = __builtin_amdgcn_rcpf(1.f + __expf(-f));
  float sp  = fmaxf(s, 0.f) + __logf(1.f + __expf(-fabsf(s)));
  return sig * sp;
}

#define BN_RSQ 0.9999950000374997f   /* 1/sqrt(1+1e-5) */

// ---------------------------------------------------------------------------
// Protein node update: aggregate pp + lp relations, dual epilogue, sum.
// ---------------------------------------------------------------------------
__global__ void __launch_bounds__(128) node_update_p(
    const bf16* __restrict__ PT, const bf16* __restrict__ LT,
    const float* __restrict__ xp,
    const int* __restrict__ pp_rp, const int* __restrict__ pp_src, const float* __restrict__ pp_d,
    const int* __restrict__ lp_rp, const int* __restrict__ lp_src, const float* __restrict__ lp_d,
    const bf16* __restrict__ T2,
    const float* __restrict__ bn_w, const float* __restrict__ bn_b,
    const float* __restrict__ ln_w, const float* __restrict__ ln_b,
    float* __restrict__ xp_out, bf16* __restrict__ xp_bf, int layer)
{
  __shared__ float sm[4];
  int node = blockIdx.x;
  int c = threadIdx.x;
  float x = xp[(size_t)node*H + c];
  const uint32* PTu = (const uint32*)(const void*)PT;
  const uint32* LTu = (const uint32*)(const void*)LT;
  float o1, o2;
  // ---- relation pp ----
  {
    int pr = layer*3 + 0;
    float fd = bf2f(PT[(size_t)node*1024 + 512 + c]);
    float sd = bf2f(PT[(size_t)node*1024 + 640 + c]);
    const uint2* Tb = (const uint2*)(const void*)(T2 + (size_t)pr*1025*512);
    float acc = 0.f;
    int e0 = pp_rp[node], e1 = pp_rp[node+1];
    for (int i=e0;i<e1;i++){
      int s = pp_src[i];
      float dd = pp_d[i];
      float bfl = dd * 128.0f;
      int b = (int)bfl; b = (b > 1023) ? 1023 : b;
      float fr = bfl - (float)b;
      uint32 g = PTu[(size_t)s*512 + c];
      uint2 t = Tb[(size_t)b*128 + c];
      float f0 = u2f_lo(t.x), s0 = u2f_hi(t.x);
      float f1 = u2f_lo(t.y), s1 = u2f_hi(t.y);
      float f  = fd + u2f_lo(g) + f0 + fr*(f1-f0);
      float sv = sd + u2f_hi(g) + s0 + fr*(s1-s0);
      acc += act_msg(f, sv);
    }
    float v = acc * (bn_w[pr*H+c] * BN_RSQ) + bn_b[pr*H+c] + x;
    float mu, var; ln_stats(v, sm, c, mu, var);
    float ln = (v-mu)*rsqrtf(var+1e-5f)*ln_w[pr*H+c] + ln_b[pr*H+c];
    o1 = fmaxf(ln, 0.f) + x;
  }
  // ---- relation lp ----
  {
    int pr = layer*3 + 1;
    float fd = bf2f(PT[(size_t)node*1024 + 768 + c]);
    float sd = bf2f(PT[(size_t)node*1024 + 896 + c]);
    const uint2* Tb = (const uint2*)(const void*)(T2 + (size_t)pr*1025*512);
    float acc = 0.f;
    int e0 = lp_rp[node], e1 = lp_rp[node+1];
    for (int i=e0;i<e1;i++){
      int s = lp_src[i];
      float dd = lp_d[i];
      float bfl = dd * 128.0f;
      int b = (int)bfl; b = (b > 1023) ? 1023 : b;
      float fr = bfl - (float)b;
      uint32 g = LTu[(size_t)s*256 + c];
      uint2 t = Tb[(size_t)b*128 + c];
      float f0 = u2f_lo(t.x), s0 = u2f_hi(t.x);
      float f1 = u2f_lo(t.y), s1 = u2f_hi(t.y);
      float f  = fd + u2f_lo(g) + f0 + fr*(f1-f0);
      float sv = sd + u2f_hi(g) + s0 + fr*(s1-s0);
      acc += act_msg(f, sv);
    }
    float v = acc * (bn_w[pr*H+c] * BN_RSQ) + bn_b[pr*H+c] + x;
    float mu, var; ln_stats(v, sm, c, mu, var);
    float ln = (v-mu)*rsqrtf(var+1e-5f)*ln_w[pr*H+c] + ln_b[pr*H+c];
    o2 = fmaxf(ln, 0.f) + x;
  }
  float out = o1 + o2;
  xp_out[(size_t)node*H + c] = out;
  xp_bf[(size_t)node*H + c] = f2bf(out);
}

// ---------------------------------------------------------------------------
// Ligand node update: aggregate pl relation only.
// ---------------------------------------------------------------------------
__global__ void __launch_bounds__(128) node_update_l(
    const bf16* __restrict__ PT, const bf16* __restrict__ LT,
    const float* __restrict__ xl,
    const int* __restrict__ pl_rp, const int* __restrict__ pl_src, const float* __restrict__ pl_d,
    const bf16* __restrict__ T2,
    const float* __restrict__ bn_w, const float* __restrict__ bn_b,
    const float* __restrict__ ln_w, const float* __restrict__ ln_b,
    float* __restrict__ xl_out, bf16* __restrict__ xl_bf, int layer)
{
  __shared__ float sm[4];
  int node = blockIdx.x;
  int c = threadIdx.x;
  float x = xl[(size_t)node*H + c];
  const uint32* PTu = (const uint32*)(const void*)PT;
  int pr = layer*3 + 2;
  float fd = bf2f(LT[(size_t)node*512 + 256 + c]);
  float sd = bf2f(LT[(size_t)node*512 + 384 + c]);
  const uint2* Tb = (const uint2*)(const void*)(T2 + (size_t)pr*1025*512);
  float acc = 0.f;
  int e0 = pl_rp[node], e1 = pl_rp[node+1];
  for (int i=e0;i<e1;i++){
    int s = pl_src[i];
    float dd = pl_d[i];
    float bfl = dd * 128.0f;
    int b = (int)bfl; b = (b > 1023) ? 1023 : b;
    float fr = bfl - (float)b;
    uint32 g = PTu[(size_t)s*512 + 128 + c];
    uint2 t = Tb[(size_t)b*128 + c];
    float f0 = u2f_lo(t.x), s0 = u2f_hi(t.x);
    float f1 = u2f_lo(t.y), s1 = u2f_hi(t.y);
    float f  = fd + u2f_lo(g) + f0 + fr*(f1-f0);
    float sv = sd + u2f_hi(g) + s0 + fr*(s1-s0);
    acc += act_msg(f, sv);
  }
  float v = acc * (bn_w[pr*H+c] * BN_RSQ) + bn_b[pr*H+c] + x;
  float mu, var; ln_stats(v, sm, c, mu, var);
  float ln = (v-mu)*rsqrtf(var+1e-5f)*ln_w[pr*H+c] + ln_b[pr*H+c];
  float out = fmaxf(ln, 0.f) + x;
  xl_out[(size_t)node*H + c] = out;
  xl_bf[(size_t)node*H + c] = f2bf(out);
}

// ---------------------------------------------------------------------------
// Final: LN(xp) @ fc_w[128,21] + fc_b
// ---------------------------------------------------------------------------
__global__ void __launch_bounds__(128) final_k(const float* __restrict__ xp,
    const float* __restrict__ lnw, const float* __restrict__ lnb,
    const float* __restrict__ fcw, const float* __restrict__ fcb,
    float* __restrict__ out, int N){
  __shared__ float sm[4];
  __shared__ float lnv[128];
  int node = blockIdx.x, c = threadIdx.x;
  float v = xp[(size_t)node*H + c];
  float mu, var; ln_stats(v, sm, c, mu, var);
  float ln = (v-mu)*rsqrtf(var+1e-5f)*lnw[c] + lnb[c];
  lnv[c] = ln;
  __syncthreads();
  if (c < 21){
    float a = fcb[c];
    #pragma unroll 4
    for (int i=0;i<128;i++) a += lnv[i]*fcw[i*21+c];
    out[(size_t)node*21 + c] = a;
  }
}

// ---------------------------------------------------------------------------
extern "C" void kernel_launch(void* const* d_in, const int* in_sizes, int n_in,
                              void* d_out, int out_size, void* d_ws, size_t ws_size,
                              hipStream_t stream){
  const float* x_protein = (const float*)d_in[0];
  const float* x_ligand  = (const float*)d_in[1];
  const int*   ei_pp = (const int*)d_in[2];
  const float* ea_pp = (const float*)d_in[3];
  const int*   ei_lp = (const int*)d_in[4];
  const float* ea_lp = (const float*)d_in[5];
  const int*   ei_pl = (const int*)d_in[6];
  const float* ea_pl = (const float*)d_in[7];
  const float* Wp  = (const float*)d_in[8];
  const float* bp  = (const float*)d_in[9];
  const float* Wl  = (const float*)d_in[10];
  const float* bl  = (const float*)d_in[11];
  const float* Wf  = (const float*)d_in[12];
  const float* bfv = (const float*)d_in[13];
  const float* Wsv = (const float*)d_in[14];
  const float* bsv = (const float*)d_in[15];
  const float* bn_w = (const float*)d_in[16];
  const float* bn_b = (const float*)d_in[17];
  const float* ln_w = (const float*)d_in[18];
  const float* ln_b = (const float*)d_in[19];
  const float* lno_w = (const float*)d_in[20];
  const float* lno_b = (const float*)d_in[21];
  const float* fc_w = (const float*)d_in[22];
  const float* fc_b = (const float*)d_in[23];

  int NP  = in_sizes[0]/6, NL = in_sizes[1]/6;
  int EPP = in_sizes[3], ELP = in_sizes[5], EPL = in_sizes[7];

  char* ws = (char*)d_ws;
  size_t off = 0;
  auto alloc = [&](size_t bytes)->void*{
    void* p = ws + off; off = (off + bytes + 255) & ~(size_t)255; return p;
  };

  float* xpA = (float*)alloc((size_t)NP*H*4);
  float* xpB = (float*)alloc((size_t)NP*H*4);
  float* xlA = (float*)alloc((size_t)NL*H*4);
  float* xlB = (float*)alloc((size_t)NL*H*4);
  bf16* xp_bf = (bf16*)alloc((size_t)NP*H*2);
  bf16* xl_bf = (bf16*)alloc((size_t)NL*H*2);
  bf16* PT    = (bf16*)alloc((size_t)NP*1024*2);
  bf16* LT    = (bf16*)alloc((size_t)NL*512*2);
  bf16* Wt_p  = (bf16*)alloc((size_t)4*1024*H*2);
  bf16* Wt_l  = (bf16*)alloc((size_t)4*512*H*2);
  float* Bias_p = (float*)alloc((size_t)4*1024*4);
  float* Bias_l = (float*)alloc((size_t)4*512*4);
  bf16* T2    = (bf16*)alloc((size_t)12*1025*512*2);
  int* counts = (int*)alloc((size_t)(2*NP+NL)*4);
  int* rp_pp  = (int*)alloc((size_t)(NP+1)*4);
  int* cur_pp = (int*)alloc((size_t)NP*4);
  int* rp_lp  = (int*)alloc((size_t)(NP+1)*4);
  int* cur_lp = (int*)alloc((size_t)NP*4);
  int* rp_pl  = (int*)alloc((size_t)(NL+1)*4);
  int* cur_pl = (int*)alloc((size_t)NL*4);
  int*   csrc_pp = (int*)alloc((size_t)EPP*4);
  float* cd_pp   = (float*)alloc((size_t)EPP*4);
  int*   csrc_lp = (int*)alloc((size_t)ELP*4);
  float* cd_lp   = (float*)alloc((size_t)ELP*4);
  int*   csrc_pl = (int*)alloc((size_t)EPL*4);
  float* cd_pl   = (float*)alloc((size_t)EPL*4);
  (void)ws_size; (void)n_in; (void)out_size;

  // --- weight prep + RBF table ---
  prep_wp<<<(4096+255)/256, 256, 0, stream>>>(Wf, Wsv, bfv, bsv, Wt_p, Bias_p);
  prep_wl<<<(2048+255)/256, 256, 0, stream>>>(Wf, Wsv, bfv, bsv, Wt_l, Bias_l);
  build_rbf_tab<<<(12*1025*128+255)/256, 256, 0, stream>>>(Wf, Wsv, T2);

  // --- CSR build ---
  hipMemsetAsync(counts, 0, (size_t)(2*NP+NL)*4, stream);
  int* cnt_pp = counts; int* cnt_lp = counts + NP; int* cnt_pl = counts + 2*NP;
  hist_k<<<(EPP+255)/256, 256, 0, stream>>>(ei_pp + EPP, EPP, cnt_pp);
  hist_k<<<(ELP+255)/256, 256, 0, stream>>>(ei_lp + ELP, ELP, cnt_lp);
  hist_k<<<(EPL+255)/256, 256, 0, stream>>>(ei_pl + EPL, EPL, cnt_pl);
  scan_k<<<1, SCAN_T, 0, stream>>>(cnt_pp, NP, rp_pp, cur_pp);
  scan_k<<<1, SCAN_T, 0, stream>>>(cnt_lp, NP, rp_lp, cur_lp);
  scan_k<<<1, SCAN_T, 0, stream>>>(cnt_pl, NL, rp_pl, cur_pl);
  fill_k<<<(EPP+255)/256, 256, 0, stream>>>(ei_pp, ei_pp + EPP, ea_pp, EPP, cur_pp, csrc_pp, cd_pp);
  fill_k<<<(ELP+255)/256, 256, 0, stream>>>(ei_lp, ei_lp + ELP, ea_lp, ELP, cur_lp, csrc_lp, cd_lp);
  fill_k<<<(EPL+255)/256, 256, 0, stream>>>(ei_pl, ei_pl + EPL, ea_pl, EPL, cur_pl, csrc_pl, cd_pl);

  // --- embeddings ---
  embed_k<<<((size_t)NP*H+255)/256, 256, 0, stream>>>(x_protein, Wp, bp, xpA, xp_bf, NP);
  embed_k<<<((size_t)NL*H+255)/256, 256, 0, stream>>>(x_ligand,  Wl, bl, xlA, xl_bf, NL);

  // --- layers ---
  float* xp_cur = xpA; float* xp_nxt = xpB;
  float* xl_cur = xlA; float* xl_nxt = xlB;
  for (int l=0; l<4; l++){
    gemm_tables<<<NP>>4, 256, 0, stream>>>(xp_bf, Wt_p + (size_t)l*1024*H,
                                           Bias_p + l*1024, PT, NP, 1024);
    gemm_tables<<<NL>>4, 256, 0, stream>>>(xl_bf, Wt_l + (size_t)l*512*H,
                                           Bias_l + l*512, LT, NL, 512);
    node_update_p<<<NP, 128, 0, stream>>>(PT, LT, xp_cur,
        rp_pp, csrc_pp, cd_pp, rp_lp, csrc_lp, cd_lp, T2,
        bn_w, bn_b, ln_w, ln_b, xp_nxt, xp_bf, l);
    node_update_l<<<NL, 128, 0, stream>>>(PT, LT, xl_cur,
        rp_pl, csrc_pl, cd_pl, T2,
        bn_w, bn_b, ln_w, ln_b, xl_nxt, xl_bf, l);
    float* t;
    t = xp_cur; xp_cur = xp_nxt; xp_nxt = t;
    t = xl_cur; xl_cur = xl_nxt; xl_nxt = t;
  }

  // --- output head ---
  final_k<<<NP, 128, 0, stream>>>(xp_cur, lno_w, lno_b, fc_w, fc_b, (float*)d_out, NP);
}

// Round 4
// 1535.593 us; speedup vs baseline: 2.0538x; 1.0962x over previous
//
#include <hip/hip_runtime.h>
#include <hip/hip_bf16.h>
#include <math.h>

#define H 128

typedef __bf16 bf16x8 __attribute__((ext_vector_type(8)));
typedef float f32x4 __attribute__((ext_vector_type(4)));
typedef __hip_bfloat16 bf16;
typedef unsigned int uint32;

static __device__ __forceinline__ float bf2f(bf16 v){ return __bfloat162float(v); }
static __device__ __forceinline__ bf16 f2bf(float v){ return __float2bfloat16(v); }
static __device__ __forceinline__ float u2f_lo(uint32 v){ return __uint_as_float(v << 16); }
static __device__ __forceinline__ float u2f_hi(uint32 v){ return __uint_as_float(v & 0xffff0000u); }

union bfpack { struct { bf16 lo, hi; } h; uint32 u; };
static __device__ __forceinline__ uint32 pack_bf2(float a, float b){
  bfpack p; p.h.lo = f2bf(a); p.h.hi = f2bf(b); return p.u;
}

// ---------------------------------------------------------------------------
// Protein node-table layout PT[node][1024] (bf16):
//   [0,256)    pp-src interleaved pairs {f_c, s_c}   (gathered by pp edges)
//   [256,512)  pl-src interleaved pairs {f_c, s_c}   (gathered by pl edges)
//   [512,640)  pp f_dst (+bias bf)   [640,768)  pp s_dst (+bs)
//   [768,896)  lp f_dst (+bf)        [896,1024) lp s_dst (+bs)
// Ligand node-table LT[node][512]:
//   [0,256)    lp-src interleaved pairs {f_c, s_c}   (gathered by lp edges)
//   [256,384)  pl f_dst (+bf)        [384,512)  pl s_dst (+bs)
// ---------------------------------------------------------------------------
__global__ void prep_wp(const float* __restrict__ Wf, const float* __restrict__ Ws,
                        const float* __restrict__ bfv, const float* __restrict__ bsv,
                        bf16* __restrict__ Wt, float* __restrict__ Bias){
  int tid = blockIdx.x*blockDim.x + threadIdx.x;   // idx*128 + k
  if (tid >= 4*1024*128) return;
  int k = tid & 127; int idx = tid >> 7;
  int r = idx & 1023; int l = idx >> 10;
  int rel, c, row0; const float* W; float bias = 0.f;
  if (r < 256)      { rel=0; c=r>>1;        row0=128; W = (r&1)?Ws:Wf; }
  else if (r < 512) { rel=2; c=(r-256)>>1;  row0=128; W = (r&1)?Ws:Wf; }
  else if (r < 640) { rel=0; c=r-512; row0=0; W=Wf; bias = bfv[(l*3+rel)*H+c]; }
  else if (r < 768) { rel=0; c=r-640; row0=0; W=Ws; bias = bsv[(l*3+rel)*H+c]; }
  else if (r < 896) { rel=1; c=r-768; row0=0; W=Wf; bias = bfv[(l*3+rel)*H+c]; }
  else              { rel=1; c=r-896; row0=0; W=Ws; bias = bsv[(l*3+rel)*H+c]; }
  Wt[tid] = f2bf(W[((size_t)(l*3+rel)*272 + row0 + k)*H + c]);
  if (k == 0) Bias[idx] = bias;
}

__global__ void prep_wl(const float* __restrict__ Wf, const float* __restrict__ Ws,
                        const float* __restrict__ bfv, const float* __restrict__ bsv,
                        bf16* __restrict__ Wt, float* __restrict__ Bias){
  int tid = blockIdx.x*blockDim.x + threadIdx.x;   // idx*128 + k
  if (tid >= 4*512*128) return;
  int k = tid & 127; int idx = tid >> 7;
  int r = idx & 511; int l = idx >> 9;
  int rel, c, row0; const float* W; float bias = 0.f;
  if (r < 256)      { rel=1; c=r>>1;   row0=128; W = (r&1)?Ws:Wf; }
  else if (r < 384) { rel=2; c=r-256; row0=0; W=Wf; bias = bfv[(l*3+rel)*H+c]; }
  else              { rel=2; c=r-384; row0=0; W=Ws; bias = bsv[(l*3+rel)*H+c]; }
  Wt[tid] = f2bf(W[((size_t)(l*3+rel)*272 + row0 + k)*H + c]);
  if (k == 0) Bias[idx] = bias;
}

// ---------------------------------------------------------------------------
// RBF lookup table: T2[pr][b][4c+{0..3}] = {f_b, s_b, f_{b+1}, s_{b+1}} (bf16)
// ---------------------------------------------------------------------------
__global__ void build_rbf_tab(const float* __restrict__ Wf, const float* __restrict__ Ws,
                              bf16* __restrict__ T2){
  int idx = blockIdx.x*blockDim.x + threadIdx.x;   // pr*1025*128 + b*128 + c
  if (idx >= 12*1025*128) return;
  int c = idx & 127;
  int b = (idx >> 7) % 1025;
  int pr = idx / (1025*128);
  float d0 = (float)b * 0.0078125f;
  float d1 = d0 + 0.0078125f;
  const float* wf = Wf + ((size_t)pr*272 + 256)*H + c;
  const float* ws = Ws + ((size_t)pr*272 + 256)*H + c;
  float f0=0.f, s0=0.f, f1=0.f, s1=0.f;
  #pragma unroll
  for (int k=0;k<16;k++){
    float o = 0.533333333f*(float)k;
    float t0 = d0 - o, t1 = d1 - o;
    float r0 = __expf(-1.7578125f*t0*t0);
    float r1 = __expf(-1.7578125f*t1*t1);
    float wfk = wf[(size_t)k*H], wsk = ws[(size_t)k*H];
    f0 += r0*wfk; s0 += r0*wsk; f1 += r1*wfk; s1 += r1*wsk;
  }
  bf16* o = T2 + ((size_t)(pr*1025 + b))*512 + 4*c;
  o[0]=f2bf(f0); o[1]=f2bf(s0); o[2]=f2bf(f1); o[3]=f2bf(s1);
}

// ---------------------------------------------------------------------------
// CSR build
// ---------------------------------------------------------------------------
__global__ void hist_k(const int* __restrict__ dst, int E, int* __restrict__ counts){
  int e = blockIdx.x*blockDim.x + threadIdx.x;
  if (e < E) atomicAdd(&counts[dst[e]], 1);
}

#define SCAN_T 1024
__global__ void scan_k(const int* __restrict__ counts, int n,
                       int* __restrict__ row_ptr, int* __restrict__ cursor){
  __shared__ int tmp[SCAN_T];
  __shared__ int carry_s;
  int tid = threadIdx.x;
  if (tid == 0) carry_s = 0;
  __syncthreads();
  for (int base=0; base<n; base+=SCAN_T){
    int i = base + tid;
    int v = (i < n) ? counts[i] : 0;
    tmp[tid] = v;
    __syncthreads();
    for (int off=1; off<SCAN_T; off<<=1){
      int t = (tid >= off) ? tmp[tid-off] : 0;
      __syncthreads();
      tmp[tid] += t;
      __syncthreads();
    }
    int incl = tmp[tid];
    int carry = carry_s;
    if (i < n){ int ex = carry + incl - v; row_ptr[i] = ex; cursor[i] = ex; }
    __syncthreads();
    if (tid == SCAN_T-1) carry_s = carry + incl;
    __syncthreads();
  }
  if (tid == 0) row_ptr[n] = carry_s;
}

__global__ void fill_k(const int* __restrict__ src, const int* __restrict__ dst,
                       const float* __restrict__ ea, int E, int* __restrict__ cursor,
                       int* __restrict__ csr_src, float* __restrict__ csr_d){
  int e = blockIdx.x*blockDim.x + threadIdx.x;
  if (e < E){
    int p = atomicAdd(&cursor[dst[e]], 1);
    csr_src[p] = src[e];
    csr_d[p] = ea[e];
  }
}

// ---------------------------------------------------------------------------
// Node embedding: x @ W[6,128] + b  (fp32 out + bf16 copy)
// ---------------------------------------------------------------------------
__global__ void embed_k(const float* __restrict__ Xin, const float* __restrict__ W,
                        const float* __restrict__ b, float* __restrict__ Xout,
                        bf16* __restrict__ Xbf, int N){
  int idx = blockIdx.x*blockDim.x + threadIdx.x;
  if (idx >= N*H) return;
  int n = idx >> 7, c = idx & 127;
  float acc = b[c];
  #pragma unroll
  for (int k=0;k<6;k++) acc += Xin[n*6+k] * W[k*H+c];
  Xout[idx] = acc;
  Xbf[idx] = f2bf(acc);
}

// ---------------------------------------------------------------------------
// Table GEMM: Out[M,N] = bf16(X[M,128] @ Wt[N,128]^T + Bias)
// Block = 4 waves = one 16-row strip; wave w covers cols [w*N/4,(w+1)*N/4).
// ---------------------------------------------------------------------------
__global__ void __launch_bounds__(256) gemm_tables(
    const bf16* __restrict__ X, const bf16* __restrict__ Wt,
    const float* __restrict__ Bias, bf16* __restrict__ Out,
    int M, int N){
  int strip = blockIdx.x;
  int m0 = strip << 4;
  int lane = threadIdx.x & 63;
  int wave = threadIdx.x >> 6;
  int lr = lane & 15, lq = lane >> 4;
  const bf16x8* A = (const bf16x8*)(const void*)(X + (size_t)(m0+lr)*H);
  bf16x8 a0 = A[0+lq], a1 = A[4+lq], a2 = A[8+lq], a3 = A[12+lq];
  int ncols = N >> 2;
  int n_end = (wave+1) * ncols;
  #pragma unroll 4
  for (int n0 = wave*ncols; n0 < n_end; n0 += 16){
    const bf16x8* B = (const bf16x8*)(const void*)(Wt + (size_t)(n0+lr)*H);
    f32x4 acc = {0.f,0.f,0.f,0.f};
    acc = __builtin_amdgcn_mfma_f32_16x16x32_bf16(a0, B[0+lq], acc, 0, 0, 0);
    acc = __builtin_amdgcn_mfma_f32_16x16x32_bf16(a1, B[4+lq], acc, 0, 0, 0);
    acc = __builtin_amdgcn_mfma_f32_16x16x32_bf16(a2, B[8+lq], acc, 0, 0, 0);
    acc = __builtin_amdgcn_mfma_f32_16x16x32_bf16(a3, B[12+lq], acc, 0, 0, 0);
    int col = n0 + lr;
    float bias = Bias[col];
    #pragma unroll
    for (int r=0;r<4;r++){
      int row = m0 + lq*4 + r;
      Out[(size_t)row*N + col] = f2bf(acc[r] + bias);
    }
  }
}

// ---------------------------------------------------------------------------
// Node-update helpers
// ---------------------------------------------------------------------------
static __device__ __forceinline__ float act_msg(float f, float s){
  float sig = __builtin_amdgcn_rcpf(1.f + __expf(-f));
  float sp  = fmaxf(s, 0.f) + __logf(1.f + __expf(-fabsf(s)));
  return sig * sp;
}

#define BN_RSQ 0.9999950000374997f   /* 1/sqrt(1+1e-5) */

// per-edge contribution for 2 channels (one lane)
static __device__ __forceinline__ void edge2(uint2 g, uint4 t, float fr,
                                             float fd0, float sd0, float fd1, float sd1,
                                             float& acc0, float& acc1){
  float f0a = u2f_lo(t.x), s0a = u2f_hi(t.x), f1a = u2f_lo(t.y), s1a = u2f_hi(t.y);
  float f0b = u2f_lo(t.z), s0b = u2f_hi(t.z), f1b = u2f_lo(t.w), s1b = u2f_hi(t.w);
  float fa = fd0 + u2f_lo(g.x) + f0a + fr*(f1a-f0a);
  float sa = sd0 + u2f_hi(g.x) + s0a + fr*(s1a-s0a);
  float fb = fd1 + u2f_lo(g.y) + f0b + fr*(f1b-f0b);
  float sb = sd1 + u2f_hi(g.y) + s0b + fr*(s1b-s0b);
  acc0 += act_msg(fa, sa);
  acc1 += act_msg(fb, sb);
}

// wave-level LN over 128 channels held as 2/lane
static __device__ __forceinline__ void ln_stats_w(float v0, float v1, float& mu, float& var){
  float s = v0 + v1, q = v0*v0 + v1*v1;
  #pragma unroll
  for (int o=32;o>=1;o>>=1){ s += __shfl_xor(s,o,64); q += __shfl_xor(q,o,64); }
  mu = s * (1.f/128.f);
  var = q * (1.f/128.f) - mu*mu;
}

// aggregate one relation over CSR edges; returns acc pair
static __device__ __forceinline__ void aggregate(
    const int* __restrict__ srcv, const float* __restrict__ dv,
    int e0, int e1,
    const uint2* __restrict__ G, int gstride, int goff,   // gather: G[s*gstride+goff+lane]
    const uint4* __restrict__ Tb, int lane,
    float fd0, float sd0, float fd1, float sd1,
    float& acc0, float& acc1){
  int i = e0;
  for (; i+2 <= e1; i += 2){
    int sA = srcv[i],   sB = srcv[i+1];
    float dA = dv[i],   dB = dv[i+1];
    float bflA = dA * 128.0f, bflB = dB * 128.0f;
    int bA = (int)bflA; bA = (bA > 1023) ? 1023 : bA;
    int bB = (int)bflB; bB = (bB > 1023) ? 1023 : bB;
    float frA = bflA - (float)bA, frB = bflB - (float)bB;
    uint2 gA = G[(size_t)sA*gstride + goff + lane];
    uint2 gB = G[(size_t)sB*gstride + goff + lane];
    uint4 tA = Tb[(size_t)bA*64 + lane];
    uint4 tB = Tb[(size_t)bB*64 + lane];
    edge2(gA, tA, frA, fd0, sd0, fd1, sd1, acc0, acc1);
    edge2(gB, tB, frB, fd0, sd0, fd1, sd1, acc0, acc1);
  }
  if (i < e1){
    int s = srcv[i];
    float dd = dv[i];
    float bfl = dd * 128.0f;
    int b = (int)bfl; b = (b > 1023) ? 1023 : b;
    float fr = bfl - (float)b;
    uint2 g = G[(size_t)s*gstride + goff + lane];
    uint4 t = Tb[(size_t)b*64 + lane];
    edge2(g, t, fr, fd0, sd0, fd1, sd1, acc0, acc1);
  }
}

// ---------------------------------------------------------------------------
// Protein node update: wave per node, 2 channels/lane, pp + lp relations.
// ---------------------------------------------------------------------------
__global__ void __launch_bounds__(256) node_update_p(
    const bf16* __restrict__ PT, const bf16* __restrict__ LT,
    const float* __restrict__ xp,
    const int* __restrict__ pp_rp, const int* __restrict__ pp_src, const float* __restrict__ pp_d,
    const int* __restrict__ lp_rp, const int* __restrict__ lp_src, const float* __restrict__ lp_d,
    const bf16* __restrict__ T2,
    const float* __restrict__ bn_w, const float* __restrict__ bn_b,
    const float* __restrict__ ln_w, const float* __restrict__ ln_b,
    float* __restrict__ xp_out, bf16* __restrict__ xp_bf, int layer, int NP)
{
  int wave = threadIdx.x >> 6;
  int lane = threadIdx.x & 63;
  int node = blockIdx.x*4 + wave;
  if (node >= NP) return;
  float2 x = ((const float2*)(const void*)(xp + (size_t)node*H))[lane];
  const uint32* PTu = (const uint32*)(const void*)PT;
  const uint2*  PTg = (const uint2*)(const void*)PT;
  const uint2*  LTg = (const uint2*)(const void*)LT;
  float o1_0, o1_1, o2_0, o2_1;
  // ---- relation pp ----
  {
    int pr = layer*3 + 0;
    uint32 fdp = PTu[(size_t)node*512 + 256 + lane];
    uint32 sdp = PTu[(size_t)node*512 + 320 + lane];
    const uint4* Tb = (const uint4*)(const void*)(T2 + (size_t)pr*1025*512);
    float acc0 = 0.f, acc1 = 0.f;
    aggregate(pp_src, pp_d, pp_rp[node], pp_rp[node+1], PTg, 256, 0, Tb, lane,
              u2f_lo(fdp), u2f_lo(sdp), u2f_hi(fdp), u2f_hi(sdp), acc0, acc1);
    float2 bw = ((const float2*)(const void*)(bn_w + pr*H))[lane];
    float2 bb = ((const float2*)(const void*)(bn_b + pr*H))[lane];
    float2 lw = ((const float2*)(const void*)(ln_w + pr*H))[lane];
    float2 lb = ((const float2*)(const void*)(ln_b + pr*H))[lane];
    float v0 = acc0 * (bw.x * BN_RSQ) + bb.x + x.x;
    float v1 = acc1 * (bw.y * BN_RSQ) + bb.y + x.y;
    float mu, var; ln_stats_w(v0, v1, mu, var);
    float rs = rsqrtf(var + 1e-5f);
    o1_0 = fmaxf((v0-mu)*rs*lw.x + lb.x, 0.f) + x.x;
    o1_1 = fmaxf((v1-mu)*rs*lw.y + lb.y, 0.f) + x.y;
  }
  // ---- relation lp ----
  {
    int pr = layer*3 + 1;
    uint32 fdp = PTu[(size_t)node*512 + 384 + lane];
    uint32 sdp = PTu[(size_t)node*512 + 448 + lane];
    const uint4* Tb = (const uint4*)(const void*)(T2 + (size_t)pr*1025*512);
    float acc0 = 0.f, acc1 = 0.f;
    aggregate(lp_src, lp_d, lp_rp[node], lp_rp[node+1], LTg, 128, 0, Tb, lane,
              u2f_lo(fdp), u2f_lo(sdp), u2f_hi(fdp), u2f_hi(sdp), acc0, acc1);
    float2 bw = ((const float2*)(const void*)(bn_w + pr*H))[lane];
    float2 bb = ((const float2*)(const void*)(bn_b + pr*H))[lane];
    float2 lw = ((const float2*)(const void*)(ln_w + pr*H))[lane];
    float2 lb = ((const float2*)(const void*)(ln_b + pr*H))[lane];
    float v0 = acc0 * (bw.x * BN_RSQ) + bb.x + x.x;
    float v1 = acc1 * (bw.y * BN_RSQ) + bb.y + x.y;
    float mu, var; ln_stats_w(v0, v1, mu, var);
    float rs = rsqrtf(var + 1e-5f);
    o2_0 = fmaxf((v0-mu)*rs*lw.x + lb.x, 0.f) + x.x;
    o2_1 = fmaxf((v1-mu)*rs*lw.y + lb.y, 0.f) + x.y;
  }
  float out0 = o1_0 + o2_0, out1 = o1_1 + o2_1;
  ((float2*)(void*)(xp_out + (size_t)node*H))[lane] = make_float2(out0, out1);
  ((uint32*)(void*)(xp_bf + (size_t)node*H))[lane] = pack_bf2(out0, out1);
}

// ---------------------------------------------------------------------------
// Ligand node update: wave per node, pl relation only.
// ---------------------------------------------------------------------------
__global__ void __launch_bounds__(256) node_update_l(
    const bf16* __restrict__ PT, const bf16* __restrict__ LT,
    const float* __restrict__ xl,
    const int* __restrict__ pl_rp, const int* __restrict__ pl_src, const float* __restrict__ pl_d,
    const bf16* __restrict__ T2,
    const float* __restrict__ bn_w, const float* __restrict__ bn_b,
    const float* __restrict__ ln_w, const float* __restrict__ ln_b,
    float* __restrict__ xl_out, bf16* __restrict__ xl_bf, int layer, int NL)
{
  int wave = threadIdx.x >> 6;
  int lane = threadIdx.x & 63;
  int node = blockIdx.x*4 + wave;
  if (node >= NL) return;
  float2 x = ((const float2*)(const void*)(xl + (size_t)node*H))[lane];
  const uint32* LTu = (const uint32*)(const void*)LT;
  const uint2*  PTg = (const uint2*)(const void*)PT;
  int pr = layer*3 + 2;
  uint32 fdp = LTu[(size_t)node*256 + 128 + lane];
  uint32 sdp = LTu[(size_t)node*256 + 192 + lane];
  const uint4* Tb = (const uint4*)(const void*)(T2 + (size_t)pr*1025*512);
  float acc0 = 0.f, acc1 = 0.f;
  aggregate(pl_src, pl_d, pl_rp[node], pl_rp[node+1], PTg, 256, 64, Tb, lane,
            u2f_lo(fdp), u2f_lo(sdp), u2f_hi(fdp), u2f_hi(sdp), acc0, acc1);
  float2 bw = ((const float2*)(const void*)(bn_w + pr*H))[lane];
  float2 bb = ((const float2*)(const void*)(bn_b + pr*H))[lane];
  float2 lw = ((const float2*)(const void*)(ln_w + pr*H))[lane];
  float2 lb = ((const float2*)(const void*)(ln_b + pr*H))[lane];
  float v0 = acc0 * (bw.x * BN_RSQ) + bb.x + x.x;
  float v1 = acc1 * (bw.y * BN_RSQ) + bb.y + x.y;
  float mu, var; ln_stats_w(v0, v1, mu, var);
  float rs = rsqrtf(var + 1e-5f);
  float out0 = fmaxf((v0-mu)*rs*lw.x + lb.x, 0.f) + x.x;
  float out1 = fmaxf((v1-mu)*rs*lw.y + lb.y, 0.f) + x.y;
  ((float2*)(void*)(xl_out + (size_t)node*H))[lane] = make_float2(out0, out1);
  ((uint32*)(void*)(xl_bf + (size_t)node*H))[lane] = pack_bf2(out0, out1);
}

// ---------------------------------------------------------------------------
// Final: LN(xp) @ fc_w[128,21] + fc_b
// ---------------------------------------------------------------------------
__global__ void __launch_bounds__(128) final_k(const float* __restrict__ xp,
    const float* __restrict__ lnw, const float* __restrict__ lnb,
    const float* __restrict__ fcw, const float* __restrict__ fcb,
    float* __restrict__ out, int N){
  __shared__ float sm[4];
  __shared__ float lnv[128];
  int node = blockIdx.x, c = threadIdx.x;
  float v = xp[(size_t)node*H + c];
  float s = v, q = v*v;
  #pragma unroll
  for (int o=32;o>=1;o>>=1){ s += __shfl_xor(s,o,64); q += __shfl_xor(q,o,64); }
  __syncthreads();
  if ((c & 63) == 0){ sm[(c>>6)*2] = s; sm[(c>>6)*2+1] = q; }
  __syncthreads();
  float S = sm[0] + sm[2], Q = sm[1] + sm[3];
  float mu = S * (1.f/128.f);
  float var = Q * (1.f/128.f) - mu*mu;
  float ln = (v-mu)*rsqrtf(var+1e-5f)*lnw[c] + lnb[c];
  lnv[c] = ln;
  __syncthreads();
  if (c < 21){
    float a = fcb[c];
    #pragma unroll 4
    for (int i=0;i<128;i++) a += lnv[i]*fcw[i*21+c];
    out[(size_t)node*21 + c] = a;
  }
}

// ---------------------------------------------------------------------------
extern "C" void kernel_launch(void* const* d_in, const int* in_sizes, int n_in,
                              void* d_out, int out_size, void* d_ws, size_t ws_size,
                              hipStream_t stream){
  const float* x_protein = (const float*)d_in[0];
  const float* x_ligand  = (const float*)d_in[1];
  const int*   ei_pp = (const int*)d_in[2];
  const float* ea_pp = (const float*)d_in[3];
  const int*   ei_lp = (const int*)d_in[4];
  const float* ea_lp = (const float*)d_in[5];
  const int*   ei_pl = (const int*)d_in[6];
  const float* ea_pl = (const float*)d_in[7];
  const float* Wp  = (const float*)d_in[8];
  const float* bp  = (const float*)d_in[9];
  const float* Wl  = (const float*)d_in[10];
  const float* bl  = (const float*)d_in[11];
  const float* Wf  = (const float*)d_in[12];
  const float* bfv = (const float*)d_in[13];
  const float* Wsv = (const float*)d_in[14];
  const float* bsv = (const float*)d_in[15];
  const float* bn_w = (const float*)d_in[16];
  const float* bn_b = (const float*)d_in[17];
  const float* ln_w = (const float*)d_in[18];
  const float* ln_b = (const float*)d_in[19];
  const float* lno_w = (const float*)d_in[20];
  const float* lno_b = (const float*)d_in[21];
  const float* fc_w = (const float*)d_in[22];
  const float* fc_b = (const float*)d_in[23];

  int NP  = in_sizes[0]/6, NL = in_sizes[1]/6;
  int EPP = in_sizes[3], ELP = in_sizes[5], EPL = in_sizes[7];

  char* ws = (char*)d_ws;
  size_t off = 0;
  auto alloc = [&](size_t bytes)->void*{
    void* p = ws + off; off = (off + bytes + 255) & ~(size_t)255; return p;
  };

  float* xpA = (float*)alloc((size_t)NP*H*4);
  float* xpB = (float*)alloc((size_t)NP*H*4);
  float* xlA = (float*)alloc((size_t)NL*H*4);
  float* xlB = (float*)alloc((size_t)NL*H*4);
  bf16* xp_bf = (bf16*)alloc((size_t)NP*H*2);
  bf16* xl_bf = (bf16*)alloc((size_t)NL*H*2);
  bf16* PT    = (bf16*)alloc((size_t)NP*1024*2);
  bf16* LT    = (bf16*)alloc((size_t)NL*512*2);
  bf16* Wt_p  = (bf16*)alloc((size_t)4*1024*H*2);
  bf16* Wt_l  = (bf16*)alloc((size_t)4*512*H*2);
  float* Bias_p = (float*)alloc((size_t)4*1024*4);
  float* Bias_l = (float*)alloc((size_t)4*512*4);
  bf16* T2    = (bf16*)alloc((size_t)12*1025*512*2);
  int* counts = (int*)alloc((size_t)(2*NP+NL)*4);
  int* rp_pp  = (int*)alloc((size_t)(NP+1)*4);
  int* cur_pp = (int*)alloc((size_t)NP*4);
  int* rp_lp  = (int*)alloc((size_t)(NP+1)*4);
  int* cur_lp = (int*)alloc((size_t)NP*4);
  int* rp_pl  = (int*)alloc((size_t)(NL+1)*4);
  int* cur_pl = (int*)alloc((size_t)NL*4);
  int*   csrc_pp = (int*)alloc((size_t)EPP*4);
  float* cd_pp   = (float*)alloc((size_t)EPP*4);
  int*   csrc_lp = (int*)alloc((size_t)ELP*4);
  float* cd_lp   = (float*)alloc((size_t)ELP*4);
  int*   csrc_pl = (int*)alloc((size_t)EPL*4);
  float* cd_pl   = (float*)alloc((size_t)EPL*4);
  (void)ws_size; (void)n_in; (void)out_size;

  // --- weight prep + RBF table ---
  prep_wp<<<(4*1024*128+255)/256, 256, 0, stream>>>(Wf, Wsv, bfv, bsv, Wt_p, Bias_p);
  prep_wl<<<(4*512*128+255)/256, 256, 0, stream>>>(Wf, Wsv, bfv, bsv, Wt_l, Bias_l);
  build_rbf_tab<<<(12*1025*128+255)/256, 256, 0, stream>>>(Wf, Wsv, T2);

  // --- CSR build ---
  hipMemsetAsync(counts, 0, (size_t)(2*NP+NL)*4, stream);
  int* cnt_pp = counts; int* cnt_lp = counts + NP; int* cnt_pl = counts + 2*NP;
  hist_k<<<(EPP+255)/256, 256, 0, stream>>>(ei_pp + EPP, EPP, cnt_pp);
  hist_k<<<(ELP+255)/256, 256, 0, stream>>>(ei_lp + ELP, ELP, cnt_lp);
  hist_k<<<(EPL+255)/256, 256, 0, stream>>>(ei_pl + EPL, EPL, cnt_pl);
  scan_k<<<1, SCAN_T, 0, stream>>>(cnt_pp, NP, rp_pp, cur_pp);
  scan_k<<<1, SCAN_T, 0, stream>>>(cnt_lp, NP, rp_lp, cur_lp);
  scan_k<<<1, SCAN_T, 0, stream>>>(cnt_pl, NL, rp_pl, cur_pl);
  fill_k<<<(EPP+255)/256, 256, 0, stream>>>(ei_pp, ei_pp + EPP, ea_pp, EPP, cur_pp, csrc_pp, cd_pp);
  fill_k<<<(ELP+255)/256, 256, 0, stream>>>(ei_lp, ei_lp + ELP, ea_lp, ELP, cur_lp, csrc_lp, cd_lp);
  fill_k<<<(EPL+255)/256, 256, 0, stream>>>(ei_pl, ei_pl + EPL, ea_pl, EPL, cur_pl, csrc_pl, cd_pl);

  // --- embeddings ---
  embed_k<<<((size_t)NP*H+255)/256, 256, 0, stream>>>(x_protein, Wp, bp, xpA, xp_bf, NP);
  embed_k<<<((size_t)NL*H+255)/256, 256, 0, stream>>>(x_ligand,  Wl, bl, xlA, xl_bf, NL);

  // --- layers ---
  float* xp_cur = xpA; float* xp_nxt = xpB;
  float* xl_cur = xlA; float* xl_nxt = xlB;
  for (int l=0; l<4; l++){
    gemm_tables<<<NP>>4, 256, 0, stream>>>(xp_bf, Wt_p + (size_t)l*1024*H,
                                           Bias_p + l*1024, PT, NP, 1024);
    gemm_tables<<<NL>>4, 256, 0, stream>>>(xl_bf, Wt_l + (size_t)l*512*H,
                                           Bias_l + l*512, LT, NL, 512);
    node_update_p<<<(NP+3)/4, 256, 0, stream>>>(PT, LT, xp_cur,
        rp_pp, csrc_pp, cd_pp, rp_lp, csrc_lp, cd_lp, T2,
        bn_w, bn_b, ln_w, ln_b, xp_nxt, xp_bf, l, NP);
    node_update_l<<<(NL+3)/4, 256, 0, stream>>>(PT, LT, xl_cur,
        rp_pl, csrc_pl, cd_pl, T2,
        bn_w, bn_b, ln_w, ln_b, xl_nxt, xl_bf, l, NL);
    float* t;
    t = xp_cur; xp_cur = xp_nxt; xp_nxt = t;
    t = xl_cur; xl_cur = xl_nxt; xl_nxt = t;
  }

  // --- output head ---
  final_k<<<NP, 128, 0, stream>>>(xp_cur, lno_w, lno_b, fc_w, fc_b, (float*)d_out, NP);
}

// Round 5
// 1410.960 us; speedup vs baseline: 2.2352x; 1.0883x over previous
//
#include <hip/hip_runtime.h>
#include <hip/hip_bf16.h>
#include <math.h>

#define H 128

typedef __bf16 bf16x8 __attribute__((ext_vector_type(8)));
typedef float f32x4 __attribute__((ext_vector_type(4)));
typedef __hip_bfloat16 bf16;
typedef unsigned int uint32;

static __device__ __forceinline__ float bf2f(bf16 v){ return __bfloat162float(v); }
static __device__ __forceinline__ bf16 f2bf(float v){ return __float2bfloat16(v); }
static __device__ __forceinline__ float u2f_lo(uint32 v){ return __uint_as_float(v << 16); }
static __device__ __forceinline__ float u2f_hi(uint32 v){ return __uint_as_float(v & 0xffff0000u); }

union bfpack { struct { bf16 lo, hi; } h; uint32 u; };
static __device__ __forceinline__ uint32 pack_bf2(float a, float b){
  bfpack p; p.h.lo = f2bf(a); p.h.hi = f2bf(b); return p.u;
}

// ---------------------------------------------------------------------------
// Protein node-table layout PT[node][1024] (bf16):
//   [0,256)    pp-src interleaved pairs {f_c, s_c}   (gathered by pp edges)
//   [256,512)  pl-src interleaved pairs {f_c, s_c}   (gathered by pl edges)
//   [512,640)  pp f_dst (+bias bf)   [640,768)  pp s_dst (+bs)
//   [768,896)  lp f_dst (+bf)        [896,1024) lp s_dst (+bs)
// Ligand node-table LT[node][512]:
//   [0,256)    lp-src interleaved pairs {f_c, s_c}   (gathered by lp edges)
//   [256,384)  pl f_dst (+bf)        [384,512)  pl s_dst (+bs)
//
// Weight storage is PERMUTED within each 64-col group for packed gemm stores:
// storage row (base + 16t + j) holds logical col (base + 4j + t).
// Bias stays in natural (logical) order.
// ---------------------------------------------------------------------------
static __device__ __forceinline__ int unperm64(int r){
  int base = r & ~63; int g = r & 63; int t = g >> 4; int j = g & 15;
  return base + 4*j + t;
}

__global__ void prep_wp(const float* __restrict__ Wf, const float* __restrict__ Ws,
                        const float* __restrict__ bfv, const float* __restrict__ bsv,
                        bf16* __restrict__ Wt, float* __restrict__ Bias){
  int tid = blockIdx.x*blockDim.x + threadIdx.x;   // storage idx*128 + k
  if (tid >= 4*1024*128) return;
  int k = tid & 127; int idx = tid >> 7;
  int rs = idx & 1023; int l = idx >> 10;
  int r = unperm64(rs);                            // logical col within table
  int rel, c, row0; const float* W; float bias = 0.f;
  if (r < 256)      { rel=0; c=r>>1;        row0=128; W = (r&1)?Ws:Wf; }
  else if (r < 512) { rel=2; c=(r-256)>>1;  row0=128; W = (r&1)?Ws:Wf; }
  else if (r < 640) { rel=0; c=r-512; row0=0; W=Wf; bias = bfv[(l*3+rel)*H+c]; }
  else if (r < 768) { rel=0; c=r-640; row0=0; W=Ws; bias = bsv[(l*3+rel)*H+c]; }
  else if (r < 896) { rel=1; c=r-768; row0=0; W=Wf; bias = bfv[(l*3+rel)*H+c]; }
  else              { rel=1; c=r-896; row0=0; W=Ws; bias = bsv[(l*3+rel)*H+c]; }
  Wt[tid] = f2bf(W[((size_t)(l*3+rel)*272 + row0 + k)*H + c]);
  if (k == 0) Bias[l*1024 + r] = bias;
}

__global__ void prep_wl(const float* __restrict__ Wf, const float* __restrict__ Ws,
                        const float* __restrict__ bfv, const float* __restrict__ bsv,
                        bf16* __restrict__ Wt, float* __restrict__ Bias){
  int tid = blockIdx.x*blockDim.x + threadIdx.x;   // storage idx*128 + k
  if (tid >= 4*512*128) return;
  int k = tid & 127; int idx = tid >> 7;
  int rs = idx & 511; int l = idx >> 9;
  int r = unperm64(rs);
  int rel, c, row0; const float* W; float bias = 0.f;
  if (r < 256)      { rel=1; c=r>>1;   row0=128; W = (r&1)?Ws:Wf; }
  else if (r < 384) { rel=2; c=r-256; row0=0; W=Wf; bias = bfv[(l*3+rel)*H+c]; }
  else              { rel=2; c=r-384; row0=0; W=Ws; bias = bsv[(l*3+rel)*H+c]; }
  Wt[tid] = f2bf(W[((size_t)(l*3+rel)*272 + row0 + k)*H + c]);
  if (k == 0) Bias[l*512 + r] = bias;
}

// ---------------------------------------------------------------------------
// RBF lookup table: T2[pr][b][4c+{0..3}] = {f_b, s_b, f_{b+1}, s_{b+1}} (bf16)
// ---------------------------------------------------------------------------
__global__ void build_rbf_tab(const float* __restrict__ Wf, const float* __restrict__ Ws,
                              bf16* __restrict__ T2){
  int idx = blockIdx.x*blockDim.x + threadIdx.x;   // pr*1025*128 + b*128 + c
  if (idx >= 12*1025*128) return;
  int c = idx & 127;
  int b = (idx >> 7) % 1025;
  int pr = idx / (1025*128);
  float d0 = (float)b * 0.0078125f;
  float d1 = d0 + 0.0078125f;
  const float* wf = Wf + ((size_t)pr*272 + 256)*H + c;
  const float* ws = Ws + ((size_t)pr*272 + 256)*H + c;
  float f0=0.f, s0=0.f, f1=0.f, s1=0.f;
  #pragma unroll
  for (int k=0;k<16;k++){
    float o = 0.533333333f*(float)k;
    float t0 = d0 - o, t1 = d1 - o;
    float r0 = __expf(-1.7578125f*t0*t0);
    float r1 = __expf(-1.7578125f*t1*t1);
    float wfk = wf[(size_t)k*H], wsk = ws[(size_t)k*H];
    f0 += r0*wfk; s0 += r0*wsk; f1 += r1*wfk; s1 += r1*wsk;
  }
  bf16* o = T2 + ((size_t)(pr*1025 + b))*512 + 4*c;
  o[0]=f2bf(f0); o[1]=f2bf(s0); o[2]=f2bf(f1); o[3]=f2bf(s1);
}

// ---------------------------------------------------------------------------
// CSR build
// ---------------------------------------------------------------------------
__global__ void hist_k(const int* __restrict__ dst, int E, int* __restrict__ counts){
  int e = blockIdx.x*blockDim.x + threadIdx.x;
  if (e < E) atomicAdd(&counts[dst[e]], 1);
}

#define SCAN_T 1024
__global__ void scan_k(const int* __restrict__ counts, int n,
                       int* __restrict__ row_ptr, int* __restrict__ cursor){
  __shared__ int tmp[SCAN_T];
  __shared__ int carry_s;
  int tid = threadIdx.x;
  if (tid == 0) carry_s = 0;
  __syncthreads();
  for (int base=0; base<n; base+=SCAN_T){
    int i = base + tid;
    int v = (i < n) ? counts[i] : 0;
    tmp[tid] = v;
    __syncthreads();
    for (int off=1; off<SCAN_T; off<<=1){
      int t = (tid >= off) ? tmp[tid-off] : 0;
      __syncthreads();
      tmp[tid] += t;
      __syncthreads();
    }
    int incl = tmp[tid];
    int carry = carry_s;
    if (i < n){ int ex = carry + incl - v; row_ptr[i] = ex; cursor[i] = ex; }
    __syncthreads();
    if (tid == SCAN_T-1) carry_s = carry + incl;
    __syncthreads();
  }
  if (tid == 0) row_ptr[n] = carry_s;
}

__global__ void fill_k(const int* __restrict__ src, const int* __restrict__ dst,
                       const float* __restrict__ ea, int E, int* __restrict__ cursor,
                       int* __restrict__ csr_src, float* __restrict__ csr_d){
  int e = blockIdx.x*blockDim.x + threadIdx.x;
  if (e < E){
    int p = atomicAdd(&cursor[dst[e]], 1);
    csr_src[p] = src[e];
    csr_d[p] = ea[e];
  }
}

// ---------------------------------------------------------------------------
// Node embedding: x @ W[6,128] + b  (fp32 out + bf16 copy)
// ---------------------------------------------------------------------------
__global__ void embed_k(const float* __restrict__ Xin, const float* __restrict__ W,
                        const float* __restrict__ b, float* __restrict__ Xout,
                        bf16* __restrict__ Xbf, int N){
  int idx = blockIdx.x*blockDim.x + threadIdx.x;
  if (idx >= N*H) return;
  int n = idx >> 7, c = idx & 127;
  float acc = b[c];
  #pragma unroll
  for (int k=0;k<6;k++) acc += Xin[n*6+k] * W[k*H+c];
  Xout[idx] = acc;
  Xbf[idx] = f2bf(acc);
}

// ---------------------------------------------------------------------------
// Table GEMM v3 (merged P+L): Out[M,N] = bf16(X@Wt^T + Bias), weights
// permuted-by-4 within 64-col groups -> each lane packs 4 adjacent cols and
// stores dwordx2 (128 B/row per store instruction).
// Block = 4 waves = one 16-row strip; wave w handles groups g = w, w+4, ...
// ---------------------------------------------------------------------------
__global__ void __launch_bounds__(256) gemm_tables(
    const bf16* __restrict__ Xp, const bf16* __restrict__ Wtp,
    const float* __restrict__ Biasp, bf16* __restrict__ Outp, int strips_p, int Np,
    const bf16* __restrict__ Xl, const bf16* __restrict__ Wtl,
    const float* __restrict__ Biasl, bf16* __restrict__ Outl, int Nl){
  int bid = blockIdx.x;
  const bf16 *X, *Wt; const float* Bias; bf16* Out; int N, strip;
  if (bid < strips_p){ X=Xp; Wt=Wtp; Bias=Biasp; Out=Outp; N=Np; strip=bid; }
  else               { X=Xl; Wt=Wtl; Bias=Biasl; Out=Outl; N=Nl; strip=bid-strips_p; }
  int m0 = strip << 4;
  int lane = threadIdx.x & 63;
  int wave = threadIdx.x >> 6;
  int lr = lane & 15, lq = lane >> 4;
  const bf16x8* A = (const bf16x8*)(const void*)(X + (size_t)(m0+lr)*H);
  bf16x8 a0 = A[0+lq], a1 = A[4+lq], a2 = A[8+lq], a3 = A[12+lq];
  int groups = N >> 6;
  for (int g = wave; g < groups; g += 4){
    int n0 = g << 6;
    f32x4 acc0 = {0.f,0.f,0.f,0.f}, acc1 = acc0, acc2 = acc0, acc3 = acc0;
    const bf16x8* B0 = (const bf16x8*)(const void*)(Wt + (size_t)(n0      + lr)*H);
    const bf16x8* B1 = (const bf16x8*)(const void*)(Wt + (size_t)(n0 + 16 + lr)*H);
    const bf16x8* B2 = (const bf16x8*)(const void*)(Wt + (size_t)(n0 + 32 + lr)*H);
    const bf16x8* B3 = (const bf16x8*)(const void*)(Wt + (size_t)(n0 + 48 + lr)*H);
    #pragma unroll
    for (int t=0;t<4;t++){
      bf16x8 a = (t==0)?a0:(t==1)?a1:(t==2)?a2:a3;
      acc0 = __builtin_amdgcn_mfma_f32_16x16x32_bf16(a, B0[t*4+lq], acc0, 0, 0, 0);
      acc1 = __builtin_amdgcn_mfma_f32_16x16x32_bf16(a, B1[t*4+lq], acc1, 0, 0, 0);
      acc2 = __builtin_amdgcn_mfma_f32_16x16x32_bf16(a, B2[t*4+lq], acc2, 0, 0, 0);
      acc3 = __builtin_amdgcn_mfma_f32_16x16x32_bf16(a, B3[t*4+lq], acc3, 0, 0, 0);
    }
    // lane lr holds logical cols n0+4lr+{0,1,2,3} in acc0..acc3
    float4 bias = ((const float4*)(const void*)(Bias + n0))[lr];
    #pragma unroll
    for (int r=0;r<4;r++){
      int row = m0 + lq*4 + r;
      uint2 pk;
      pk.x = pack_bf2(acc0[r] + bias.x, acc1[r] + bias.y);
      pk.y = pack_bf2(acc2[r] + bias.z, acc3[r] + bias.w);
      *(uint2*)(void*)(Out + (size_t)row*N + n0 + 4*lr) = pk;
    }
  }
}

// ---------------------------------------------------------------------------
// Node-update helpers
// ---------------------------------------------------------------------------
static __device__ __forceinline__ float act_msg(float f, float s){
  float sig = __builtin_amdgcn_rcpf(1.f + __expf(-f));
  float sp  = fmaxf(s, 0.f) + __logf(1.f + __expf(-fabsf(s)));
  return sig * sp;
}

#define BN_RSQ 0.9999950000374997f   /* 1/sqrt(1+1e-5) */

static __device__ __forceinline__ void edge2(uint2 g, uint4 t, float fr,
                                             float fd0, float sd0, float fd1, float sd1,
                                             float& acc0, float& acc1){
  float f0a = u2f_lo(t.x), s0a = u2f_hi(t.x), f1a = u2f_lo(t.y), s1a = u2f_hi(t.y);
  float f0b = u2f_lo(t.z), s0b = u2f_hi(t.z), f1b = u2f_lo(t.w), s1b = u2f_hi(t.w);
  float fa = fd0 + u2f_lo(g.x) + f0a + fr*(f1a-f0a);
  float sa = sd0 + u2f_hi(g.x) + s0a + fr*(s1a-s0a);
  float fb = fd1 + u2f_lo(g.y) + f0b + fr*(f1b-f0b);
  float sb = sd1 + u2f_hi(g.y) + s0b + fr*(s1b-s0b);
  acc0 += act_msg(fa, sa);
  acc1 += act_msg(fb, sb);
}

static __device__ __forceinline__ void ln_stats_w(float v0, float v1, float& mu, float& var){
  float s = v0 + v1, q = v0*v0 + v1*v1;
  #pragma unroll
  for (int o=32;o>=1;o>>=1){ s += __shfl_xor(s,o,64); q += __shfl_xor(q,o,64); }
  mu = s * (1.f/128.f);
  var = q * (1.f/128.f) - mu*mu;
}

static __device__ __forceinline__ void aggregate(
    const int* __restrict__ srcv, const float* __restrict__ dv,
    int e0, int e1,
    const uint2* __restrict__ G, int gstride, int goff,
    const uint4* __restrict__ Tb, int lane,
    float fd0, float sd0, float fd1, float sd1,
    float& acc0, float& acc1){
  int i = e0;
  for (; i+2 <= e1; i += 2){
    int sA = srcv[i],   sB = srcv[i+1];
    float dA = dv[i],   dB = dv[i+1];
    float bflA = dA * 128.0f, bflB = dB * 128.0f;
    int bA = (int)bflA; bA = (bA > 1023) ? 1023 : bA;
    int bB = (int)bflB; bB = (bB > 1023) ? 1023 : bB;
    float frA = bflA - (float)bA, frB = bflB - (float)bB;
    uint2 gA = G[(size_t)sA*gstride + goff + lane];
    uint2 gB = G[(size_t)sB*gstride + goff + lane];
    uint4 tA = Tb[(size_t)bA*64 + lane];
    uint4 tB = Tb[(size_t)bB*64 + lane];
    edge2(gA, tA, frA, fd0, sd0, fd1, sd1, acc0, acc1);
    edge2(gB, tB, frB, fd0, sd0, fd1, sd1, acc0, acc1);
  }
  if (i < e1){
    int s = srcv[i];
    float dd = dv[i];
    float bfl = dd * 128.0f;
    int b = (int)bfl; b = (b > 1023) ? 1023 : b;
    float fr = bfl - (float)b;
    uint2 g = G[(size_t)s*gstride + goff + lane];
    uint4 t = Tb[(size_t)b*64 + lane];
    edge2(g, t, fr, fd0, sd0, fd1, sd1, acc0, acc1);
  }
}

// ---------------------------------------------------------------------------
// Merged node update: wave per node. Blocks [0,PB) protein, [PB,PB+LB) ligand.
// ---------------------------------------------------------------------------
__global__ void __launch_bounds__(256) node_update(
    const bf16* __restrict__ PT, const bf16* __restrict__ LT,
    const float* __restrict__ xp, const float* __restrict__ xl,
    const int* __restrict__ pp_rp, const int* __restrict__ pp_src, const float* __restrict__ pp_d,
    const int* __restrict__ lp_rp, const int* __restrict__ lp_src, const float* __restrict__ lp_d,
    const int* __restrict__ pl_rp, const int* __restrict__ pl_src, const float* __restrict__ pl_d,
    const bf16* __restrict__ T2,
    const float* __restrict__ bn_w, const float* __restrict__ bn_b,
    const float* __restrict__ ln_w, const float* __restrict__ ln_b,
    float* __restrict__ xp_out, bf16* __restrict__ xp_bf,
    float* __restrict__ xl_out, bf16* __restrict__ xl_bf,
    int layer, int NP, int NL, int PB)
{
  int wave = threadIdx.x >> 6;
  int lane = threadIdx.x & 63;
  const uint2* PTg = (const uint2*)(const void*)PT;
  if ((int)blockIdx.x < PB){
    int node = blockIdx.x*4 + wave;
    if (node >= NP) return;
    float2 x = ((const float2*)(const void*)(xp + (size_t)node*H))[lane];
    const uint32* PTu = (const uint32*)(const void*)PT;
    const uint2*  LTg = (const uint2*)(const void*)LT;
    float o1_0, o1_1, o2_0, o2_1;
    { // relation pp
      int pr = layer*3 + 0;
      uint32 fdp = PTu[(size_t)node*512 + 256 + lane];
      uint32 sdp = PTu[(size_t)node*512 + 320 + lane];
      const uint4* Tb = (const uint4*)(const void*)(T2 + (size_t)pr*1025*512);
      float acc0 = 0.f, acc1 = 0.f;
      aggregate(pp_src, pp_d, pp_rp[node], pp_rp[node+1], PTg, 256, 0, Tb, lane,
                u2f_lo(fdp), u2f_lo(sdp), u2f_hi(fdp), u2f_hi(sdp), acc0, acc1);
      float2 bw = ((const float2*)(const void*)(bn_w + pr*H))[lane];
      float2 bb = ((const float2*)(const void*)(bn_b + pr*H))[lane];
      float2 lw = ((const float2*)(const void*)(ln_w + pr*H))[lane];
      float2 lb = ((const float2*)(const void*)(ln_b + pr*H))[lane];
      float v0 = acc0 * (bw.x * BN_RSQ) + bb.x + x.x;
      float v1 = acc1 * (bw.y * BN_RSQ) + bb.y + x.y;
      float mu, var; ln_stats_w(v0, v1, mu, var);
      float rs = rsqrtf(var + 1e-5f);
      o1_0 = fmaxf((v0-mu)*rs*lw.x + lb.x, 0.f) + x.x;
      o1_1 = fmaxf((v1-mu)*rs*lw.y + lb.y, 0.f) + x.y;
    }
    { // relation lp
      int pr = layer*3 + 1;
      uint32 fdp = PTu[(size_t)node*512 + 384 + lane];
      uint32 sdp = PTu[(size_t)node*512 + 448 + lane];
      const uint4* Tb = (const uint4*)(const void*)(T2 + (size_t)pr*1025*512);
      float acc0 = 0.f, acc1 = 0.f;
      aggregate(lp_src, lp_d, lp_rp[node], lp_rp[node+1], LTg, 128, 0, Tb, lane,
                u2f_lo(fdp), u2f_lo(sdp), u2f_hi(fdp), u2f_hi(sdp), acc0, acc1);
      float2 bw = ((const float2*)(const void*)(bn_w + pr*H))[lane];
      float2 bb = ((const float2*)(const void*)(bn_b + pr*H))[lane];
      float2 lw = ((const float2*)(const void*)(ln_w + pr*H))[lane];
      float2 lb = ((const float2*)(const void*)(ln_b + pr*H))[lane];
      float v0 = acc0 * (bw.x * BN_RSQ) + bb.x + x.x;
      float v1 = acc1 * (bw.y * BN_RSQ) + bb.y + x.y;
      float mu, var; ln_stats_w(v0, v1, mu, var);
      float rs = rsqrtf(var + 1e-5f);
      o2_0 = fmaxf((v0-mu)*rs*lw.x + lb.x, 0.f) + x.x;
      o2_1 = fmaxf((v1-mu)*rs*lw.y + lb.y, 0.f) + x.y;
    }
    float out0 = o1_0 + o2_0, out1 = o1_1 + o2_1;
    ((float2*)(void*)(xp_out + (size_t)node*H))[lane] = make_float2(out0, out1);
    ((uint32*)(void*)(xp_bf + (size_t)node*H))[lane] = pack_bf2(out0, out1);
  } else {
    int node = (blockIdx.x - PB)*4 + wave;
    if (node >= NL) return;
    float2 x = ((const float2*)(const void*)(xl + (size_t)node*H))[lane];
    const uint32* LTu = (const uint32*)(const void*)LT;
    int pr = layer*3 + 2;
    uint32 fdp = LTu[(size_t)node*256 + 128 + lane];
    uint32 sdp = LTu[(size_t)node*256 + 192 + lane];
    const uint4* Tb = (const uint4*)(const void*)(T2 + (size_t)pr*1025*512);
    float acc0 = 0.f, acc1 = 0.f;
    aggregate(pl_src, pl_d, pl_rp[node], pl_rp[node+1], PTg, 256, 64, Tb, lane,
              u2f_lo(fdp), u2f_lo(sdp), u2f_hi(fdp), u2f_hi(sdp), acc0, acc1);
    float2 bw = ((const float2*)(const void*)(bn_w + pr*H))[lane];
    float2 bb = ((const float2*)(const void*)(bn_b + pr*H))[lane];
    float2 lw = ((const float2*)(const void*)(ln_w + pr*H))[lane];
    float2 lb = ((const float2*)(const void*)(ln_b + pr*H))[lane];
    float v0 = acc0 * (bw.x * BN_RSQ) + bb.x + x.x;
    float v1 = acc1 * (bw.y * BN_RSQ) + bb.y + x.y;
    float mu, var; ln_stats_w(v0, v1, mu, var);
    float rs = rsqrtf(var + 1e-5f);
    float out0 = fmaxf((v0-mu)*rs*lw.x + lb.x, 0.f) + x.x;
    float out1 = fmaxf((v1-mu)*rs*lw.y + lb.y, 0.f) + x.y;
    ((float2*)(void*)(xl_out + (size_t)node*H))[lane] = make_float2(out0, out1);
    ((uint32*)(void*)(xl_bf + (size_t)node*H))[lane] = pack_bf2(out0, out1);
  }
}

// ---------------------------------------------------------------------------
// Final: LN(xp) @ fc_w[128,21] + fc_b
// ---------------------------------------------------------------------------
__global__ void __launch_bounds__(128) final_k(const float* __restrict__ xp,
    const float* __restrict__ lnw, const float* __restrict__ lnb,
    const float* __restrict__ fcw, const float* __restrict__ fcb,
    float* __restrict__ out, int N){
  __shared__ float sm[4];
  __shared__ float lnv[128];
  int node = blockIdx.x, c = threadIdx.x;
  float v = xp[(size_t)node*H + c];
  float s = v, q = v*v;
  #pragma unroll
  for (int o=32;o>=1;o>>=1){ s += __shfl_xor(s,o,64); q += __shfl_xor(q,o,64); }
  __syncthreads();
  if ((c & 63) == 0){ sm[(c>>6)*2] = s; sm[(c>>6)*2+1] = q; }
  __syncthreads();
  float S = sm[0] + sm[2], Q = sm[1] + sm[3];
  float mu = S * (1.f/128.f);
  float var = Q * (1.f/128.f) - mu*mu;
  float ln = (v-mu)*rsqrtf(var+1e-5f)*lnw[c] + lnb[c];
  lnv[c] = ln;
  __syncthreads();
  if (c < 21){
    float a = fcb[c];
    #pragma unroll 4
    for (int i=0;i<128;i++) a += lnv[i]*fcw[i*21+c];
    out[(size_t)node*21 + c] = a;
  }
}

// ---------------------------------------------------------------------------
extern "C" void kernel_launch(void* const* d_in, const int* in_sizes, int n_in,
                              void* d_out, int out_size, void* d_ws, size_t ws_size,
                              hipStream_t stream){
  const float* x_protein = (const float*)d_in[0];
  const float* x_ligand  = (const float*)d_in[1];
  const int*   ei_pp = (const int*)d_in[2];
  const float* ea_pp = (const float*)d_in[3];
  const int*   ei_lp = (const int*)d_in[4];
  const float* ea_lp = (const float*)d_in[5];
  const int*   ei_pl = (const int*)d_in[6];
  const float* ea_pl = (const float*)d_in[7];
  const float* Wp  = (const float*)d_in[8];
  const float* bp  = (const float*)d_in[9];
  const float* Wl  = (const float*)d_in[10];
  const float* bl  = (const float*)d_in[11];
  const float* Wf  = (const float*)d_in[12];
  const float* bfv = (const float*)d_in[13];
  const float* Wsv = (const float*)d_in[14];
  const float* bsv = (const float*)d_in[15];
  const float* bn_w = (const float*)d_in[16];
  const float* bn_b = (const float*)d_in[17];
  const float* ln_w = (const float*)d_in[18];
  const float* ln_b = (const float*)d_in[19];
  const float* lno_w = (const float*)d_in[20];
  const float* lno_b = (const float*)d_in[21];
  const float* fc_w = (const float*)d_in[22];
  const float* fc_b = (const float*)d_in[23];

  int NP  = in_sizes[0]/6, NL = in_sizes[1]/6;
  int EPP = in_sizes[3], ELP = in_sizes[5], EPL = in_sizes[7];

  char* ws = (char*)d_ws;
  size_t off = 0;
  auto alloc = [&](size_t bytes)->void*{
    void* p = ws + off; off = (off + bytes + 255) & ~(size_t)255; return p;
  };

  float* xpA = (float*)alloc((size_t)NP*H*4);
  float* xpB = (float*)alloc((size_t)NP*H*4);
  float* xlA = (float*)alloc((size_t)NL*H*4);
  float* xlB = (float*)alloc((size_t)NL*H*4);
  bf16* xp_bf = (bf16*)alloc((size_t)NP*H*2);
  bf16* xl_bf = (bf16*)alloc((size_t)NL*H*2);
  bf16* PT    = (bf16*)alloc((size_t)NP*1024*2);
  bf16* LT    = (bf16*)alloc((size_t)NL*512*2);
  bf16* Wt_p  = (bf16*)alloc((size_t)4*1024*H*2);
  bf16* Wt_l  = (bf16*)alloc((size_t)4*512*H*2);
  float* Bias_p = (float*)alloc((size_t)4*1024*4);
  float* Bias_l = (float*)alloc((size_t)4*512*4);
  bf16* T2    = (bf16*)alloc((size_t)12*1025*512*2);
  int* counts = (int*)alloc((size_t)(2*NP+NL)*4);
  int* rp_pp  = (int*)alloc((size_t)(NP+1)*4);
  int* cur_pp = (int*)alloc((size_t)NP*4);
  int* rp_lp  = (int*)alloc((size_t)(NP+1)*4);
  int* cur_lp = (int*)alloc((size_t)NP*4);
  int* rp_pl  = (int*)alloc((size_t)(NL+1)*4);
  int* cur_pl = (int*)alloc((size_t)NL*4);
  int*   csrc_pp = (int*)alloc((size_t)EPP*4);
  float* cd_pp   = (float*)alloc((size_t)EPP*4);
  int*   csrc_lp = (int*)alloc((size_t)ELP*4);
  float* cd_lp   = (float*)alloc((size_t)ELP*4);
  int*   csrc_pl = (int*)alloc((size_t)EPL*4);
  float* cd_pl   = (float*)alloc((size_t)EPL*4);
  (void)ws_size; (void)n_in; (void)out_size;

  // --- weight prep + RBF table ---
  prep_wp<<<(4*1024*128+255)/256, 256, 0, stream>>>(Wf, Wsv, bfv, bsv, Wt_p, Bias_p);
  prep_wl<<<(4*512*128+255)/256, 256, 0, stream>>>(Wf, Wsv, bfv, bsv, Wt_l, Bias_l);
  build_rbf_tab<<<(12*1025*128+255)/256, 256, 0, stream>>>(Wf, Wsv, T2);

  // --- CSR build ---
  hipMemsetAsync(counts, 0, (size_t)(2*NP+NL)*4, stream);
  int* cnt_pp = counts; int* cnt_lp = counts + NP; int* cnt_pl = counts + 2*NP;
  hist_k<<<(EPP+255)/256, 256, 0, stream>>>(ei_pp + EPP, EPP, cnt_pp);
  hist_k<<<(ELP+255)/256, 256, 0, stream>>>(ei_lp + ELP, ELP, cnt_lp);
  hist_k<<<(EPL+255)/256, 256, 0, stream>>>(ei_pl + EPL, EPL, cnt_pl);
  scan_k<<<1, SCAN_T, 0, stream>>>(cnt_pp, NP, rp_pp, cur_pp);
  scan_k<<<1, SCAN_T, 0, stream>>>(cnt_lp, NP, rp_lp, cur_lp);
  scan_k<<<1, SCAN_T, 0, stream>>>(cnt_pl, NL, rp_pl, cur_pl);
  fill_k<<<(EPP+255)/256, 256, 0, stream>>>(ei_pp, ei_pp + EPP, ea_pp, EPP, cur_pp, csrc_pp, cd_pp);
  fill_k<<<(ELP+255)/256, 256, 0, stream>>>(ei_lp, ei_lp + ELP, ea_lp, ELP, cur_lp, csrc_lp, cd_lp);
  fill_k<<<(EPL+255)/256, 256, 0, stream>>>(ei_pl, ei_pl + EPL, ea_pl, EPL, cur_pl, csrc_pl, cd_pl);

  // --- embeddings ---
  embed_k<<<((size_t)NP*H+255)/256, 256, 0, stream>>>(x_protein, Wp, bp, xpA, xp_bf, NP);
  embed_k<<<((size_t)NL*H+255)/256, 256, 0, stream>>>(x_ligand,  Wl, bl, xlA, xl_bf, NL);

  // --- layers ---
  float* xp_cur = xpA; float* xp_nxt = xpB;
  float* xl_cur = xlA; float* xl_nxt = xlB;
  int strips_p = NP >> 4, strips_l = NL >> 4;
  int PB = (NP + 3) / 4, LB = (NL + 3) / 4;
  for (int l=0; l<4; l++){
    gemm_tables<<<strips_p + strips_l, 256, 0, stream>>>(
        xp_bf, Wt_p + (size_t)l*1024*H, Bias_p + l*1024, PT, strips_p, 1024,
        xl_bf, Wt_l + (size_t)l*512*H,  Bias_l + l*512,  LT, 512);
    node_update<<<PB + LB, 256, 0, stream>>>(PT, LT, xp_cur, xl_cur,
        rp_pp, csrc_pp, cd_pp, rp_lp, csrc_lp, cd_lp, rp_pl, csrc_pl, cd_pl, T2,
        bn_w, bn_b, ln_w, ln_b, xp_nxt, xp_bf, xl_nxt, xl_bf, l, NP, NL, PB);
    float* t;
    t = xp_cur; xp_cur = xp_nxt; xp_nxt = t;
    t = xl_cur; xl_cur = xl_nxt; xl_nxt = t;
  }

  // --- output head ---
  final_k<<<NP, 128, 0, stream>>>(xp_cur, lno_w, lno_b, fc_w, fc_b, (float*)d_out, NP);
}

// Round 6
// 1194.211 us; speedup vs baseline: 2.6409x; 1.1815x over previous
//
#include <hip/hip_runtime.h>
#include <hip/hip_bf16.h>
#include <math.h>

#define H 128

typedef __bf16 bf16x8 __attribute__((ext_vector_type(8)));
typedef float f32x4 __attribute__((ext_vector_type(4)));
typedef float f32x2 __attribute__((ext_vector_type(2)));
typedef __hip_bfloat16 bf16;
typedef unsigned int uint32;

static __device__ __forceinline__ float bf2f(bf16 v){ return __bfloat162float(v); }
static __device__ __forceinline__ bf16 f2bf(float v){ return __float2bfloat16(v); }
static __device__ __forceinline__ float u2f_lo(uint32 v){ return __uint_as_float(v << 16); }
static __device__ __forceinline__ float u2f_hi(uint32 v){ return __uint_as_float(v & 0xffff0000u); }

union bfpack { struct { bf16 lo, hi; } h; uint32 u; };
static __device__ __forceinline__ uint32 pack_bf2(float a, float b){
  bfpack p; p.h.lo = f2bf(a); p.h.hi = f2bf(b); return p.u;
}

// ---------------------------------------------------------------------------
// Protein node-table layout PT[node][1024] (bf16):
//   [0,256)    pp-src interleaved pairs {f_c, s_c}
//   [256,512)  pl-src interleaved pairs {f_c, s_c}
//   [512,640)  pp f_dst (+bf)   [640,768)  pp s_dst (+bs)
//   [768,896)  lp f_dst (+bf)   [896,1024) lp s_dst (+bs)
// Ligand node-table LT[node][512]:
//   [0,256)    lp-src pairs     [256,384) pl f_dst (+bf)  [384,512) pl s_dst (+bs)
// Weights permuted within 64-col groups: storage row (base+16t+j) = logical (base+4j+t).
// RBF table (nearest-bin): T2[pr][b][4l..4l+3] = {f_{2l}, s_{2l}, f_{2l+1}, s_{2l+1}},
// 12 x 1025 x 512 B = 6.3 MB (per-layer slice 1.57 MB/3rel -> L2 resident).
// ---------------------------------------------------------------------------
static __device__ __forceinline__ int unperm64(int r){
  int base = r & ~63; int g = r & 63; int t = g >> 4; int j = g & 15;
  return base + 4*j + t;
}

#define PREP_WP_N (4*1024*128)
#define PREP_WL_N (4*512*128)
#define RBF_N     (12*1025*128)

__global__ void prep_all(const float* __restrict__ Wf, const float* __restrict__ Ws,
                         const float* __restrict__ bfv, const float* __restrict__ bsv,
                         bf16* __restrict__ Wt_p, float* __restrict__ Bias_p,
                         bf16* __restrict__ Wt_l, float* __restrict__ Bias_l,
                         bf16* __restrict__ T2){
  int t = blockIdx.x*blockDim.x + threadIdx.x;
  if (t < PREP_WP_N){
    int k = t & 127; int idx = t >> 7;
    int rs = idx & 1023; int l = idx >> 10;
    int r = unperm64(rs);
    int rel, c, row0; const float* W; float bias = 0.f;
    if (r < 256)      { rel=0; c=r>>1;        row0=128; W = (r&1)?Ws:Wf; }
    else if (r < 512) { rel=2; c=(r-256)>>1;  row0=128; W = (r&1)?Ws:Wf; }
    else if (r < 640) { rel=0; c=r-512; row0=0; W=Wf; bias = bfv[(l*3+rel)*H+c]; }
    else if (r < 768) { rel=0; c=r-640; row0=0; W=Ws; bias = bsv[(l*3+rel)*H+c]; }
    else if (r < 896) { rel=1; c=r-768; row0=0; W=Wf; bias = bfv[(l*3+rel)*H+c]; }
    else              { rel=1; c=r-896; row0=0; W=Ws; bias = bsv[(l*3+rel)*H+c]; }
    Wt_p[t] = f2bf(W[((size_t)(l*3+rel)*272 + row0 + k)*H + c]);
    if (k == 0) Bias_p[l*1024 + r] = bias;
    return;
  }
  t -= PREP_WP_N;
  if (t < PREP_WL_N){
    int k = t & 127; int idx = t >> 7;
    int rs = idx & 511; int l = idx >> 9;
    int r = unperm64(rs);
    int rel, c, row0; const float* W; float bias = 0.f;
    if (r < 256)      { rel=1; c=r>>1;   row0=128; W = (r&1)?Ws:Wf; }
    else if (r < 384) { rel=2; c=r-256; row0=0; W=Wf; bias = bfv[(l*3+rel)*H+c]; }
    else              { rel=2; c=r-384; row0=0; W=Ws; bias = bsv[(l*3+rel)*H+c]; }
    Wt_l[t] = f2bf(W[((size_t)(l*3+rel)*272 + row0 + k)*H + c]);
    if (k == 0) Bias_l[l*512 + r] = bias;
    return;
  }
  t -= PREP_WL_N;
  if (t < RBF_N){
    int c = t & 127;
    int b = (t >> 7) % 1025;
    int pr = t / (1025*128);
    float d0 = (float)b * 0.0078125f;
    const float* wf = Wf + ((size_t)pr*272 + 256)*H + c;
    const float* ws = Ws + ((size_t)pr*272 + 256)*H + c;
    float f0=0.f, s0=0.f;
    #pragma unroll
    for (int k=0;k<16;k++){
      float o = 0.533333333f*(float)k;
      float tt = d0 - o;
      float r0 = __expf(-1.7578125f*tt*tt);
      f0 += r0*wf[(size_t)k*H]; s0 += r0*ws[(size_t)k*H];
    }
    bf16* o = T2 + ((size_t)(pr*1025 + b))*256 + 2*c;
    o[0]=f2bf(f0); o[1]=f2bf(s0);
  }
}

// ---------------------------------------------------------------------------
// CSR build (merged)
// ---------------------------------------------------------------------------
__global__ void hist3_k(const int* __restrict__ dpp, int Epp,
                        const int* __restrict__ dlp, int Elp,
                        const int* __restrict__ dpl, int Epl,
                        int* __restrict__ cpp, int* __restrict__ clp, int* __restrict__ cpl){
  int e = blockIdx.x*blockDim.x + threadIdx.x;
  if (e < Epp) atomicAdd(&cpp[dpp[e]], 1);
  else if (e < Epp+Elp) atomicAdd(&clp[dlp[e-Epp]], 1);
  else if (e < Epp+Elp+Epl) atomicAdd(&cpl[dpl[e-Epp-Elp]], 1);
}

__global__ void fill3_k(const int* __restrict__ ei_pp, const float* __restrict__ ea_pp, int Epp,
                        const int* __restrict__ ei_lp, const float* __restrict__ ea_lp, int Elp,
                        const int* __restrict__ ei_pl, const float* __restrict__ ea_pl, int Epl,
                        int* __restrict__ cur_pp, int* __restrict__ s_pp, float* __restrict__ d_pp,
                        int* __restrict__ cur_lp, int* __restrict__ s_lp, float* __restrict__ d_lp,
                        int* __restrict__ cur_pl, int* __restrict__ s_pl, float* __restrict__ d_pl){
  int e = blockIdx.x*blockDim.x + threadIdx.x;
  if (e < Epp){
    int p = atomicAdd(&cur_pp[ei_pp[Epp + e]], 1);
    s_pp[p] = ei_pp[e]; d_pp[p] = ea_pp[e];
  } else if (e < Epp+Elp){
    int i = e - Epp;
    int p = atomicAdd(&cur_lp[ei_lp[Elp + i]], 1);
    s_lp[p] = ei_lp[i]; d_lp[p] = ea_lp[i];
  } else if (e < Epp+Elp+Epl){
    int i = e - Epp - Elp;
    int p = atomicAdd(&cur_pl[ei_pl[Epl + i]], 1);
    s_pl[p] = ei_pl[i]; d_pl[p] = ea_pl[i];
  }
}

// 3 independent block-scans (one per relation), wave-shuffle based.
__global__ void __launch_bounds__(1024) scan3_k(
    const int* __restrict__ counts, int NP, int NL,
    int* __restrict__ rp_pp, int* __restrict__ cur_pp,
    int* __restrict__ rp_lp, int* __restrict__ cur_lp,
    int* __restrict__ rp_pl, int* __restrict__ cur_pl){
  const int* cnt; int n; int* rp; int* cur;
  if (blockIdx.x == 0){ cnt = counts;        n = NP; rp = rp_pp; cur = cur_pp; }
  else if (blockIdx.x == 1){ cnt = counts+NP; n = NP; rp = rp_lp; cur = cur_lp; }
  else { cnt = counts+2*NP; n = NL; rp = rp_pl; cur = cur_pl; }
  __shared__ int wsum[16];
  __shared__ int carry_s;
  int tid = threadIdx.x, lane = tid & 63, wid = tid >> 6;
  if (tid == 0) carry_s = 0;
  __syncthreads();
  for (int base = 0; base < n; base += 1024){
    int i = base + tid;
    int v = (i < n) ? cnt[i] : 0;
    int x = v;
    #pragma unroll
    for (int o=1;o<64;o<<=1){
      int y = __shfl_up(x, o, 64);
      if (lane >= o) x += y;
    }
    if (lane == 63) wsum[wid] = x;
    __syncthreads();
    if (wid == 0 && lane < 16){
      int w = wsum[lane];
      #pragma unroll
      for (int o=1;o<16;o<<=1){
        int y = __shfl_up(w, o, 64);
        if (lane >= o) w += y;
      }
      wsum[lane] = w;
    }
    __syncthreads();
    int carry = carry_s;
    int waveoff = (wid == 0) ? 0 : wsum[wid-1];
    int incl = carry + waveoff + x;
    if (i < n){ int ex = incl - v; rp[i] = ex; cur[i] = ex; }
    __syncthreads();
    if (tid == 0) carry_s = carry + wsum[15];
    __syncthreads();
  }
  if (tid == 0) rp[n] = carry_s;
}

// ---------------------------------------------------------------------------
// Node embedding (merged): x @ W[6,128] + b
// ---------------------------------------------------------------------------
__global__ void embed2_k(const float* __restrict__ Xp, const float* __restrict__ Wp,
                         const float* __restrict__ bp, float* __restrict__ Xpo,
                         bf16* __restrict__ Xpb, int NP,
                         const float* __restrict__ Xl, const float* __restrict__ Wl,
                         const float* __restrict__ bl, float* __restrict__ Xlo,
                         bf16* __restrict__ Xlb, int NL){
  int idx = blockIdx.x*blockDim.x + threadIdx.x;
  const float* Xin; const float* W; const float* b; float* Xout; bf16* Xbf;
  if (idx < NP*H){ Xin=Xp; W=Wp; b=bp; Xout=Xpo; Xbf=Xpb; }
  else { idx -= NP*H; if (idx >= NL*H) return; Xin=Xl; W=Wl; b=bl; Xout=Xlo; Xbf=Xlb; }
  int n = idx >> 7, c = idx & 127;
  float acc = b[c];
  #pragma unroll
  for (int k=0;k<6;k++) acc += Xin[n*6+k] * W[k*H+c];
  Xout[idx] = acc;
  Xbf[idx] = f2bf(acc);
}

// ---------------------------------------------------------------------------
// Table GEMM (merged P+L), packed dwordx2 stores via permuted weights.
// ---------------------------------------------------------------------------
__global__ void __launch_bounds__(256) gemm_tables(
    const bf16* __restrict__ Xp, const bf16* __restrict__ Wtp,
    const float* __restrict__ Biasp, bf16* __restrict__ Outp, int strips_p, int Np,
    const bf16* __restrict__ Xl, const bf16* __restrict__ Wtl,
    const float* __restrict__ Biasl, bf16* __restrict__ Outl, int Nl){
  int bid = blockIdx.x;
  const bf16 *X, *Wt; const float* Bias; bf16* Out; int N, strip;
  if (bid < strips_p){ X=Xp; Wt=Wtp; Bias=Biasp; Out=Outp; N=Np; strip=bid; }
  else               { X=Xl; Wt=Wtl; Bias=Biasl; Out=Outl; N=Nl; strip=bid-strips_p; }
  int m0 = strip << 4;
  int lane = threadIdx.x & 63;
  int wave = threadIdx.x >> 6;
  int lr = lane & 15, lq = lane >> 4;
  const bf16x8* A = (const bf16x8*)(const void*)(X + (size_t)(m0+lr)*H);
  bf16x8 a0 = A[0+lq], a1 = A[4+lq], a2 = A[8+lq], a3 = A[12+lq];
  int groups = N >> 6;
  for (int g = wave; g < groups; g += 4){
    int n0 = g << 6;
    f32x4 acc0 = {0.f,0.f,0.f,0.f}, acc1 = acc0, acc2 = acc0, acc3 = acc0;
    const bf16x8* B0 = (const bf16x8*)(const void*)(Wt + (size_t)(n0      + lr)*H);
    const bf16x8* B1 = (const bf16x8*)(const void*)(Wt + (size_t)(n0 + 16 + lr)*H);
    const bf16x8* B2 = (const bf16x8*)(const void*)(Wt + (size_t)(n0 + 32 + lr)*H);
    const bf16x8* B3 = (const bf16x8*)(const void*)(Wt + (size_t)(n0 + 48 + lr)*H);
    #pragma unroll
    for (int t=0;t<4;t++){
      bf16x8 a = (t==0)?a0:(t==1)?a1:(t==2)?a2:a3;
      acc0 = __builtin_amdgcn_mfma_f32_16x16x32_bf16(a, B0[t*4+lq], acc0, 0, 0, 0);
      acc1 = __builtin_amdgcn_mfma_f32_16x16x32_bf16(a, B1[t*4+lq], acc1, 0, 0, 0);
      acc2 = __builtin_amdgcn_mfma_f32_16x16x32_bf16(a, B2[t*4+lq], acc2, 0, 0, 0);
      acc3 = __builtin_amdgcn_mfma_f32_16x16x32_bf16(a, B3[t*4+lq], acc3, 0, 0, 0);
    }
    float4 bias = ((const float4*)(const void*)(Bias + n0))[lr];
    #pragma unroll
    for (int r=0;r<4;r++){
      int row = m0 + lq*4 + r;
      uint2 pk;
      pk.x = pack_bf2(acc0[r] + bias.x, acc1[r] + bias.y);
      pk.y = pack_bf2(acc2[r] + bias.z, acc3[r] + bias.w);
      *(uint2*)(void*)(Out + (size_t)row*N + n0 + 4*lr) = pk;
    }
  }
}

// ---------------------------------------------------------------------------
// Node-update helpers
// ---------------------------------------------------------------------------
static __device__ __forceinline__ float act_msg(float f, float s){
  float sig = __builtin_amdgcn_rcpf(1.f + __expf(-f));
  float sp  = fmaxf(s, 0.f) + __logf(1.f + __expf(-fabsf(s)));
  return sig * sp;
}

#define BN_RSQ 0.9999950000374997f   /* 1/sqrt(1+1e-5) */

static __device__ __forceinline__ void edge_nb(uint2 g, uint2 t,
                                               f32x2 fd2, f32x2 sd2, f32x2& acc){
  f32x2 f2, s2;
  f2.x = u2f_lo(g.x) + u2f_lo(t.x);
  f2.y = u2f_lo(g.y) + u2f_lo(t.y);
  s2.x = u2f_hi(g.x) + u2f_hi(t.x);
  s2.y = u2f_hi(g.y) + u2f_hi(t.y);
  f2 += fd2; s2 += sd2;
  acc.x += act_msg(f2.x, s2.x);
  acc.y += act_msg(f2.y, s2.y);
}

static __device__ __forceinline__ void ln_stats_w(float v0, float v1, float& mu, float& var){
  float s = v0 + v1, q = v0*v0 + v1*v1;
  #pragma unroll
  for (int o=32;o>=1;o>>=1){ s += __shfl_xor(s,o,64); q += __shfl_xor(q,o,64); }
  mu = s * (1.f/128.f);
  var = q * (1.f/128.f) - mu*mu;
}

// depth-2 software-pipelined CSR aggregation (nearest-bin RBF)
static __device__ __forceinline__ void aggregate(
    const int* __restrict__ srcv, const float* __restrict__ dv,
    int e0, int e1,
    const uint2* __restrict__ G, int gstride, int goff,
    const uint2* __restrict__ Tb, int lane,
    f32x2 fd2, f32x2 sd2, f32x2& acc)
{
  if (e0 >= e1) return;
  uint2 gA, tA, gB, tB;
  #define LOADE(gX, tX, idx) { \
    int s_ = __builtin_amdgcn_readfirstlane(srcv[idx]); \
    float d_ = dv[idx]; \
    float bf_ = __fmaf_rn(d_, 128.f, 0.5f); \
    int b_ = (int)bf_; b_ = (b_ > 1024) ? 1024 : b_; \
    b_ = __builtin_amdgcn_readfirstlane(b_); \
    gX = G[(size_t)s_*gstride + goff + lane]; \
    tX = Tb[(size_t)b_*64 + lane]; }
  LOADE(gA, tA, e0);
  bool twoPlus = (e0+1 < e1);
  if (twoPlus) LOADE(gB, tB, e0+1);
  int i = e0;
  for (; i+2 < e1; i++){
    uint2 gC, tC;
    LOADE(gC, tC, i+2);
    edge_nb(gA, tA, fd2, sd2, acc);
    gA = gB; tA = tB; gB = gC; tB = tC;
  }
  edge_nb(gA, tA, fd2, sd2, acc);
  if (twoPlus) edge_nb(gB, tB, fd2, sd2, acc);
  #undef LOADE
}

// ---------------------------------------------------------------------------
// Merged node update: wave per node. Blocks [0,PB) protein, rest ligand.
// ---------------------------------------------------------------------------
__global__ void __launch_bounds__(256) node_update(
    const bf16* __restrict__ PT, const bf16* __restrict__ LT,
    const float* __restrict__ xp, const float* __restrict__ xl,
    const int* __restrict__ pp_rp, const int* __restrict__ pp_src, const float* __restrict__ pp_d,
    const int* __restrict__ lp_rp, const int* __restrict__ lp_src, const float* __restrict__ lp_d,
    const int* __restrict__ pl_rp, const int* __restrict__ pl_src, const float* __restrict__ pl_d,
    const bf16* __restrict__ T2,
    const float* __restrict__ bn_w, const float* __restrict__ bn_b,
    const float* __restrict__ ln_w, const float* __restrict__ ln_b,
    float* __restrict__ xp_out, bf16* __restrict__ xp_bf,
    float* __restrict__ xl_out, bf16* __restrict__ xl_bf,
    int layer, int NP, int NL, int PB)
{
  int wave = threadIdx.x >> 6;
  int lane = threadIdx.x & 63;
  const uint2* PTg = (const uint2*)(const void*)PT;
  if ((int)blockIdx.x < PB){
    int node = blockIdx.x*4 + wave;
    if (node >= NP) return;
    float2 x = ((const float2*)(const void*)(xp + (size_t)node*H))[lane];
    const uint32* PTu = (const uint32*)(const void*)PT;
    const uint2*  LTg = (const uint2*)(const void*)LT;
    float o1_0, o1_1, o2_0, o2_1;
    { // relation pp
      int pr = layer*3 + 0;
      uint32 fdp = PTu[(size_t)node*512 + 256 + lane];
      uint32 sdp = PTu[(size_t)node*512 + 320 + lane];
      const uint2* Tb = (const uint2*)(const void*)(T2 + (size_t)pr*1025*256);
      f32x2 fd2 = {u2f_lo(fdp), u2f_hi(fdp)};
      f32x2 sd2 = {u2f_lo(sdp), u2f_hi(sdp)};
      f32x2 acc = {0.f, 0.f};
      aggregate(pp_src, pp_d, pp_rp[node], pp_rp[node+1], PTg, 256, 0, Tb, lane, fd2, sd2, acc);
      float2 bw = ((const float2*)(const void*)(bn_w + pr*H))[lane];
      float2 bb = ((const float2*)(const void*)(bn_b + pr*H))[lane];
      float2 lw = ((const float2*)(const void*)(ln_w + pr*H))[lane];
      float2 lb = ((const float2*)(const void*)(ln_b + pr*H))[lane];
      float v0 = acc.x * (bw.x * BN_RSQ) + bb.x + x.x;
      float v1 = acc.y * (bw.y * BN_RSQ) + bb.y + x.y;
      float mu, var; ln_stats_w(v0, v1, mu, var);
      float rs = rsqrtf(var + 1e-5f);
      o1_0 = fmaxf((v0-mu)*rs*lw.x + lb.x, 0.f) + x.x;
      o1_1 = fmaxf((v1-mu)*rs*lw.y + lb.y, 0.f) + x.y;
    }
    { // relation lp
      int pr = layer*3 + 1;
      uint32 fdp = PTu[(size_t)node*512 + 384 + lane];
      uint32 sdp = PTu[(size_t)node*512 + 448 + lane];
      const uint2* Tb = (const uint2*)(const void*)(T2 + (size_t)pr*1025*256);
      f32x2 fd2 = {u2f_lo(fdp), u2f_hi(fdp)};
      f32x2 sd2 = {u2f_lo(sdp), u2f_hi(sdp)};
      f32x2 acc = {0.f, 0.f};
      aggregate(lp_src, lp_d, lp_rp[node], lp_rp[node+1], LTg, 128, 0, Tb, lane, fd2, sd2, acc);
      float2 bw = ((const float2*)(const void*)(bn_w + pr*H))[lane];
      float2 bb = ((const float2*)(const void*)(bn_b + pr*H))[lane];
      float2 lw = ((const float2*)(const void*)(ln_w + pr*H))[lane];
      float2 lb = ((const float2*)(const void*)(ln_b + pr*H))[lane];
      float v0 = acc.x * (bw.x * BN_RSQ) + bb.x + x.x;
      float v1 = acc.y * (bw.y * BN_RSQ) + bb.y + x.y;
      float mu, var; ln_stats_w(v0, v1, mu, var);
      float rs = rsqrtf(var + 1e-5f);
      o2_0 = fmaxf((v0-mu)*rs*lw.x + lb.x, 0.f) + x.x;
      o2_1 = fmaxf((v1-mu)*rs*lw.y + lb.y, 0.f) + x.y;
    }
    float out0 = o1_0 + o2_0, out1 = o1_1 + o2_1;
    ((float2*)(void*)(xp_out + (size_t)node*H))[lane] = make_float2(out0, out1);
    ((uint32*)(void*)(xp_bf + (size_t)node*H))[lane] = pack_bf2(out0, out1);
  } else {
    int node = (blockIdx.x - PB)*4 + wave;
    if (node >= NL) return;
    float2 x = ((const float2*)(const void*)(xl + (size_t)node*H))[lane];
    const uint32* LTu = (const uint32*)(const void*)LT;
    int pr = layer*3 + 2;
    uint32 fdp = LTu[(size_t)node*256 + 128 + lane];
    uint32 sdp = LTu[(size_t)node*256 + 192 + lane];
    const uint2* Tb = (const uint2*)(const void*)(T2 + (size_t)pr*1025*256);
    f32x2 fd2 = {u2f_lo(fdp), u2f_hi(fdp)};
    f32x2 sd2 = {u2f_lo(sdp), u2f_hi(sdp)};
    f32x2 acc = {0.f, 0.f};
    aggregate(pl_src, pl_d, pl_rp[node], pl_rp[node+1], PTg, 256, 64, Tb, lane, fd2, sd2, acc);
    float2 bw = ((const float2*)(const void*)(bn_w + pr*H))[lane];
    float2 bb = ((const float2*)(const void*)(bn_b + pr*H))[lane];
    float2 lw = ((const float2*)(const void*)(ln_w + pr*H))[lane];
    float2 lb = ((const float2*)(const void*)(ln_b + pr*H))[lane];
    float v0 = acc.x * (bw.x * BN_RSQ) + bb.x + x.x;
    float v1 = acc.y * (bw.y * BN_RSQ) + bb.y + x.y;
    float mu, var; ln_stats_w(v0, v1, mu, var);
    float rs = rsqrtf(var + 1e-5f);
    float out0 = fmaxf((v0-mu)*rs*lw.x + lb.x, 0.f) + x.x;
    float out1 = fmaxf((v1-mu)*rs*lw.y + lb.y, 0.f) + x.y;
    ((float2*)(void*)(xl_out + (size_t)node*H))[lane] = make_float2(out0, out1);
    ((uint32*)(void*)(xl_bf + (size_t)node*H))[lane] = pack_bf2(out0, out1);
  }
}

// ---------------------------------------------------------------------------
// Final: LN(xp) @ fc_w[128,21] + fc_b
// ---------------------------------------------------------------------------
__global__ void __launch_bounds__(128) final_k(const float* __restrict__ xp,
    const float* __restrict__ lnw, const float* __restrict__ lnb,
    const float* __restrict__ fcw, const float* __restrict__ fcb,
    float* __restrict__ out, int N){
  __shared__ float sm[4];
  __shared__ float lnv[128];
  int node = blockIdx.x, c = threadIdx.x;
  float v = xp[(size_t)node*H + c];
  float s = v, q = v*v;
  #pragma unroll
  for (int o=32;o>=1;o>>=1){ s += __shfl_xor(s,o,64); q += __shfl_xor(q,o,64); }
  __syncthreads();
  if ((c & 63) == 0){ sm[(c>>6)*2] = s; sm[(c>>6)*2+1] = q; }
  __syncthreads();
  float S = sm[0] + sm[2], Q = sm[1] + sm[3];
  float mu = S * (1.f/128.f);
  float var = Q * (1.f/128.f) - mu*mu;
  float ln = (v-mu)*rsqrtf(var+1e-5f)*lnw[c] + lnb[c];
  lnv[c] = ln;
  __syncthreads();
  if (c < 21){
    float a = fcb[c];
    #pragma unroll 4
    for (int i=0;i<128;i++) a += lnv[i]*fcw[i*21+c];
    out[(size_t)node*21 + c] = a;
  }
}

// ---------------------------------------------------------------------------
extern "C" void kernel_launch(void* const* d_in, const int* in_sizes, int n_in,
                              void* d_out, int out_size, void* d_ws, size_t ws_size,
                              hipStream_t stream){
  const float* x_protein = (const float*)d_in[0];
  const float* x_ligand  = (const float*)d_in[1];
  const int*   ei_pp = (const int*)d_in[2];
  const float* ea_pp = (const float*)d_in[3];
  const int*   ei_lp = (const int*)d_in[4];
  const float* ea_lp = (const float*)d_in[5];
  const int*   ei_pl = (const int*)d_in[6];
  const float* ea_pl = (const float*)d_in[7];
  const float* Wp  = (const float*)d_in[8];
  const float* bp  = (const float*)d_in[9];
  const float* Wl  = (const float*)d_in[10];
  const float* bl  = (const float*)d_in[11];
  const float* Wf  = (const float*)d_in[12];
  const float* bfv = (const float*)d_in[13];
  const float* Wsv = (const float*)d_in[14];
  const float* bsv = (const float*)d_in[15];
  const float* bn_w = (const float*)d_in[16];
  const float* bn_b = (const float*)d_in[17];
  const float* ln_w = (const float*)d_in[18];
  const float* ln_b = (const float*)d_in[19];
  const float* lno_w = (const float*)d_in[20];
  const float* lno_b = (const float*)d_in[21];
  const float* fc_w = (const float*)d_in[22];
  const float* fc_b = (const float*)d_in[23];

  int NP  = in_sizes[0]/6, NL = in_sizes[1]/6;
  int EPP = in_sizes[3], ELP = in_sizes[5], EPL = in_sizes[7];

  char* ws = (char*)d_ws;
  size_t off = 0;
  auto alloc = [&](size_t bytes)->void*{
    void* p = ws + off; off = (off + bytes + 255) & ~(size_t)255; return p;
  };

  float* xpA = (float*)alloc((size_t)NP*H*4);
  float* xpB = (float*)alloc((size_t)NP*H*4);
  float* xlA = (float*)alloc((size_t)NL*H*4);
  float* xlB = (float*)alloc((size_t)NL*H*4);
  bf16* xp_bf = (bf16*)alloc((size_t)NP*H*2);
  bf16* xl_bf = (bf16*)alloc((size_t)NL*H*2);
  bf16* PT    = (bf16*)alloc((size_t)NP*1024*2);
  bf16* LT    = (bf16*)alloc((size_t)NL*512*2);
  bf16* Wt_p  = (bf16*)alloc((size_t)4*1024*H*2);
  bf16* Wt_l  = (bf16*)alloc((size_t)4*512*H*2);
  float* Bias_p = (float*)alloc((size_t)4*1024*4);
  float* Bias_l = (float*)alloc((size_t)4*512*4);
  bf16* T2    = (bf16*)alloc((size_t)12*1025*256*2);
  int* counts = (int*)alloc((size_t)(2*NP+NL)*4);
  int* rp_pp  = (int*)alloc((size_t)(NP+1)*4);
  int* cur_pp = (int*)alloc((size_t)NP*4);
  int* rp_lp  = (int*)alloc((size_t)(NP+1)*4);
  int* cur_lp = (int*)alloc((size_t)NP*4);
  int* rp_pl  = (int*)alloc((size_t)(NL+1)*4);
  int* cur_pl = (int*)alloc((size_t)NL*4);
  int*   csrc_pp = (int*)alloc((size_t)EPP*4);
  float* cd_pp   = (float*)alloc((size_t)EPP*4);
  int*   csrc_lp = (int*)alloc((size_t)ELP*4);
  float* cd_lp   = (float*)alloc((size_t)ELP*4);
  int*   csrc_pl = (int*)alloc((size_t)EPL*4);
  float* cd_pl   = (float*)alloc((size_t)EPL*4);
  (void)ws_size; (void)n_in; (void)out_size;

  // --- prep (weights + RBF table), CSR hist ---
  int prep_total = PREP_WP_N + PREP_WL_N + RBF_N;
  prep_all<<<(prep_total+255)/256, 256, 0, stream>>>(Wf, Wsv, bfv, bsv,
                                                     Wt_p, Bias_p, Wt_l, Bias_l, T2);
  hipMemsetAsync(counts, 0, (size_t)(2*NP+NL)*4, stream);
  int* cnt_pp = counts; int* cnt_lp = counts + NP; int* cnt_pl = counts + 2*NP;
  int Etot = EPP + ELP + EPL;
  hist3_k<<<(Etot+255)/256, 256, 0, stream>>>(ei_pp+EPP, EPP, ei_lp+ELP, ELP, ei_pl+EPL, EPL,
                                              cnt_pp, cnt_lp, cnt_pl);
  scan3_k<<<3, 1024, 0, stream>>>(counts, NP, NL, rp_pp, cur_pp, rp_lp, cur_lp, rp_pl, cur_pl);
  fill3_k<<<(Etot+255)/256, 256, 0, stream>>>(ei_pp, ea_pp, EPP, ei_lp, ea_lp, ELP,
                                              ei_pl, ea_pl, EPL,
                                              cur_pp, csrc_pp, cd_pp,
                                              cur_lp, csrc_lp, cd_lp,
                                              cur_pl, csrc_pl, cd_pl);

  // --- embeddings ---
  embed2_k<<<(((size_t)(NP+NL)*H)+255)/256, 256, 0, stream>>>(
      x_protein, Wp, bp, xpA, xp_bf, NP, x_ligand, Wl, bl, xlA, xl_bf, NL);

  // --- layers ---
  float* xp_cur = xpA; float* xp_nxt = xpB;
  float* xl_cur = xlA; float* xl_nxt = xlB;
  int strips_p = NP >> 4, strips_l = NL >> 4;
  int PB = (NP + 3) / 4, LB = (NL + 3) / 4;
  for (int l=0; l<4; l++){
    gemm_tables<<<strips_p + strips_l, 256, 0, stream>>>(
        xp_bf, Wt_p + (size_t)l*1024*H, Bias_p + l*1024, PT, strips_p, 1024,
        xl_bf, Wt_l + (size_t)l*512*H,  Bias_l + l*512,  LT, 512);
    node_update<<<PB + LB, 256, 0, stream>>>(PT, LT, xp_cur, xl_cur,
        rp_pp, csrc_pp, cd_pp, rp_lp, csrc_lp, cd_lp, rp_pl, csrc_pl, cd_pl, T2,
        bn_w, bn_b, ln_w, ln_b, xp_nxt, xp_bf, xl_nxt, xl_bf, l, NP, NL, PB);
    float* t;
    t = xp_cur; xp_cur = xp_nxt; xp_nxt = t;
    t = xl_cur; xl_cur = xl_nxt; xl_nxt = t;
  }

  // --- output head ---
  final_k<<<NP, 128, 0, stream>>>(xp_cur, lno_w, lno_b, fc_w, fc_b, (float*)d_out, NP);
}

// Round 7
// 914.123 us; speedup vs baseline: 3.4500x; 1.3064x over previous
//
#include <hip/hip_runtime.h>
#include <hip/hip_bf16.h>
#include <math.h>

#define H 128

typedef __bf16 bf16x8 __attribute__((ext_vector_type(8)));
typedef float f32x4 __attribute__((ext_vector_type(4)));
typedef float f32x2 __attribute__((ext_vector_type(2)));
typedef __hip_bfloat16 bf16;
typedef unsigned int uint32;

static __device__ __forceinline__ float bf2f(bf16 v){ return __bfloat162float(v); }
static __device__ __forceinline__ bf16 f2bf(float v){ return __float2bfloat16(v); }
static __device__ __forceinline__ float u2f_lo(uint32 v){ return __uint_as_float(v << 16); }
static __device__ __forceinline__ float u2f_hi(uint32 v){ return __uint_as_float(v & 0xffff0000u); }

union bfpack { struct { bf16 lo, hi; } h; uint32 u; };
static __device__ __forceinline__ uint32 pack_bf2(float a, float b){
  bfpack p; p.h.lo = f2bf(a); p.h.hi = f2bf(b); return p.u;
}

// ---------------------------------------------------------------------------
// Table layouts: see R5/R6 comments (PT[node][1024], LT[node][512], weights
// permuted within 64-col groups, nearest-bin RBF table T2[pr][1025][256]).
// ---------------------------------------------------------------------------
static __device__ __forceinline__ int unperm64(int r){
  int base = r & ~63; int g = r & 63; int t = g >> 4; int j = g & 15;
  return base + 4*j + t;
}

#define PREP_WP_N (4*1024*128)
#define PREP_WL_N (4*512*128)
#define RBF_N     (12*1025*128)

__global__ void prep_all(const float* __restrict__ Wf, const float* __restrict__ Ws,
                         const float* __restrict__ bfv, const float* __restrict__ bsv,
                         bf16* __restrict__ Wt_p, float* __restrict__ Bias_p,
                         bf16* __restrict__ Wt_l, float* __restrict__ Bias_l,
                         bf16* __restrict__ T2){
  int t = blockIdx.x*blockDim.x + threadIdx.x;
  if (t < PREP_WP_N){
    int k = t & 127; int idx = t >> 7;
    int rs = idx & 1023; int l = idx >> 10;
    int r = unperm64(rs);
    int rel, c, row0; const float* W; float bias = 0.f;
    if (r < 256)      { rel=0; c=r>>1;        row0=128; W = (r&1)?Ws:Wf; }
    else if (r < 512) { rel=2; c=(r-256)>>1;  row0=128; W = (r&1)?Ws:Wf; }
    else if (r < 640) { rel=0; c=r-512; row0=0; W=Wf; bias = bfv[(l*3+rel)*H+c]; }
    else if (r < 768) { rel=0; c=r-640; row0=0; W=Ws; bias = bsv[(l*3+rel)*H+c]; }
    else if (r < 896) { rel=1; c=r-768; row0=0; W=Wf; bias = bfv[(l*3+rel)*H+c]; }
    else              { rel=1; c=r-896; row0=0; W=Ws; bias = bsv[(l*3+rel)*H+c]; }
    Wt_p[t] = f2bf(W[((size_t)(l*3+rel)*272 + row0 + k)*H + c]);
    if (k == 0) Bias_p[l*1024 + r] = bias;
    return;
  }
  t -= PREP_WP_N;
  if (t < PREP_WL_N){
    int k = t & 127; int idx = t >> 7;
    int rs = idx & 511; int l = idx >> 9;
    int r = unperm64(rs);
    int rel, c, row0; const float* W; float bias = 0.f;
    if (r < 256)      { rel=1; c=r>>1;   row0=128; W = (r&1)?Ws:Wf; }
    else if (r < 384) { rel=2; c=r-256; row0=0; W=Wf; bias = bfv[(l*3+rel)*H+c]; }
    else              { rel=2; c=r-384; row0=0; W=Ws; bias = bsv[(l*3+rel)*H+c]; }
    Wt_l[t] = f2bf(W[((size_t)(l*3+rel)*272 + row0 + k)*H + c]);
    if (k == 0) Bias_l[l*512 + r] = bias;
    return;
  }
  t -= PREP_WL_N;
  if (t < RBF_N){
    int c = t & 127;
    int b = (t >> 7) % 1025;
    int pr = t / (1025*128);
    float d0 = (float)b * 0.0078125f;
    const float* wf = Wf + ((size_t)pr*272 + 256)*H + c;
    const float* ws = Ws + ((size_t)pr*272 + 256)*H + c;
    float f0=0.f, s0=0.f;
    #pragma unroll
    for (int k=0;k<16;k++){
      float o = 0.533333333f*(float)k;
      float tt = d0 - o;
      float r0 = __expf(-1.7578125f*tt*tt);
      f0 += r0*wf[(size_t)k*H]; s0 += r0*ws[(size_t)k*H];
    }
    bf16* o = T2 + ((size_t)(pr*1025 + b))*256 + 2*c;
    o[0]=f2bf(f0); o[1]=f2bf(s0);
  }
}

// ---------------------------------------------------------------------------
// CSR build: hist -> chunk sums -> mid scan -> final scan -> fill
// ---------------------------------------------------------------------------
__global__ void hist3_k(const int* __restrict__ dpp, int Epp,
                        const int* __restrict__ dlp, int Elp,
                        const int* __restrict__ dpl, int Epl,
                        int* __restrict__ cpp, int* __restrict__ clp, int* __restrict__ cpl){
  int e = blockIdx.x*blockDim.x + threadIdx.x;
  if (e < Epp) atomicAdd(&cpp[dpp[e]], 1);
  else if (e < Epp+Elp) atomicAdd(&clp[dlp[e-Epp]], 1);
  else if (e < Epp+Elp+Epl) atomicAdd(&cpl[dpl[e-Epp-Elp]], 1);
}

#define SCH 1024   // scan chunk size

// per-chunk sums; chsum laid out [Cpp | Clp | Cpl]
__global__ void __launch_bounds__(256) chunksum_k(
    const int* __restrict__ counts, int NP, int NL, int Cpp, int Cpl,
    int* __restrict__ chsum){
  __shared__ int wred[4];
  int b = blockIdx.x;
  const int* cnt; int n; int ch;
  if (b < Cpp){ cnt = counts; n = NP; ch = b; }
  else if (b < 2*Cpp){ cnt = counts + NP; n = NP; ch = b - Cpp; }
  else { cnt = counts + 2*NP; n = NL; ch = b - 2*Cpp; }
  int base = ch * SCH;
  int tid = threadIdx.x;
  int s = 0;
  #pragma unroll
  for (int j=0;j<SCH/256;j++){
    int i = base + tid + j*256;
    if (i < n) s += cnt[i];
  }
  #pragma unroll
  for (int o=32;o>=1;o>>=1) s += __shfl_xor(s,o,64);
  if ((tid & 63) == 0) wred[tid>>6] = s;
  __syncthreads();
  if (tid == 0) chsum[b] = wred[0]+wred[1]+wred[2]+wred[3];
}

// one wave per relation scans its chunk sums (assumes <=64 chunks/relation)
__global__ void __launch_bounds__(192) scanmid_k(
    int* __restrict__ chsum, int Cpp, int Cpl, int NP, int NL,
    int* __restrict__ rp_pp, int* __restrict__ rp_lp, int* __restrict__ rp_pl){
  int wid = threadIdx.x >> 6, lane = threadIdx.x & 63;
  int C, off; int* rp_end; int n;
  if (wid == 0){ C = Cpp; off = 0;      rp_end = rp_pp; n = NP; }
  else if (wid == 1){ C = Cpp; off = Cpp; rp_end = rp_lp; n = NP; }
  else { C = Cpl; off = 2*Cpp; rp_end = rp_pl; n = NL; }
  int v = (lane < C) ? chsum[off + lane] : 0;
  int x = v;
  #pragma unroll
  for (int o=1;o<64;o<<=1){
    int y = __shfl_up(x, o, 64);
    if (lane >= o) x += y;
  }
  if (lane < C) chsum[off + lane] = x - v;   // exclusive
  if (lane == 63) rp_end[n] = x;             // total
}

// re-scan each chunk with chunk offset, write rp & cur
__global__ void __launch_bounds__(1024) scanfin_k(
    const int* __restrict__ counts, int NP, int NL, int Cpp, int Cpl,
    const int* __restrict__ chsum,
    int* __restrict__ rp_pp, int* __restrict__ cur_pp,
    int* __restrict__ rp_lp, int* __restrict__ cur_lp,
    int* __restrict__ rp_pl, int* __restrict__ cur_pl){
  __shared__ int wsum[16];
  int b = blockIdx.x;
  const int* cnt; int n, ch; int* rp; int* cur;
  if (b < Cpp){ cnt = counts; n = NP; ch = b; rp = rp_pp; cur = cur_pp; }
  else if (b < 2*Cpp){ cnt = counts + NP; n = NP; ch = b - Cpp; rp = rp_lp; cur = cur_lp; }
  else { cnt = counts + 2*NP; n = NL; ch = b - 2*Cpp; rp = rp_pl; cur = cur_pl; }
  int tid = threadIdx.x, lane = tid & 63, wid = tid >> 6;
  int i = ch*SCH + tid;
  int v = (i < n) ? cnt[i] : 0;
  int x = v;
  #pragma unroll
  for (int o=1;o<64;o<<=1){
    int y = __shfl_up(x, o, 64);
    if (lane >= o) x += y;
  }
  if (lane == 63) wsum[wid] = x;
  __syncthreads();
  if (wid == 0 && lane < 16){
    int w = wsum[lane];
    #pragma unroll
    for (int o=1;o<16;o<<=1){
      int y = __shfl_up(w, o, 64);
      if (lane >= o) w += y;
    }
    wsum[lane] = w;
  }
  __syncthreads();
  int waveoff = (wid == 0) ? 0 : wsum[wid-1];
  int ex = chsum[b] + waveoff + x - v;
  if (i < n){ rp[i] = ex; cur[i] = ex; }
}

__global__ void fill3_k(const int* __restrict__ ei_pp, const float* __restrict__ ea_pp, int Epp,
                        const int* __restrict__ ei_lp, const float* __restrict__ ea_lp, int Elp,
                        const int* __restrict__ ei_pl, const float* __restrict__ ea_pl, int Epl,
                        int* __restrict__ cur_pp, int* __restrict__ s_pp, float* __restrict__ d_pp,
                        int* __restrict__ cur_lp, int* __restrict__ s_lp, float* __restrict__ d_lp,
                        int* __restrict__ cur_pl, int* __restrict__ s_pl, float* __restrict__ d_pl){
  int e = blockIdx.x*blockDim.x + threadIdx.x;
  if (e < Epp){
    int p = atomicAdd(&cur_pp[ei_pp[Epp + e]], 1);
    s_pp[p] = ei_pp[e]; d_pp[p] = ea_pp[e];
  } else if (e < Epp+Elp){
    int i = e - Epp;
    int p = atomicAdd(&cur_lp[ei_lp[Elp + i]], 1);
    s_lp[p] = ei_lp[i]; d_lp[p] = ea_lp[i];
  } else if (e < Epp+Elp+Epl){
    int i = e - Epp - Elp;
    int p = atomicAdd(&cur_pl[ei_pl[Epl + i]], 1);
    s_pl[p] = ei_pl[i]; d_pl[p] = ea_pl[i];
  }
}

// ---------------------------------------------------------------------------
// Node embedding (merged): x @ W[6,128] + b
// ---------------------------------------------------------------------------
__global__ void embed2_k(const float* __restrict__ Xp, const float* __restrict__ Wp,
                         const float* __restrict__ bp, float* __restrict__ Xpo,
                         bf16* __restrict__ Xpb, int NP,
                         const float* __restrict__ Xl, const float* __restrict__ Wl,
                         const float* __restrict__ bl, float* __restrict__ Xlo,
                         bf16* __restrict__ Xlb, int NL){
  int idx = blockIdx.x*blockDim.x + threadIdx.x;
  const float* Xin; const float* W; const float* b; float* Xout; bf16* Xbf;
  if (idx < NP*H){ Xin=Xp; W=Wp; b=bp; Xout=Xpo; Xbf=Xpb; }
  else { idx -= NP*H; if (idx >= NL*H) return; Xin=Xl; W=Wl; b=bl; Xout=Xlo; Xbf=Xlb; }
  int n = idx >> 7, c = idx & 127;
  float acc = b[c];
  #pragma unroll
  for (int k=0;k<6;k++) acc += Xin[n*6+k] * W[k*H+c];
  Xout[idx] = acc;
  Xbf[idx] = f2bf(acc);
}

// ---------------------------------------------------------------------------
// Table GEMM v4: wave owns one 64-col group (B frags resident in VGPRs) and
// iterates GR row-strips; 4 waves of a block share the same row-chunk (A reuse
// through L1/L2). Weight read traffic drops ~8x vs v3.
// ---------------------------------------------------------------------------
#define GR 8
__global__ void __launch_bounds__(256) gemm_tables(
    const bf16* __restrict__ Xp, const bf16* __restrict__ Wtp,
    const float* __restrict__ Biasp, bf16* __restrict__ Outp,
    int strips_p, int tasks_p,
    const bf16* __restrict__ Xl, const bf16* __restrict__ Wtl,
    const float* __restrict__ Biasl, bf16* __restrict__ Outl,
    int strips_l, int tasks_total){
  int wt = blockIdx.x*4 + (threadIdx.x >> 6);
  if (wt >= tasks_total) return;
  const bf16 *X, *Wt; const float* Bias; bf16* Out; int N, strips, g, chunk;
  if (wt < tasks_p){
    X=Xp; Wt=Wtp; Bias=Biasp; Out=Outp; N=1024; strips=strips_p;
    g = wt & 15; chunk = wt >> 4;
  } else {
    int w = wt - tasks_p;
    X=Xl; Wt=Wtl; Bias=Biasl; Out=Outl; N=512; strips=strips_l;
    g = w & 7; chunk = w >> 3;
  }
  int n0 = g << 6;
  int lane = threadIdx.x & 63;
  int lr = lane & 15, lq = lane >> 4;
  const bf16x8* B0 = (const bf16x8*)(const void*)(Wt + (size_t)(n0      + lr)*H);
  const bf16x8* B1 = (const bf16x8*)(const void*)(Wt + (size_t)(n0 + 16 + lr)*H);
  const bf16x8* B2 = (const bf16x8*)(const void*)(Wt + (size_t)(n0 + 32 + lr)*H);
  const bf16x8* B3 = (const bf16x8*)(const void*)(Wt + (size_t)(n0 + 48 + lr)*H);
  bf16x8 b0_0=B0[lq], b0_1=B0[4+lq], b0_2=B0[8+lq], b0_3=B0[12+lq];
  bf16x8 b1_0=B1[lq], b1_1=B1[4+lq], b1_2=B1[8+lq], b1_3=B1[12+lq];
  bf16x8 b2_0=B2[lq], b2_1=B2[4+lq], b2_2=B2[8+lq], b2_3=B2[12+lq];
  bf16x8 b3_0=B3[lq], b3_1=B3[4+lq], b3_2=B3[8+lq], b3_3=B3[12+lq];
  float4 bias = ((const float4*)(const void*)(Bias + n0))[lr];
  #pragma unroll 2
  for (int r=0;r<GR;r++){
    int strip = chunk*GR + r;
    if (strip >= strips) break;
    int m0 = strip << 4;
    const bf16x8* A = (const bf16x8*)(const void*)(X + (size_t)(m0+lr)*H);
    bf16x8 a0 = A[lq], a1 = A[4+lq], a2 = A[8+lq], a3 = A[12+lq];
    f32x4 acc0 = {0.f,0.f,0.f,0.f}, acc1 = acc0, acc2 = acc0, acc3 = acc0;
    acc0 = __builtin_amdgcn_mfma_f32_16x16x32_bf16(a0, b0_0, acc0, 0, 0, 0);
    acc1 = __builtin_amdgcn_mfma_f32_16x16x32_bf16(a0, b1_0, acc1, 0, 0, 0);
    acc2 = __builtin_amdgcn_mfma_f32_16x16x32_bf16(a0, b2_0, acc2, 0, 0, 0);
    acc3 = __builtin_amdgcn_mfma_f32_16x16x32_bf16(a0, b3_0, acc3, 0, 0, 0);
    acc0 = __builtin_amdgcn_mfma_f32_16x16x32_bf16(a1, b0_1, acc0, 0, 0, 0);
    acc1 = __builtin_amdgcn_mfma_f32_16x16x32_bf16(a1, b1_1, acc1, 0, 0, 0);
    acc2 = __builtin_amdgcn_mfma_f32_16x16x32_bf16(a1, b2_1, acc2, 0, 0, 0);
    acc3 = __builtin_amdgcn_mfma_f32_16x16x32_bf16(a1, b3_1, acc3, 0, 0, 0);
    acc0 = __builtin_amdgcn_mfma_f32_16x16x32_bf16(a2, b0_2, acc0, 0, 0, 0);
    acc1 = __builtin_amdgcn_mfma_f32_16x16x32_bf16(a2, b1_2, acc1, 0, 0, 0);
    acc2 = __builtin_amdgcn_mfma_f32_16x16x32_bf16(a2, b2_2, acc2, 0, 0, 0);
    acc3 = __builtin_amdgcn_mfma_f32_16x16x32_bf16(a2, b3_2, acc3, 0, 0, 0);
    acc0 = __builtin_amdgcn_mfma_f32_16x16x32_bf16(a3, b0_3, acc0, 0, 0, 0);
    acc1 = __builtin_amdgcn_mfma_f32_16x16x32_bf16(a3, b1_3, acc1, 0, 0, 0);
    acc2 = __builtin_amdgcn_mfma_f32_16x16x32_bf16(a3, b2_3, acc2, 0, 0, 0);
    acc3 = __builtin_amdgcn_mfma_f32_16x16x32_bf16(a3, b3_3, acc3, 0, 0, 0);
    #pragma unroll
    for (int rr=0;rr<4;rr++){
      int row = m0 + lq*4 + rr;
      uint2 pk;
      pk.x = pack_bf2(acc0[rr] + bias.x, acc1[rr] + bias.y);
      pk.y = pack_bf2(acc2[rr] + bias.z, acc3[rr] + bias.w);
      *(uint2*)(void*)(Out + (size_t)row*N + n0 + 4*lr) = pk;
    }
  }
}

// ---------------------------------------------------------------------------
// Node-update helpers
// ---------------------------------------------------------------------------
static __device__ __forceinline__ float act_msg(float f, float s){
  float sig = __builtin_amdgcn_rcpf(1.f + __expf(-f));
  float sp  = fmaxf(s, 0.f) + __logf(1.f + __expf(-fabsf(s)));
  return sig * sp;
}

#define BN_RSQ 0.9999950000374997f   /* 1/sqrt(1+1e-5) */

static __device__ __forceinline__ void edge_nb(uint2 g, uint2 t,
                                               f32x2 fd2, f32x2 sd2, f32x2& acc){
  f32x2 f2, s2;
  f2.x = u2f_lo(g.x) + u2f_lo(t.x);
  f2.y = u2f_lo(g.y) + u2f_lo(t.y);
  s2.x = u2f_hi(g.x) + u2f_hi(t.x);
  s2.y = u2f_hi(g.y) + u2f_hi(t.y);
  f2 += fd2; s2 += sd2;
  acc.x += act_msg(f2.x, s2.x);
  acc.y += act_msg(f2.y, s2.y);
}

static __device__ __forceinline__ void ln_stats_w(float v0, float v1, float& mu, float& var){
  float s = v0 + v1, q = v0*v0 + v1*v1;
  #pragma unroll
  for (int o=32;o>=1;o>>=1){ s += __shfl_xor(s,o,64); q += __shfl_xor(q,o,64); }
  mu = s * (1.f/128.f);
  var = q * (1.f/128.f) - mu*mu;
}

// depth-3 software-pipelined CSR aggregation (nearest-bin RBF)
static __device__ __forceinline__ void aggregate(
    const int* __restrict__ srcv, const float* __restrict__ dv,
    int e0, int e1,
    const uint2* __restrict__ G, int gstride, int goff,
    const uint2* __restrict__ Tb, int lane,
    f32x2 fd2, f32x2 sd2, f32x2& acc)
{
  if (e0 >= e1) return;
  int n = e1 - e0;
  uint2 gA, tA, gB, tB, gC, tC;
  #define LOADE(gX, tX, idx) { \
    int s_ = __builtin_amdgcn_readfirstlane(srcv[idx]); \
    float d_ = dv[idx]; \
    float bf_ = __fmaf_rn(d_, 128.f, 0.5f); \
    int b_ = (int)bf_; b_ = (b_ > 1024) ? 1024 : b_; \
    b_ = __builtin_amdgcn_readfirstlane(b_); \
    gX = G[(size_t)s_*gstride + goff + lane]; \
    tX = Tb[(size_t)b_*64 + lane]; }
  LOADE(gA, tA, e0);
  if (n > 1) LOADE(gB, tB, e0+1);
  if (n > 2) LOADE(gC, tC, e0+2);
  for (int i = e0; i+3 < e1; i++){
    uint2 gD, tD;
    LOADE(gD, tD, i+3);
    edge_nb(gA, tA, fd2, sd2, acc);
    gA = gB; tA = tB; gB = gC; tB = tC; gC = gD; tC = tD;
  }
  edge_nb(gA, tA, fd2, sd2, acc);
  if (n > 1) edge_nb(gB, tB, fd2, sd2, acc);
  if (n > 2) edge_nb(gC, tC, fd2, sd2, acc);
  #undef LOADE
}

// ---------------------------------------------------------------------------
// Merged node update: wave per node. Blocks [0,PB) protein, rest ligand.
// ---------------------------------------------------------------------------
__global__ void __launch_bounds__(256) node_update(
    const bf16* __restrict__ PT, const bf16* __restrict__ LT,
    const float* __restrict__ xp, const float* __restrict__ xl,
    const int* __restrict__ pp_rp, const int* __restrict__ pp_src, const float* __restrict__ pp_d,
    const int* __restrict__ lp_rp, const int* __restrict__ lp_src, const float* __restrict__ lp_d,
    const int* __restrict__ pl_rp, const int* __restrict__ pl_src, const float* __restrict__ pl_d,
    const bf16* __restrict__ T2,
    const float* __restrict__ bn_w, const float* __restrict__ bn_b,
    const float* __restrict__ ln_w, const float* __restrict__ ln_b,
    float* __restrict__ xp_out, bf16* __restrict__ xp_bf,
    float* __restrict__ xl_out, bf16* __restrict__ xl_bf,
    int layer, int NP, int NL, int PB)
{
  int wave = threadIdx.x >> 6;
  int lane = threadIdx.x & 63;
  const uint2* PTg = (const uint2*)(const void*)PT;
  if ((int)blockIdx.x < PB){
    int node = blockIdx.x*4 + wave;
    if (node >= NP) return;
    float2 x = ((const float2*)(const void*)(xp + (size_t)node*H))[lane];
    const uint32* PTu = (const uint32*)(const void*)PT;
    const uint2*  LTg = (const uint2*)(const void*)LT;
    float o1_0, o1_1, o2_0, o2_1;
    { // relation pp
      int pr = layer*3 + 0;
      uint32 fdp = PTu[(size_t)node*512 + 256 + lane];
      uint32 sdp = PTu[(size_t)node*512 + 320 + lane];
      const uint2* Tb = (const uint2*)(const void*)(T2 + (size_t)pr*1025*256);
      f32x2 fd2 = {u2f_lo(fdp), u2f_hi(fdp)};
      f32x2 sd2 = {u2f_lo(sdp), u2f_hi(sdp)};
      f32x2 acc = {0.f, 0.f};
      aggregate(pp_src, pp_d, pp_rp[node], pp_rp[node+1], PTg, 256, 0, Tb, lane, fd2, sd2, acc);
      float2 bw = ((const float2*)(const void*)(bn_w + pr*H))[lane];
      float2 bb = ((const float2*)(const void*)(bn_b + pr*H))[lane];
      float2 lw = ((const float2*)(const void*)(ln_w + pr*H))[lane];
      float2 lb = ((const float2*)(const void*)(ln_b + pr*H))[lane];
      float v0 = acc.x * (bw.x * BN_RSQ) + bb.x + x.x;
      float v1 = acc.y * (bw.y * BN_RSQ) + bb.y + x.y;
      float mu, var; ln_stats_w(v0, v1, mu, var);
      float rs = rsqrtf(var + 1e-5f);
      o1_0 = fmaxf((v0-mu)*rs*lw.x + lb.x, 0.f) + x.x;
      o1_1 = fmaxf((v1-mu)*rs*lw.y + lb.y, 0.f) + x.y;
    }
    { // relation lp
      int pr = layer*3 + 1;
      uint32 fdp = PTu[(size_t)node*512 + 384 + lane];
      uint32 sdp = PTu[(size_t)node*512 + 448 + lane];
      const uint2* Tb = (const uint2*)(const void*)(T2 + (size_t)pr*1025*256);
      f32x2 fd2 = {u2f_lo(fdp), u2f_hi(fdp)};
      f32x2 sd2 = {u2f_lo(sdp), u2f_hi(sdp)};
      f32x2 acc = {0.f, 0.f};
      aggregate(lp_src, lp_d, lp_rp[node], lp_rp[node+1], LTg, 128, 0, Tb, lane, fd2, sd2, acc);
      float2 bw = ((const float2*)(const void*)(bn_w + pr*H))[lane];
      float2 bb = ((const float2*)(const void*)(bn_b + pr*H))[lane];
      float2 lw = ((const float2*)(const void*)(ln_w + pr*H))[lane];
      float2 lb = ((const float2*)(const void*)(ln_b + pr*H))[lane];
      float v0 = acc.x * (bw.x * BN_RSQ) + bb.x + x.x;
      float v1 = acc.y * (bw.y * BN_RSQ) + bb.y + x.y;
      float mu, var; ln_stats_w(v0, v1, mu, var);
      float rs = rsqrtf(var + 1e-5f);
      o2_0 = fmaxf((v0-mu)*rs*lw.x + lb.x, 0.f) + x.x;
      o2_1 = fmaxf((v1-mu)*rs*lw.y + lb.y, 0.f) + x.y;
    }
    float out0 = o1_0 + o2_0, out1 = o1_1 + o2_1;
    ((float2*)(void*)(xp_out + (size_t)node*H))[lane] = make_float2(out0, out1);
    ((uint32*)(void*)(xp_bf + (size_t)node*H))[lane] = pack_bf2(out0, out1);
  } else {
    int node = (blockIdx.x - PB)*4 + wave;
    if (node >= NL) return;
    float2 x = ((const float2*)(const void*)(xl + (size_t)node*H))[lane];
    const uint32* LTu = (const uint32*)(const void*)LT;
    int pr = layer*3 + 2;
    uint32 fdp = LTu[(size_t)node*256 + 128 + lane];
    uint32 sdp = LTu[(size_t)node*256 + 192 + lane];
    const uint2* Tb = (const uint2*)(const void*)(T2 + (size_t)pr*1025*256);
    f32x2 fd2 = {u2f_lo(fdp), u2f_hi(fdp)};
    f32x2 sd2 = {u2f_lo(sdp), u2f_hi(sdp)};
    f32x2 acc = {0.f, 0.f};
    aggregate(pl_src, pl_d, pl_rp[node], pl_rp[node+1], PTg, 256, 64, Tb, lane, fd2, sd2, acc);
    float2 bw = ((const float2*)(const void*)(bn_w + pr*H))[lane];
    float2 bb = ((const float2*)(const void*)(bn_b + pr*H))[lane];
    float2 lw = ((const float2*)(const void*)(ln_w + pr*H))[lane];
    float2 lb = ((const float2*)(const void*)(ln_b + pr*H))[lane];
    float v0 = acc.x * (bw.x * BN_RSQ) + bb.x + x.x;
    float v1 = acc.y * (bw.y * BN_RSQ) + bb.y + x.y;
    float mu, var; ln_stats_w(v0, v1, mu, var);
    float rs = rsqrtf(var + 1e-5f);
    float out0 = fmaxf((v0-mu)*rs*lw.x + lb.x, 0.f) + x.x;
    float out1 = fmaxf((v1-mu)*rs*lw.y + lb.y, 0.f) + x.y;
    ((float2*)(void*)(xl_out + (size_t)node*H))[lane] = make_float2(out0, out1);
    ((uint32*)(void*)(xl_bf + (size_t)node*H))[lane] = pack_bf2(out0, out1);
  }
}

// ---------------------------------------------------------------------------
// Final: LN(xp) @ fc_w[128,21] + fc_b
// ---------------------------------------------------------------------------
__global__ void __launch_bounds__(128) final_k(const float* __restrict__ xp,
    const float* __restrict__ lnw, const float* __restrict__ lnb,
    const float* __restrict__ fcw, const float* __restrict__ fcb,
    float* __restrict__ out, int N){
  __shared__ float sm[4];
  __shared__ float lnv[128];
  int node = blockIdx.x, c = threadIdx.x;
  float v = xp[(size_t)node*H + c];
  float s = v, q = v*v;
  #pragma unroll
  for (int o=32;o>=1;o>>=1){ s += __shfl_xor(s,o,64); q += __shfl_xor(q,o,64); }
  __syncthreads();
  if ((c & 63) == 0){ sm[(c>>6)*2] = s; sm[(c>>6)*2+1] = q; }
  __syncthreads();
  float S = sm[0] + sm[2], Q = sm[1] + sm[3];
  float mu = S * (1.f/128.f);
  float var = Q * (1.f/128.f) - mu*mu;
  float ln = (v-mu)*rsqrtf(var+1e-5f)*lnw[c] + lnb[c];
  lnv[c] = ln;
  __syncthreads();
  if (c < 21){
    float a = fcb[c];
    #pragma unroll 4
    for (int i=0;i<128;i++) a += lnv[i]*fcw[i*21+c];
    out[(size_t)node*21 + c] = a;
  }
}

// ---------------------------------------------------------------------------
extern "C" void kernel_launch(void* const* d_in, const int* in_sizes, int n_in,
                              void* d_out, int out_size, void* d_ws, size_t ws_size,
                              hipStream_t stream){
  const float* x_protein = (const float*)d_in[0];
  const float* x_ligand  = (const float*)d_in[1];
  const int*   ei_pp = (const int*)d_in[2];
  const float* ea_pp = (const float*)d_in[3];
  const int*   ei_lp = (const int*)d_in[4];
  const float* ea_lp = (const float*)d_in[5];
  const int*   ei_pl = (const int*)d_in[6];
  const float* ea_pl = (const float*)d_in[7];
  const float* Wp  = (const float*)d_in[8];
  const float* bp  = (const float*)d_in[9];
  const float* Wl  = (const float*)d_in[10];
  const float* bl  = (const float*)d_in[11];
  const float* Wf  = (const float*)d_in[12];
  const float* bfv = (const float*)d_in[13];
  const float* Wsv = (const float*)d_in[14];
  const float* bsv = (const float*)d_in[15];
  const float* bn_w = (const float*)d_in[16];
  const float* bn_b = (const float*)d_in[17];
  const float* ln_w = (const float*)d_in[18];
  const float* ln_b = (const float*)d_in[19];
  const float* lno_w = (const float*)d_in[20];
  const float* lno_b = (const float*)d_in[21];
  const float* fc_w = (const float*)d_in[22];
  const float* fc_b = (const float*)d_in[23];

  int NP  = in_sizes[0]/6, NL = in_sizes[1]/6;
  int EPP = in_sizes[3], ELP = in_sizes[5], EPL = in_sizes[7];

  char* ws = (char*)d_ws;
  size_t off = 0;
  auto alloc = [&](size_t bytes)->void*{
    void* p = ws + off; off = (off + bytes + 255) & ~(size_t)255; return p;
  };

  float* xpA = (float*)alloc((size_t)NP*H*4);
  float* xpB = (float*)alloc((size_t)NP*H*4);
  float* xlA = (float*)alloc((size_t)NL*H*4);
  float* xlB = (float*)alloc((size_t)NL*H*4);
  bf16* xp_bf = (bf16*)alloc((size_t)NP*H*2);
  bf16* xl_bf = (bf16*)alloc((size_t)NL*H*2);
  bf16* PT    = (bf16*)alloc((size_t)NP*1024*2);
  bf16* LT    = (bf16*)alloc((size_t)NL*512*2);
  bf16* Wt_p  = (bf16*)alloc((size_t)4*1024*H*2);
  bf16* Wt_l  = (bf16*)alloc((size_t)4*512*H*2);
  float* Bias_p = (float*)alloc((size_t)4*1024*4);
  float* Bias_l = (float*)alloc((size_t)4*512*4);
  bf16* T2    = (bf16*)alloc((size_t)12*1025*256*2);
  int* counts = (int*)alloc((size_t)(2*NP+NL)*4);
  int* rp_pp  = (int*)alloc((size_t)(NP+1)*4);
  int* cur_pp = (int*)alloc((size_t)NP*4);
  int* rp_lp  = (int*)alloc((size_t)(NP+1)*4);
  int* cur_lp = (int*)alloc((size_t)NP*4);
  int* rp_pl  = (int*)alloc((size_t)(NL+1)*4);
  int* cur_pl = (int*)alloc((size_t)NL*4);
  int*   csrc_pp = (int*)alloc((size_t)EPP*4);
  float* cd_pp   = (float*)alloc((size_t)EPP*4);
  int*   csrc_lp = (int*)alloc((size_t)ELP*4);
  float* cd_lp   = (float*)alloc((size_t)ELP*4);
  int*   csrc_pl = (int*)alloc((size_t)EPL*4);
  float* cd_pl   = (float*)alloc((size_t)EPL*4);
  int Cpp = (NP + SCH - 1) / SCH;
  int Cpl = (NL + SCH - 1) / SCH;
  int* chsum = (int*)alloc((size_t)(2*Cpp + Cpl)*4);
  (void)ws_size; (void)n_in; (void)out_size;

  // --- prep (weights + RBF table) ---
  int prep_total = PREP_WP_N + PREP_WL_N + RBF_N;
  prep_all<<<(prep_total+255)/256, 256, 0, stream>>>(Wf, Wsv, bfv, bsv,
                                                     Wt_p, Bias_p, Wt_l, Bias_l, T2);
  // --- CSR build ---
  hipMemsetAsync(counts, 0, (size_t)(2*NP+NL)*4, stream);
  int* cnt_pp = counts; int* cnt_lp = counts + NP; int* cnt_pl = counts + 2*NP;
  int Etot = EPP + ELP + EPL;
  hist3_k<<<(Etot+255)/256, 256, 0, stream>>>(ei_pp+EPP, EPP, ei_lp+ELP, ELP, ei_pl+EPL, EPL,
                                              cnt_pp, cnt_lp, cnt_pl);
  chunksum_k<<<2*Cpp + Cpl, 256, 0, stream>>>(counts, NP, NL, Cpp, Cpl, chsum);
  scanmid_k<<<1, 192, 0, stream>>>(chsum, Cpp, Cpl, NP, NL, rp_pp, rp_lp, rp_pl);
  scanfin_k<<<2*Cpp + Cpl, 1024, 0, stream>>>(counts, NP, NL, Cpp, Cpl, chsum,
                                              rp_pp, cur_pp, rp_lp, cur_lp, rp_pl, cur_pl);
  fill3_k<<<(Etot+255)/256, 256, 0, stream>>>(ei_pp, ea_pp, EPP, ei_lp, ea_lp, ELP,
                                              ei_pl, ea_pl, EPL,
                                              cur_pp, csrc_pp, cd_pp,
                                              cur_lp, csrc_lp, cd_lp,
                                              cur_pl, csrc_pl, cd_pl);

  // --- embeddings ---
  embed2_k<<<(((size_t)(NP+NL)*H)+255)/256, 256, 0, stream>>>(
      x_protein, Wp, bp, xpA, xp_bf, NP, x_ligand, Wl, bl, xlA, xl_bf, NL);

  // --- layers ---
  float* xp_cur = xpA; float* xp_nxt = xpB;
  float* xl_cur = xlA; float* xl_nxt = xlB;
  int strips_p = NP >> 4, strips_l = NL >> 4;
  int tasks_p = 16 * ((strips_p + GR - 1) / GR);
  int tasks_l = 8  * ((strips_l + GR - 1) / GR);
  int tasks_total = tasks_p + tasks_l;
  int PB = (NP + 3) / 4, LB = (NL + 3) / 4;
  for (int l=0; l<4; l++){
    gemm_tables<<<(tasks_total+3)/4, 256, 0, stream>>>(
        xp_bf, Wt_p + (size_t)l*1024*H, Bias_p + l*1024, PT, strips_p, tasks_p,
        xl_bf, Wt_l + (size_t)l*512*H,  Bias_l + l*512,  LT, strips_l, tasks_total);
    node_update<<<PB + LB, 256, 0, stream>>>(PT, LT, xp_cur, xl_cur,
        rp_pp, csrc_pp, cd_pp, rp_lp, csrc_lp, cd_lp, rp_pl, csrc_pl, cd_pl, T2,
        bn_w, bn_b, ln_w, ln_b, xp_nxt, xp_bf, xl_nxt, xl_bf, l, NP, NL, PB);
    float* t;
    t = xp_cur; xp_cur = xp_nxt; xp_nxt = t;
    t = xl_cur; xl_cur = xl_nxt; xl_nxt = t;
  }

  // --- output head ---
  final_k<<<NP, 128, 0, stream>>>(xp_cur, lno_w, lno_b, fc_w, fc_b, (float*)d_out, NP);
}

// Round 8
// 870.948 us; speedup vs baseline: 3.6210x; 1.0496x over previous
//
#include <hip/hip_runtime.h>
#include <hip/hip_bf16.h>
#include <math.h>

#define H 128

typedef __bf16 bf16x8 __attribute__((ext_vector_type(8)));
typedef float f32x4 __attribute__((ext_vector_type(4)));
typedef float f32x2 __attribute__((ext_vector_type(2)));
typedef __hip_bfloat16 bf16;
typedef unsigned int uint32;

static __device__ __forceinline__ float bf2f(bf16 v){ return __bfloat162float(v); }
static __device__ __forceinline__ bf16 f2bf(float v){ return __float2bfloat16(v); }
static __device__ __forceinline__ float u2f_lo(uint32 v){ return __uint_as_float(v << 16); }
static __device__ __forceinline__ float u2f_hi(uint32 v){ return __uint_as_float(v & 0xffff0000u); }

union bfpack { struct { bf16 lo, hi; } h; uint32 u; };
static __device__ __forceinline__ uint32 pack_bf2(float a, float b){
  bfpack p; p.h.lo = f2bf(a); p.h.hi = f2bf(b); return p.u;
}

// ---------------------------------------------------------------------------
// Table layouts: PT[node][1024], LT[node][512] (see earlier rounds), weights
// permuted within 64-col groups, nearest-bin RBF table T2[pr][1025][256].
// CSR edge info packed as int2 {src, float_bits(d)}.
// ---------------------------------------------------------------------------
static __device__ __forceinline__ int unperm64(int r){
  int base = r & ~63; int g = r & 63; int t = g >> 4; int j = g & 15;
  return base + 4*j + t;
}

#define PREP_WP_N (4*1024*128)
#define PREP_WL_N (4*512*128)
#define RBF_N     (12*1025*128)

__global__ void prep_all(const float* __restrict__ Wf, const float* __restrict__ Ws,
                         const float* __restrict__ bfv, const float* __restrict__ bsv,
                         bf16* __restrict__ Wt_p, float* __restrict__ Bias_p,
                         bf16* __restrict__ Wt_l, float* __restrict__ Bias_l,
                         bf16* __restrict__ T2){
  int t = blockIdx.x*blockDim.x + threadIdx.x;
  if (t < PREP_WP_N){
    int k = t & 127; int idx = t >> 7;
    int rs = idx & 1023; int l = idx >> 10;
    int r = unperm64(rs);
    int rel, c, row0; const float* W; float bias = 0.f;
    if (r < 256)      { rel=0; c=r>>1;        row0=128; W = (r&1)?Ws:Wf; }
    else if (r < 512) { rel=2; c=(r-256)>>1;  row0=128; W = (r&1)?Ws:Wf; }
    else if (r < 640) { rel=0; c=r-512; row0=0; W=Wf; bias = bfv[(l*3+rel)*H+c]; }
    else if (r < 768) { rel=0; c=r-640; row0=0; W=Ws; bias = bsv[(l*3+rel)*H+c]; }
    else if (r < 896) { rel=1; c=r-768; row0=0; W=Wf; bias = bfv[(l*3+rel)*H+c]; }
    else              { rel=1; c=r-896; row0=0; W=Ws; bias = bsv[(l*3+rel)*H+c]; }
    Wt_p[t] = f2bf(W[((size_t)(l*3+rel)*272 + row0 + k)*H + c]);
    if (k == 0) Bias_p[l*1024 + r] = bias;
    return;
  }
  t -= PREP_WP_N;
  if (t < PREP_WL_N){
    int k = t & 127; int idx = t >> 7;
    int rs = idx & 511; int l = idx >> 9;
    int r = unperm64(rs);
    int rel, c, row0; const float* W; float bias = 0.f;
    if (r < 256)      { rel=1; c=r>>1;   row0=128; W = (r&1)?Ws:Wf; }
    else if (r < 384) { rel=2; c=r-256; row0=0; W=Wf; bias = bfv[(l*3+rel)*H+c]; }
    else              { rel=2; c=r-384; row0=0; W=Ws; bias = bsv[(l*3+rel)*H+c]; }
    Wt_l[t] = f2bf(W[((size_t)(l*3+rel)*272 + row0 + k)*H + c]);
    if (k == 0) Bias_l[l*512 + r] = bias;
    return;
  }
  t -= PREP_WL_N;
  if (t < RBF_N){
    int c = t & 127;
    int b = (t >> 7) % 1025;
    int pr = t / (1025*128);
    float d0 = (float)b * 0.0078125f;
    const float* wf = Wf + ((size_t)pr*272 + 256)*H + c;
    const float* ws = Ws + ((size_t)pr*272 + 256)*H + c;
    float f0=0.f, s0=0.f;
    #pragma unroll
    for (int k=0;k<16;k++){
      float o = 0.533333333f*(float)k;
      float tt = d0 - o;
      float r0 = __expf(-1.7578125f*tt*tt);
      f0 += r0*wf[(size_t)k*H]; s0 += r0*ws[(size_t)k*H];
    }
    bf16* o = T2 + ((size_t)(pr*1025 + b))*256 + 2*c;
    o[0]=f2bf(f0); o[1]=f2bf(s0);
  }
}

// ---------------------------------------------------------------------------
// CSR build: hist -> chunk sums -> mid scan -> final scan -> fill
// ---------------------------------------------------------------------------
__global__ void hist3_k(const int* __restrict__ dpp, int Epp,
                        const int* __restrict__ dlp, int Elp,
                        const int* __restrict__ dpl, int Epl,
                        int* __restrict__ cpp, int* __restrict__ clp, int* __restrict__ cpl){
  int e = blockIdx.x*blockDim.x + threadIdx.x;
  if (e < Epp) atomicAdd(&cpp[dpp[e]], 1);
  else if (e < Epp+Elp) atomicAdd(&clp[dlp[e-Epp]], 1);
  else if (e < Epp+Elp+Epl) atomicAdd(&cpl[dpl[e-Epp-Elp]], 1);
}

#define SCH 1024   // scan chunk size

__global__ void __launch_bounds__(256) chunksum_k(
    const int* __restrict__ counts, int NP, int NL, int Cpp, int Cpl,
    int* __restrict__ chsum){
  __shared__ int wred[4];
  int b = blockIdx.x;
  const int* cnt; int n; int ch;
  if (b < Cpp){ cnt = counts; n = NP; ch = b; }
  else if (b < 2*Cpp){ cnt = counts + NP; n = NP; ch = b - Cpp; }
  else { cnt = counts + 2*NP; n = NL; ch = b - 2*Cpp; }
  int base = ch * SCH;
  int tid = threadIdx.x;
  int s = 0;
  #pragma unroll
  for (int j=0;j<SCH/256;j++){
    int i = base + tid + j*256;
    if (i < n) s += cnt[i];
  }
  #pragma unroll
  for (int o=32;o>=1;o>>=1) s += __shfl_xor(s,o,64);
  if ((tid & 63) == 0) wred[tid>>6] = s;
  __syncthreads();
  if (tid == 0) chsum[b] = wred[0]+wred[1]+wred[2]+wred[3];
}

__global__ void __launch_bounds__(192) scanmid_k(
    int* __restrict__ chsum, int Cpp, int Cpl, int NP, int NL,
    int* __restrict__ rp_pp, int* __restrict__ rp_lp, int* __restrict__ rp_pl){
  int wid = threadIdx.x >> 6, lane = threadIdx.x & 63;
  int C, off; int* rp_end; int n;
  if (wid == 0){ C = Cpp; off = 0;      rp_end = rp_pp; n = NP; }
  else if (wid == 1){ C = Cpp; off = Cpp; rp_end = rp_lp; n = NP; }
  else { C = Cpl; off = 2*Cpp; rp_end = rp_pl; n = NL; }
  int v = (lane < C) ? chsum[off + lane] : 0;
  int x = v;
  #pragma unroll
  for (int o=1;o<64;o<<=1){
    int y = __shfl_up(x, o, 64);
    if (lane >= o) x += y;
  }
  if (lane < C) chsum[off + lane] = x - v;
  if (lane == 63) rp_end[n] = x;
}

__global__ void __launch_bounds__(1024) scanfin_k(
    const int* __restrict__ counts, int NP, int NL, int Cpp, int Cpl,
    const int* __restrict__ chsum,
    int* __restrict__ rp_pp, int* __restrict__ cur_pp,
    int* __restrict__ rp_lp, int* __restrict__ cur_lp,
    int* __restrict__ rp_pl, int* __restrict__ cur_pl){
  __shared__ int wsum[16];
  int b = blockIdx.x;
  const int* cnt; int n, ch; int* rp; int* cur;
  if (b < Cpp){ cnt = counts; n = NP; ch = b; rp = rp_pp; cur = cur_pp; }
  else if (b < 2*Cpp){ cnt = counts + NP; n = NP; ch = b - Cpp; rp = rp_lp; cur = cur_lp; }
  else { cnt = counts + 2*NP; n = NL; ch = b - 2*Cpp; rp = rp_pl; cur = cur_pl; }
  int tid = threadIdx.x, lane = tid & 63, wid = tid >> 6;
  int i = ch*SCH + tid;
  int v = (i < n) ? cnt[i] : 0;
  int x = v;
  #pragma unroll
  for (int o=1;o<64;o<<=1){
    int y = __shfl_up(x, o, 64);
    if (lane >= o) x += y;
  }
  if (lane == 63) wsum[wid] = x;
  __syncthreads();
  if (wid == 0 && lane < 16){
    int w = wsum[lane];
    #pragma unroll
    for (int o=1;o<16;o<<=1){
      int y = __shfl_up(w, o, 64);
      if (lane >= o) w += y;
    }
    wsum[lane] = w;
  }
  __syncthreads();
  int waveoff = (wid == 0) ? 0 : wsum[wid-1];
  int ex = chsum[b] + waveoff + x - v;
  if (i < n){ rp[i] = ex; cur[i] = ex; }
}

// fill packed int2 {src, d_bits}
__global__ void fill3_k(const int* __restrict__ ei_pp, const float* __restrict__ ea_pp, int Epp,
                        const int* __restrict__ ei_lp, const float* __restrict__ ea_lp, int Elp,
                        const int* __restrict__ ei_pl, const float* __restrict__ ea_pl, int Epl,
                        int* __restrict__ cur_pp, int2* __restrict__ e2_pp,
                        int* __restrict__ cur_lp, int2* __restrict__ e2_lp,
                        int* __restrict__ cur_pl, int2* __restrict__ e2_pl){
  int e = blockIdx.x*blockDim.x + threadIdx.x;
  if (e < Epp){
    int p = atomicAdd(&cur_pp[ei_pp[Epp + e]], 1);
    e2_pp[p] = make_int2(ei_pp[e], __float_as_int(ea_pp[e]));
  } else if (e < Epp+Elp){
    int i = e - Epp;
    int p = atomicAdd(&cur_lp[ei_lp[Elp + i]], 1);
    e2_lp[p] = make_int2(ei_lp[i], __float_as_int(ea_lp[i]));
  } else if (e < Epp+Elp+Epl){
    int i = e - Epp - Elp;
    int p = atomicAdd(&cur_pl[ei_pl[Epl + i]], 1);
    e2_pl[p] = make_int2(ei_pl[i], __float_as_int(ea_pl[i]));
  }
}

// ---------------------------------------------------------------------------
// Node embedding (merged): x @ W[6,128] + b
// ---------------------------------------------------------------------------
__global__ void embed2_k(const float* __restrict__ Xp, const float* __restrict__ Wp,
                         const float* __restrict__ bp, float* __restrict__ Xpo,
                         bf16* __restrict__ Xpb, int NP,
                         const float* __restrict__ Xl, const float* __restrict__ Wl,
                         const float* __restrict__ bl, float* __restrict__ Xlo,
                         bf16* __restrict__ Xlb, int NL){
  int idx = blockIdx.x*blockDim.x + threadIdx.x;
  const float* Xin; const float* W; const float* b; float* Xout; bf16* Xbf;
  if (idx < NP*H){ Xin=Xp; W=Wp; b=bp; Xout=Xpo; Xbf=Xpb; }
  else { idx -= NP*H; if (idx >= NL*H) return; Xin=Xl; W=Wl; b=bl; Xout=Xlo; Xbf=Xlb; }
  int n = idx >> 7, c = idx & 127;
  float acc = b[c];
  #pragma unroll
  for (int k=0;k<6;k++) acc += Xin[n*6+k] * W[k*H+c];
  Xout[idx] = acc;
  Xbf[idx] = f2bf(acc);
}

// ---------------------------------------------------------------------------
// Table GEMM v4 (B-resident): wave owns one 64-col group, iterates row strips.
// ---------------------------------------------------------------------------
#define GR 8
__global__ void __launch_bounds__(256) gemm_tables(
    const bf16* __restrict__ Xp, const bf16* __restrict__ Wtp,
    const float* __restrict__ Biasp, bf16* __restrict__ Outp,
    int strips_p, int tasks_p,
    const bf16* __restrict__ Xl, const bf16* __restrict__ Wtl,
    const float* __restrict__ Biasl, bf16* __restrict__ Outl,
    int strips_l, int tasks_total){
  int wt = blockIdx.x*4 + (threadIdx.x >> 6);
  if (wt >= tasks_total) return;
  const bf16 *X, *Wt; const float* Bias; bf16* Out; int N, strips, g, chunk;
  if (wt < tasks_p){
    X=Xp; Wt=Wtp; Bias=Biasp; Out=Outp; N=1024; strips=strips_p;
    g = wt & 15; chunk = wt >> 4;
  } else {
    int w = wt - tasks_p;
    X=Xl; Wt=Wtl; Bias=Biasl; Out=Outl; N=512; strips=strips_l;
    g = w & 7; chunk = w >> 3;
  }
  int n0 = g << 6;
  int lane = threadIdx.x & 63;
  int lr = lane & 15, lq = lane >> 4;
  const bf16x8* B0 = (const bf16x8*)(const void*)(Wt + (size_t)(n0      + lr)*H);
  const bf16x8* B1 = (const bf16x8*)(const void*)(Wt + (size_t)(n0 + 16 + lr)*H);
  const bf16x8* B2 = (const bf16x8*)(const void*)(Wt + (size_t)(n0 + 32 + lr)*H);
  const bf16x8* B3 = (const bf16x8*)(const void*)(Wt + (size_t)(n0 + 48 + lr)*H);
  bf16x8 b0_0=B0[lq], b0_1=B0[4+lq], b0_2=B0[8+lq], b0_3=B0[12+lq];
  bf16x8 b1_0=B1[lq], b1_1=B1[4+lq], b1_2=B1[8+lq], b1_3=B1[12+lq];
  bf16x8 b2_0=B2[lq], b2_1=B2[4+lq], b2_2=B2[8+lq], b2_3=B2[12+lq];
  bf16x8 b3_0=B3[lq], b3_1=B3[4+lq], b3_2=B3[8+lq], b3_3=B3[12+lq];
  float4 bias = ((const float4*)(const void*)(Bias + n0))[lr];
  #pragma unroll 2
  for (int r=0;r<GR;r++){
    int strip = chunk*GR + r;
    if (strip >= strips) break;
    int m0 = strip << 4;
    const bf16x8* A = (const bf16x8*)(const void*)(X + (size_t)(m0+lr)*H);
    bf16x8 a0 = A[lq], a1 = A[4+lq], a2 = A[8+lq], a3 = A[12+lq];
    f32x4 acc0 = {0.f,0.f,0.f,0.f}, acc1 = acc0, acc2 = acc0, acc3 = acc0;
    acc0 = __builtin_amdgcn_mfma_f32_16x16x32_bf16(a0, b0_0, acc0, 0, 0, 0);
    acc1 = __builtin_amdgcn_mfma_f32_16x16x32_bf16(a0, b1_0, acc1, 0, 0, 0);
    acc2 = __builtin_amdgcn_mfma_f32_16x16x32_bf16(a0, b2_0, acc2, 0, 0, 0);
    acc3 = __builtin_amdgcn_mfma_f32_16x16x32_bf16(a0, b3_0, acc3, 0, 0, 0);
    acc0 = __builtin_amdgcn_mfma_f32_16x16x32_bf16(a1, b0_1, acc0, 0, 0, 0);
    acc1 = __builtin_amdgcn_mfma_f32_16x16x32_bf16(a1, b1_1, acc1, 0, 0, 0);
    acc2 = __builtin_amdgcn_mfma_f32_16x16x32_bf16(a1, b2_1, acc2, 0, 0, 0);
    acc3 = __builtin_amdgcn_mfma_f32_16x16x32_bf16(a1, b3_1, acc3, 0, 0, 0);
    acc0 = __builtin_amdgcn_mfma_f32_16x16x32_bf16(a2, b0_2, acc0, 0, 0, 0);
    acc1 = __builtin_amdgcn_mfma_f32_16x16x32_bf16(a2, b1_2, acc1, 0, 0, 0);
    acc2 = __builtin_amdgcn_mfma_f32_16x16x32_bf16(a2, b2_2, acc2, 0, 0, 0);
    acc3 = __builtin_amdgcn_mfma_f32_16x16x32_bf16(a2, b3_2, acc3, 0, 0, 0);
    acc0 = __builtin_amdgcn_mfma_f32_16x16x32_bf16(a3, b0_3, acc0, 0, 0, 0);
    acc1 = __builtin_amdgcn_mfma_f32_16x16x32_bf16(a3, b1_3, acc1, 0, 0, 0);
    acc2 = __builtin_amdgcn_mfma_f32_16x16x32_bf16(a3, b2_3, acc2, 0, 0, 0);
    acc3 = __builtin_amdgcn_mfma_f32_16x16x32_bf16(a3, b3_3, acc3, 0, 0, 0);
    #pragma unroll
    for (int rr=0;rr<4;rr++){
      int row = m0 + lq*4 + rr;
      uint2 pk;
      pk.x = pack_bf2(acc0[rr] + bias.x, acc1[rr] + bias.y);
      pk.y = pack_bf2(acc2[rr] + bias.z, acc3[rr] + bias.w);
      *(uint2*)(void*)(Out + (size_t)row*N + n0 + 4*lr) = pk;
    }
  }
}

// ---------------------------------------------------------------------------
// Node-update helpers
// ---------------------------------------------------------------------------
static __device__ __forceinline__ float act_msg(float f, float s){
  float sig = __builtin_amdgcn_rcpf(1.f + __expf(-f));
  float sp  = fmaxf(s, 0.f) + __logf(1.f + __expf(-fabsf(s)));
  return sig * sp;
}

#define BN_RSQ 0.9999950000374997f   /* 1/sqrt(1+1e-5) */

static __device__ __forceinline__ void edge_nb(uint2 g, uint2 t,
                                               f32x2 fd2, f32x2 sd2, f32x2& acc){
  f32x2 f2, s2;
  f2.x = u2f_lo(g.x) + u2f_lo(t.x);
  f2.y = u2f_lo(g.y) + u2f_lo(t.y);
  s2.x = u2f_hi(g.x) + u2f_hi(t.x);
  s2.y = u2f_hi(g.y) + u2f_hi(t.y);
  f2 += fd2; s2 += sd2;
  acc.x += act_msg(f2.x, s2.x);
  acc.y += act_msg(f2.y, s2.y);
}

static __device__ __forceinline__ void ln_stats_w(float v0, float v1, float& mu, float& var){
  float s = v0 + v1, q = v0*v0 + v1*v1;
  #pragma unroll
  for (int o=32;o>=1;o>>=1){ s += __shfl_xor(s,o,64); q += __shfl_xor(q,o,64); }
  mu = s * (1.f/128.f);
  var = q * (1.f/128.f) - mu*mu;
}

// CSR aggregation: 64-edge chunk of {src,bin} held in registers (one 8B load
// per 64 edges); per edge: 2 readlane (SALU) + 2 gathers, depth-3 pipeline.
static __device__ __forceinline__ void aggregate(
    const int2* __restrict__ ev_arr, int e0, int e1,
    const uint2* __restrict__ G, int gstride, int goff,
    const uint2* __restrict__ Tb, int lane,
    f32x2 fd2, f32x2 sd2, f32x2& acc)
{
  for (int base = e0; base < e1; base += 64){
    int idx = base + lane;
    int2 ev = ev_arr[(idx < e1) ? idx : (e1-1)];
    float dd = __int_as_float(ev.y);
    int bnv = (int)__fmaf_rn(dd, 128.f, 0.5f);
    bnv = (bnv > 1024) ? 1024 : bnv;
    int cnt = e1 - base; cnt = (cnt > 64) ? 64 : cnt;
    uint2 gA, tA, gB, tB, gC, tC;
    #define LDJ(gX, tX, j) { \
      int s_ = __builtin_amdgcn_readlane(ev.x, (j)); \
      int b_ = __builtin_amdgcn_readlane(bnv, (j)); \
      gX = G[(size_t)s_*gstride + goff + lane]; \
      tX = Tb[(size_t)b_*64 + lane]; }
    LDJ(gA, tA, 0);
    if (cnt > 1) LDJ(gB, tB, 1);
    if (cnt > 2) LDJ(gC, tC, 2);
    for (int j = 0; j+3 < cnt; j++){
      uint2 gD, tD;
      LDJ(gD, tD, j+3);
      edge_nb(gA, tA, fd2, sd2, acc);
      gA = gB; tA = tB; gB = gC; tB = tC; gC = gD; tC = tD;
    }
    edge_nb(gA, tA, fd2, sd2, acc);
    if (cnt > 1) edge_nb(gB, tB, fd2, sd2, acc);
    if (cnt > 2) edge_nb(gC, tC, fd2, sd2, acc);
    #undef LDJ
  }
}

// ---------------------------------------------------------------------------
// Merged node update: wave per node. Blocks [0,PB) protein, rest ligand.
// ---------------------------------------------------------------------------
__global__ void __launch_bounds__(256) node_update(
    const bf16* __restrict__ PT, const bf16* __restrict__ LT,
    const float* __restrict__ xp, const float* __restrict__ xl,
    const int* __restrict__ pp_rp, const int2* __restrict__ pp_e2,
    const int* __restrict__ lp_rp, const int2* __restrict__ lp_e2,
    const int* __restrict__ pl_rp, const int2* __restrict__ pl_e2,
    const bf16* __restrict__ T2,
    const float* __restrict__ bn_w, const float* __restrict__ bn_b,
    const float* __restrict__ ln_w, const float* __restrict__ ln_b,
    float* __restrict__ xp_out, bf16* __restrict__ xp_bf,
    float* __restrict__ xl_out, bf16* __restrict__ xl_bf,
    int layer, int NP, int NL, int PB)
{
  int wave = threadIdx.x >> 6;
  int lane = threadIdx.x & 63;
  const uint2* PTg = (const uint2*)(const void*)PT;
  if ((int)blockIdx.x < PB){
    int node = blockIdx.x*4 + wave;
    if (node >= NP) return;
    float2 x = ((const float2*)(const void*)(xp + (size_t)node*H))[lane];
    const uint32* PTu = (const uint32*)(const void*)PT;
    const uint2*  LTg = (const uint2*)(const void*)LT;
    float o1_0, o1_1, o2_0, o2_1;
    { // relation pp
      int pr = layer*3 + 0;
      uint32 fdp = PTu[(size_t)node*512 + 256 + lane];
      uint32 sdp = PTu[(size_t)node*512 + 320 + lane];
      const uint2* Tb = (const uint2*)(const void*)(T2 + (size_t)pr*1025*256);
      f32x2 fd2 = {u2f_lo(fdp), u2f_hi(fdp)};
      f32x2 sd2 = {u2f_lo(sdp), u2f_hi(sdp)};
      f32x2 acc = {0.f, 0.f};
      aggregate(pp_e2, pp_rp[node], pp_rp[node+1], PTg, 256, 0, Tb, lane, fd2, sd2, acc);
      float2 bw = ((const float2*)(const void*)(bn_w + pr*H))[lane];
      float2 bb = ((const float2*)(const void*)(bn_b + pr*H))[lane];
      float2 lw = ((const float2*)(const void*)(ln_w + pr*H))[lane];
      float2 lb = ((const float2*)(const void*)(ln_b + pr*H))[lane];
      float v0 = acc.x * (bw.x * BN_RSQ) + bb.x + x.x;
      float v1 = acc.y * (bw.y * BN_RSQ) + bb.y + x.y;
      float mu, var; ln_stats_w(v0, v1, mu, var);
      float rs = rsqrtf(var + 1e-5f);
      o1_0 = fmaxf((v0-mu)*rs*lw.x + lb.x, 0.f) + x.x;
      o1_1 = fmaxf((v1-mu)*rs*lw.y + lb.y, 0.f) + x.y;
    }
    { // relation lp
      int pr = layer*3 + 1;
      uint32 fdp = PTu[(size_t)node*512 + 384 + lane];
      uint32 sdp = PTu[(size_t)node*512 + 448 + lane];
      const uint2* Tb = (const uint2*)(const void*)(T2 + (size_t)pr*1025*256);
      f32x2 fd2 = {u2f_lo(fdp), u2f_hi(fdp)};
      f32x2 sd2 = {u2f_lo(sdp), u2f_hi(sdp)};
      f32x2 acc = {0.f, 0.f};
      aggregate(lp_e2, lp_rp[node], lp_rp[node+1], LTg, 128, 0, Tb, lane, fd2, sd2, acc);
      float2 bw = ((const float2*)(const void*)(bn_w + pr*H))[lane];
      float2 bb = ((const float2*)(const void*)(bn_b + pr*H))[lane];
      float2 lw = ((const float2*)(const void*)(ln_w + pr*H))[lane];
      float2 lb = ((const float2*)(const void*)(ln_b + pr*H))[lane];
      float v0 = acc.x * (bw.x * BN_RSQ) + bb.x + x.x;
      float v1 = acc.y * (bw.y * BN_RSQ) + bb.y + x.y;
      float mu, var; ln_stats_w(v0, v1, mu, var);
      float rs = rsqrtf(var + 1e-5f);
      o2_0 = fmaxf((v0-mu)*rs*lw.x + lb.x, 0.f) + x.x;
      o2_1 = fmaxf((v1-mu)*rs*lw.y + lb.y, 0.f) + x.y;
    }
    float out0 = o1_0 + o2_0, out1 = o1_1 + o2_1;
    ((float2*)(void*)(xp_out + (size_t)node*H))[lane] = make_float2(out0, out1);
    ((uint32*)(void*)(xp_bf + (size_t)node*H))[lane] = pack_bf2(out0, out1);
  } else {
    int node = (blockIdx.x - PB)*4 + wave;
    if (node >= NL) return;
    float2 x = ((const float2*)(const void*)(xl + (size_t)node*H))[lane];
    const uint32* LTu = (const uint32*)(const void*)LT;
    int pr = layer*3 + 2;
    uint32 fdp = LTu[(size_t)node*256 + 128 + lane];
    uint32 sdp = LTu[(size_t)node*256 + 192 + lane];
    const uint2* Tb = (const uint2*)(const void*)(T2 + (size_t)pr*1025*256);
    f32x2 fd2 = {u2f_lo(fdp), u2f_hi(fdp)};
    f32x2 sd2 = {u2f_lo(sdp), u2f_hi(sdp)};
    f32x2 acc = {0.f, 0.f};
    aggregate(pl_e2, pl_rp[node], pl_rp[node+1], PTg, 256, 64, Tb, lane, fd2, sd2, acc);
    float2 bw = ((const float2*)(const void*)(bn_w + pr*H))[lane];
    float2 bb = ((const float2*)(const void*)(bn_b + pr*H))[lane];
    float2 lw = ((const float2*)(const void*)(ln_w + pr*H))[lane];
    float2 lb = ((const float2*)(const void*)(ln_b + pr*H))[lane];
    float v0 = acc.x * (bw.x * BN_RSQ) + bb.x + x.x;
    float v1 = acc.y * (bw.y * BN_RSQ) + bb.y + x.y;
    float mu, var; ln_stats_w(v0, v1, mu, var);
    float rs = rsqrtf(var + 1e-5f);
    float out0 = fmaxf((v0-mu)*rs*lw.x + lb.x, 0.f) + x.x;
    float out1 = fmaxf((v1-mu)*rs*lw.y + lb.y, 0.f) + x.y;
    ((float2*)(void*)(xl_out + (size_t)node*H))[lane] = make_float2(out0, out1);
    ((uint32*)(void*)(xl_bf + (size_t)node*H))[lane] = pack_bf2(out0, out1);
  }
}

// ---------------------------------------------------------------------------
// Final: LN(xp) @ fc_w[128,21] + fc_b
// ---------------------------------------------------------------------------
__global__ void __launch_bounds__(128) final_k(const float* __restrict__ xp,
    const float* __restrict__ lnw, const float* __restrict__ lnb,
    const float* __restrict__ fcw, const float* __restrict__ fcb,
    float* __restrict__ out, int N){
  __shared__ float sm[4];
  __shared__ float lnv[128];
  int node = blockIdx.x, c = threadIdx.x;
  float v = xp[(size_t)node*H + c];
  float s = v, q = v*v;
  #pragma unroll
  for (int o=32;o>=1;o>>=1){ s += __shfl_xor(s,o,64); q += __shfl_xor(q,o,64); }
  __syncthreads();
  if ((c & 63) == 0){ sm[(c>>6)*2] = s; sm[(c>>6)*2+1] = q; }
  __syncthreads();
  float S = sm[0] + sm[2], Q = sm[1] + sm[3];
  float mu = S * (1.f/128.f);
  float var = Q * (1.f/128.f) - mu*mu;
  float ln = (v-mu)*rsqrtf(var+1e-5f)*lnw[c] + lnb[c];
  lnv[c] = ln;
  __syncthreads();
  if (c < 21){
    float a = fcb[c];
    #pragma unroll 4
    for (int i=0;i<128;i++) a += lnv[i]*fcw[i*21+c];
    out[(size_t)node*21 + c] = a;
  }
}

// ---------------------------------------------------------------------------
extern "C" void kernel_launch(void* const* d_in, const int* in_sizes, int n_in,
                              void* d_out, int out_size, void* d_ws, size_t ws_size,
                              hipStream_t stream){
  const float* x_protein = (const float*)d_in[0];
  const float* x_ligand  = (const float*)d_in[1];
  const int*   ei_pp = (const int*)d_in[2];
  const float* ea_pp = (const float*)d_in[3];
  const int*   ei_lp = (const int*)d_in[4];
  const float* ea_lp = (const float*)d_in[5];
  const int*   ei_pl = (const int*)d_in[6];
  const float* ea_pl = (const float*)d_in[7];
  const float* Wp  = (const float*)d_in[8];
  const float* bp  = (const float*)d_in[9];
  const float* Wl  = (const float*)d_in[10];
  const float* bl  = (const float*)d_in[11];
  const float* Wf  = (const float*)d_in[12];
  const float* bfv = (const float*)d_in[13];
  const float* Wsv = (const float*)d_in[14];
  const float* bsv = (const float*)d_in[15];
  const float* bn_w = (const float*)d_in[16];
  const float* bn_b = (const float*)d_in[17];
  const float* ln_w = (const float*)d_in[18];
  const float* ln_b = (const float*)d_in[19];
  const float* lno_w = (const float*)d_in[20];
  const float* lno_b = (const float*)d_in[21];
  const float* fc_w = (const float*)d_in[22];
  const float* fc_b = (const float*)d_in[23];

  int NP  = in_sizes[0]/6, NL = in_sizes[1]/6;
  int EPP = in_sizes[3], ELP = in_sizes[5], EPL = in_sizes[7];

  char* ws = (char*)d_ws;
  size_t off = 0;
  auto alloc = [&](size_t bytes)->void*{
    void* p = ws + off; off = (off + bytes + 255) & ~(size_t)255; return p;
  };

  float* xpA = (float*)alloc((size_t)NP*H*4);
  float* xpB = (float*)alloc((size_t)NP*H*4);
  float* xlA = (float*)alloc((size_t)NL*H*4);
  float* xlB = (float*)alloc((size_t)NL*H*4);
  bf16* xp_bf = (bf16*)alloc((size_t)NP*H*2);
  bf16* xl_bf = (bf16*)alloc((size_t)NL*H*2);
  bf16* PT    = (bf16*)alloc((size_t)NP*1024*2);
  bf16* LT    = (bf16*)alloc((size_t)NL*512*2);
  bf16* Wt_p  = (bf16*)alloc((size_t)4*1024*H*2);
  bf16* Wt_l  = (bf16*)alloc((size_t)4*512*H*2);
  float* Bias_p = (float*)alloc((size_t)4*1024*4);
  float* Bias_l = (float*)alloc((size_t)4*512*4);
  bf16* T2    = (bf16*)alloc((size_t)12*1025*256*2);
  int* counts = (int*)alloc((size_t)(2*NP+NL)*4);
  int* rp_pp  = (int*)alloc((size_t)(NP+1)*4);
  int* cur_pp = (int*)alloc((size_t)NP*4);
  int* rp_lp  = (int*)alloc((size_t)(NP+1)*4);
  int* cur_lp = (int*)alloc((size_t)NP*4);
  int* rp_pl  = (int*)alloc((size_t)(NL+1)*4);
  int* cur_pl = (int*)alloc((size_t)NL*4);
  int2* e2_pp = (int2*)alloc((size_t)EPP*8);
  int2* e2_lp = (int2*)alloc((size_t)ELP*8);
  int2* e2_pl = (int2*)alloc((size_t)EPL*8);
  int Cpp = (NP + SCH - 1) / SCH;
  int Cpl = (NL + SCH - 1) / SCH;
  int* chsum = (int*)alloc((size_t)(2*Cpp + Cpl)*4);
  (void)ws_size; (void)n_in; (void)out_size;

  // --- prep (weights + RBF table) ---
  int prep_total = PREP_WP_N + PREP_WL_N + RBF_N;
  prep_all<<<(prep_total+255)/256, 256, 0, stream>>>(Wf, Wsv, bfv, bsv,
                                                     Wt_p, Bias_p, Wt_l, Bias_l, T2);
  // --- CSR build ---
  hipMemsetAsync(counts, 0, (size_t)(2*NP+NL)*4, stream);
  int* cnt_pp = counts; int* cnt_lp = counts + NP; int* cnt_pl = counts + 2*NP;
  int Etot = EPP + ELP + EPL;
  hist3_k<<<(Etot+255)/256, 256, 0, stream>>>(ei_pp+EPP, EPP, ei_lp+ELP, ELP, ei_pl+EPL, EPL,
                                              cnt_pp, cnt_lp, cnt_pl);
  chunksum_k<<<2*Cpp + Cpl, 256, 0, stream>>>(counts, NP, NL, Cpp, Cpl, chsum);
  scanmid_k<<<1, 192, 0, stream>>>(chsum, Cpp, Cpl, NP, NL, rp_pp, rp_lp, rp_pl);
  scanfin_k<<<2*Cpp + Cpl, 1024, 0, stream>>>(counts, NP, NL, Cpp, Cpl, chsum,
                                              rp_pp, cur_pp, rp_lp, cur_lp, rp_pl, cur_pl);
  fill3_k<<<(Etot+255)/256, 256, 0, stream>>>(ei_pp, ea_pp, EPP, ei_lp, ea_lp, ELP,
                                              ei_pl, ea_pl, EPL,
                                              cur_pp, e2_pp, cur_lp, e2_lp, cur_pl, e2_pl);

  // --- embeddings ---
  embed2_k<<<(((size_t)(NP+NL)*H)+255)/256, 256, 0, stream>>>(
      x_protein, Wp, bp, xpA, xp_bf, NP, x_ligand, Wl, bl, xlA, xl_bf, NL);

  // --- layers ---
  float* xp_cur = xpA; float* xp_nxt = xpB;
  float* xl_cur = xlA; float* xl_nxt = xlB;
  int strips_p = NP >> 4, strips_l = NL >> 4;
  int tasks_p = 16 * ((strips_p + GR - 1) / GR);
  int tasks_l = 8  * ((strips_l + GR - 1) / GR);
  int tasks_total = tasks_p + tasks_l;
  int PB = (NP + 3) / 4, LB = (NL + 3) / 4;
  for (int l=0; l<4; l++){
    gemm_tables<<<(tasks_total+3)/4, 256, 0, stream>>>(
        xp_bf, Wt_p + (size_t)l*1024*H, Bias_p + l*1024, PT, strips_p, tasks_p,
        xl_bf, Wt_l + (size_t)l*512*H,  Bias_l + l*512,  LT, strips_l, tasks_total);
    node_update<<<PB + LB, 256, 0, stream>>>(PT, LT, xp_cur, xl_cur,
        rp_pp, e2_pp, rp_lp, e2_lp, rp_pl, e2_pl, T2,
        bn_w, bn_b, ln_w, ln_b, xp_nxt, xp_bf, xl_nxt, xl_bf, l, NP, NL, PB);
    float* t;
    t = xp_cur; xp_cur = xp_nxt; xp_nxt = t;
    t = xl_cur; xl_cur = xl_nxt; xl_nxt = t;
  }

  // --- output head ---
  final_k<<<NP, 128, 0, stream>>>(xp_cur, lno_w, lno_b, fc_w, fc_b, (float*)d_out, NP);
}

// Round 9
// 835.020 us; speedup vs baseline: 3.7768x; 1.0430x over previous
//
#include <hip/hip_runtime.h>
#include <hip/hip_bf16.h>
#include <math.h>

#define H 128

typedef __bf16 bf16x8 __attribute__((ext_vector_type(8)));
typedef float f32x4 __attribute__((ext_vector_type(4)));
typedef float f32x2 __attribute__((ext_vector_type(2)));
typedef __hip_bfloat16 bf16;
typedef unsigned int uint32;

static __device__ __forceinline__ float bf2f(bf16 v){ return __bfloat162float(v); }
static __device__ __forceinline__ bf16 f2bf(float v){ return __float2bfloat16(v); }
static __device__ __forceinline__ float u2f_lo(uint32 v){ return __uint_as_float(v << 16); }
static __device__ __forceinline__ float u2f_hi(uint32 v){ return __uint_as_float(v & 0xffff0000u); }

union bfpack { struct { bf16 lo, hi; } h; uint32 u; };
static __device__ __forceinline__ uint32 pack_bf2(float a, float b){
  bfpack p; p.h.lo = f2bf(a); p.h.hi = f2bf(b); return p.u;
}

// ---------------------------------------------------------------------------
// Table layouts: PT[node][1024], LT[node][512] (see earlier rounds), weights
// permuted within 64-col groups, nearest-bin RBF table T2[pr][1025][256].
// CSR edge info packed as int2 {src, float_bits(d)}.
// ---------------------------------------------------------------------------
static __device__ __forceinline__ int unperm64(int r){
  int base = r & ~63; int g = r & 63; int t = g >> 4; int j = g & 15;
  return base + 4*j + t;
}

#define PREP_WP_N (4*1024*128)
#define PREP_WL_N (4*512*128)
#define RBF_N     (12*1025*128)

__global__ void prep_all(const float* __restrict__ Wf, const float* __restrict__ Ws,
                         const float* __restrict__ bfv, const float* __restrict__ bsv,
                         bf16* __restrict__ Wt_p, float* __restrict__ Bias_p,
                         bf16* __restrict__ Wt_l, float* __restrict__ Bias_l,
                         bf16* __restrict__ T2){
  int t = blockIdx.x*blockDim.x + threadIdx.x;
  if (t < PREP_WP_N){
    int k = t & 127; int idx = t >> 7;
    int rs = idx & 1023; int l = idx >> 10;
    int r = unperm64(rs);
    int rel, c, row0; const float* W; float bias = 0.f;
    if (r < 256)      { rel=0; c=r>>1;        row0=128; W = (r&1)?Ws:Wf; }
    else if (r < 512) { rel=2; c=(r-256)>>1;  row0=128; W = (r&1)?Ws:Wf; }
    else if (r < 640) { rel=0; c=r-512; row0=0; W=Wf; bias = bfv[(l*3+rel)*H+c]; }
    else if (r < 768) { rel=0; c=r-640; row0=0; W=Ws; bias = bsv[(l*3+rel)*H+c]; }
    else if (r < 896) { rel=1; c=r-768; row0=0; W=Wf; bias = bfv[(l*3+rel)*H+c]; }
    else              { rel=1; c=r-896; row0=0; W=Ws; bias = bsv[(l*3+rel)*H+c]; }
    Wt_p[t] = f2bf(W[((size_t)(l*3+rel)*272 + row0 + k)*H + c]);
    if (k == 0) Bias_p[l*1024 + r] = bias;
    return;
  }
  t -= PREP_WP_N;
  if (t < PREP_WL_N){
    int k = t & 127; int idx = t >> 7;
    int rs = idx & 511; int l = idx >> 9;
    int r = unperm64(rs);
    int rel, c, row0; const float* W; float bias = 0.f;
    if (r < 256)      { rel=1; c=r>>1;   row0=128; W = (r&1)?Ws:Wf; }
    else if (r < 384) { rel=2; c=r-256; row0=0; W=Wf; bias = bfv[(l*3+rel)*H+c]; }
    else              { rel=2; c=r-384; row0=0; W=Ws; bias = bsv[(l*3+rel)*H+c]; }
    Wt_l[t] = f2bf(W[((size_t)(l*3+rel)*272 + row0 + k)*H + c]);
    if (k == 0) Bias_l[l*512 + r] = bias;
    return;
  }
  t -= PREP_WL_N;
  if (t < RBF_N){
    int c = t & 127;
    int b = (t >> 7) % 1025;
    int pr = t / (1025*128);
    float d0 = (float)b * 0.0078125f;
    const float* wf = Wf + ((size_t)pr*272 + 256)*H + c;
    const float* ws = Ws + ((size_t)pr*272 + 256)*H + c;
    float f0=0.f, s0=0.f;
    #pragma unroll
    for (int k=0;k<16;k++){
      float o = 0.533333333f*(float)k;
      float tt = d0 - o;
      float r0 = __expf(-1.7578125f*tt*tt);
      f0 += r0*wf[(size_t)k*H]; s0 += r0*ws[(size_t)k*H];
    }
    bf16* o = T2 + ((size_t)(pr*1025 + b))*256 + 2*c;
    o[0]=f2bf(f0); o[1]=f2bf(s0);
  }
}

// ---------------------------------------------------------------------------
// CSR build: hist -> chunk sums -> mid scan -> final scan -> fill
// ---------------------------------------------------------------------------
__global__ void hist3_k(const int* __restrict__ dpp, int Epp,
                        const int* __restrict__ dlp, int Elp,
                        const int* __restrict__ dpl, int Epl,
                        int* __restrict__ cpp, int* __restrict__ clp, int* __restrict__ cpl){
  int e = blockIdx.x*blockDim.x + threadIdx.x;
  if (e < Epp) atomicAdd(&cpp[dpp[e]], 1);
  else if (e < Epp+Elp) atomicAdd(&clp[dlp[e-Epp]], 1);
  else if (e < Epp+Elp+Epl) atomicAdd(&cpl[dpl[e-Epp-Elp]], 1);
}

#define SCH 1024   // scan chunk size

__global__ void __launch_bounds__(256) chunksum_k(
    const int* __restrict__ counts, int NP, int NL, int Cpp, int Cpl,
    int* __restrict__ chsum){
  __shared__ int wred[4];
  int b = blockIdx.x;
  const int* cnt; int n; int ch;
  if (b < Cpp){ cnt = counts; n = NP; ch = b; }
  else if (b < 2*Cpp){ cnt = counts + NP; n = NP; ch = b - Cpp; }
  else { cnt = counts + 2*NP; n = NL; ch = b - 2*Cpp; }
  int base = ch * SCH;
  int tid = threadIdx.x;
  int s = 0;
  #pragma unroll
  for (int j=0;j<SCH/256;j++){
    int i = base + tid + j*256;
    if (i < n) s += cnt[i];
  }
  #pragma unroll
  for (int o=32;o>=1;o>>=1) s += __shfl_xor(s,o,64);
  if ((tid & 63) == 0) wred[tid>>6] = s;
  __syncthreads();
  if (tid == 0) chsum[b] = wred[0]+wred[1]+wred[2]+wred[3];
}

__global__ void __launch_bounds__(192) scanmid_k(
    int* __restrict__ chsum, int Cpp, int Cpl, int NP, int NL,
    int* __restrict__ rp_pp, int* __restrict__ rp_lp, int* __restrict__ rp_pl){
  int wid = threadIdx.x >> 6, lane = threadIdx.x & 63;
  int C, off; int* rp_end; int n;
  if (wid == 0){ C = Cpp; off = 0;      rp_end = rp_pp; n = NP; }
  else if (wid == 1){ C = Cpp; off = Cpp; rp_end = rp_lp; n = NP; }
  else { C = Cpl; off = 2*Cpp; rp_end = rp_pl; n = NL; }
  int v = (lane < C) ? chsum[off + lane] : 0;
  int x = v;
  #pragma unroll
  for (int o=1;o<64;o<<=1){
    int y = __shfl_up(x, o, 64);
    if (lane >= o) x += y;
  }
  if (lane < C) chsum[off + lane] = x - v;
  if (lane == 63) rp_end[n] = x;
}

__global__ void __launch_bounds__(1024) scanfin_k(
    const int* __restrict__ counts, int NP, int NL, int Cpp, int Cpl,
    const int* __restrict__ chsum,
    int* __restrict__ rp_pp, int* __restrict__ cur_pp,
    int* __restrict__ rp_lp, int* __restrict__ cur_lp,
    int* __restrict__ rp_pl, int* __restrict__ cur_pl){
  __shared__ int wsum[16];
  int b = blockIdx.x;
  const int* cnt; int n, ch; int* rp; int* cur;
  if (b < Cpp){ cnt = counts; n = NP; ch = b; rp = rp_pp; cur = cur_pp; }
  else if (b < 2*Cpp){ cnt = counts + NP; n = NP; ch = b - Cpp; rp = rp_lp; cur = cur_lp; }
  else { cnt = counts + 2*NP; n = NL; ch = b - 2*Cpp; rp = rp_pl; cur = cur_pl; }
  int tid = threadIdx.x, lane = tid & 63, wid = tid >> 6;
  int i = ch*SCH + tid;
  int v = (i < n) ? cnt[i] : 0;
  int x = v;
  #pragma unroll
  for (int o=1;o<64;o<<=1){
    int y = __shfl_up(x, o, 64);
    if (lane >= o) x += y;
  }
  if (lane == 63) wsum[wid] = x;
  __syncthreads();
  if (wid == 0 && lane < 16){
    int w = wsum[lane];
    #pragma unroll
    for (int o=1;o<16;o<<=1){
      int y = __shfl_up(w, o, 64);
      if (lane >= o) w += y;
    }
    wsum[lane] = w;
  }
  __syncthreads();
  int waveoff = (wid == 0) ? 0 : wsum[wid-1];
  int ex = chsum[b] + waveoff + x - v;
  if (i < n){ rp[i] = ex; cur[i] = ex; }
}

// fill packed int2 {src, d_bits}
__global__ void fill3_k(const int* __restrict__ ei_pp, const float* __restrict__ ea_pp, int Epp,
                        const int* __restrict__ ei_lp, const float* __restrict__ ea_lp, int Elp,
                        const int* __restrict__ ei_pl, const float* __restrict__ ea_pl, int Epl,
                        int* __restrict__ cur_pp, int2* __restrict__ e2_pp,
                        int* __restrict__ cur_lp, int2* __restrict__ e2_lp,
                        int* __restrict__ cur_pl, int2* __restrict__ e2_pl){
  int e = blockIdx.x*blockDim.x + threadIdx.x;
  if (e < Epp){
    int p = atomicAdd(&cur_pp[ei_pp[Epp + e]], 1);
    e2_pp[p] = make_int2(ei_pp[e], __float_as_int(ea_pp[e]));
  } else if (e < Epp+Elp){
    int i = e - Epp;
    int p = atomicAdd(&cur_lp[ei_lp[Elp + i]], 1);
    e2_lp[p] = make_int2(ei_lp[i], __float_as_int(ea_lp[i]));
  } else if (e < Epp+Elp+Epl){
    int i = e - Epp - Elp;
    int p = atomicAdd(&cur_pl[ei_pl[Epl + i]], 1);
    e2_pl[p] = make_int2(ei_pl[i], __float_as_int(ea_pl[i]));
  }
}

// ---------------------------------------------------------------------------
// Node embedding (merged): x @ W[6,128] + b
// ---------------------------------------------------------------------------
__global__ void embed2_k(const float* __restrict__ Xp, const float* __restrict__ Wp,
                         const float* __restrict__ bp, float* __restrict__ Xpo,
                         bf16* __restrict__ Xpb, int NP,
                         const float* __restrict__ Xl, const float* __restrict__ Wl,
                         const float* __restrict__ bl, float* __restrict__ Xlo,
                         bf16* __restrict__ Xlb, int NL){
  int idx = blockIdx.x*blockDim.x + threadIdx.x;
  const float* Xin; const float* W; const float* b; float* Xout; bf16* Xbf;
  if (idx < NP*H){ Xin=Xp; W=Wp; b=bp; Xout=Xpo; Xbf=Xpb; }
  else { idx -= NP*H; if (idx >= NL*H) return; Xin=Xl; W=Wl; b=bl; Xout=Xlo; Xbf=Xlb; }
  int n = idx >> 7, c = idx & 127;
  float acc = b[c];
  #pragma unroll
  for (int k=0;k<6;k++) acc += Xin[n*6+k] * W[k*H+c];
  Xout[idx] = acc;
  Xbf[idx] = f2bf(acc);
}

// ---------------------------------------------------------------------------
// Table GEMM v4 (B-resident): wave owns one 64-col group, iterates row strips.
// ---------------------------------------------------------------------------
#define GR 8
__global__ void __launch_bounds__(256) gemm_tables(
    const bf16* __restrict__ Xp, const bf16* __restrict__ Wtp,
    const float* __restrict__ Biasp, bf16* __restrict__ Outp,
    int strips_p, int tasks_p,
    const bf16* __restrict__ Xl, const bf16* __restrict__ Wtl,
    const float* __restrict__ Biasl, bf16* __restrict__ Outl,
    int strips_l, int tasks_total){
  int wt = blockIdx.x*4 + (threadIdx.x >> 6);
  if (wt >= tasks_total) return;
  const bf16 *X, *Wt; const float* Bias; bf16* Out; int N, strips, g, chunk;
  if (wt < tasks_p){
    X=Xp; Wt=Wtp; Bias=Biasp; Out=Outp; N=1024; strips=strips_p;
    g = wt & 15; chunk = wt >> 4;
  } else {
    int w = wt - tasks_p;
    X=Xl; Wt=Wtl; Bias=Biasl; Out=Outl; N=512; strips=strips_l;
    g = w & 7; chunk = w >> 3;
  }
  int n0 = g << 6;
  int lane = threadIdx.x & 63;
  int lr = lane & 15, lq = lane >> 4;
  const bf16x8* B0 = (const bf16x8*)(const void*)(Wt + (size_t)(n0      + lr)*H);
  const bf16x8* B1 = (const bf16x8*)(const void*)(Wt + (size_t)(n0 + 16 + lr)*H);
  const bf16x8* B2 = (const bf16x8*)(const void*)(Wt + (size_t)(n0 + 32 + lr)*H);
  const bf16x8* B3 = (const bf16x8*)(const void*)(Wt + (size_t)(n0 + 48 + lr)*H);
  bf16x8 b0_0=B0[lq], b0_1=B0[4+lq], b0_2=B0[8+lq], b0_3=B0[12+lq];
  bf16x8 b1_0=B1[lq], b1_1=B1[4+lq], b1_2=B1[8+lq], b1_3=B1[12+lq];
  bf16x8 b2_0=B2[lq], b2_1=B2[4+lq], b2_2=B2[8+lq], b2_3=B2[12+lq];
  bf16x8 b3_0=B3[lq], b3_1=B3[4+lq], b3_2=B3[8+lq], b3_3=B3[12+lq];
  float4 bias = ((const float4*)(const void*)(Bias + n0))[lr];
  #pragma unroll 2
  for (int r=0;r<GR;r++){
    int strip = chunk*GR + r;
    if (strip >= strips) break;
    int m0 = strip << 4;
    const bf16x8* A = (const bf16x8*)(const void*)(X + (size_t)(m0+lr)*H);
    bf16x8 a0 = A[lq], a1 = A[4+lq], a2 = A[8+lq], a3 = A[12+lq];
    f32x4 acc0 = {0.f,0.f,0.f,0.f}, acc1 = acc0, acc2 = acc0, acc3 = acc0;
    acc0 = __builtin_amdgcn_mfma_f32_16x16x32_bf16(a0, b0_0, acc0, 0, 0, 0);
    acc1 = __builtin_amdgcn_mfma_f32_16x16x32_bf16(a0, b1_0, acc1, 0, 0, 0);
    acc2 = __builtin_amdgcn_mfma_f32_16x16x32_bf16(a0, b2_0, acc2, 0, 0, 0);
    acc3 = __builtin_amdgcn_mfma_f32_16x16x32_bf16(a0, b3_0, acc3, 0, 0, 0);
    acc0 = __builtin_amdgcn_mfma_f32_16x16x32_bf16(a1, b0_1, acc0, 0, 0, 0);
    acc1 = __builtin_amdgcn_mfma_f32_16x16x32_bf16(a1, b1_1, acc1, 0, 0, 0);
    acc2 = __builtin_amdgcn_mfma_f32_16x16x32_bf16(a1, b2_1, acc2, 0, 0, 0);
    acc3 = __builtin_amdgcn_mfma_f32_16x16x32_bf16(a1, b3_1, acc3, 0, 0, 0);
    acc0 = __builtin_amdgcn_mfma_f32_16x16x32_bf16(a2, b0_2, acc0, 0, 0, 0);
    acc1 = __builtin_amdgcn_mfma_f32_16x16x32_bf16(a2, b1_2, acc1, 0, 0, 0);
    acc2 = __builtin_amdgcn_mfma_f32_16x16x32_bf16(a2, b2_2, acc2, 0, 0, 0);
    acc3 = __builtin_amdgcn_mfma_f32_16x16x32_bf16(a2, b3_2, acc3, 0, 0, 0);
    acc0 = __builtin_amdgcn_mfma_f32_16x16x32_bf16(a3, b0_3, acc0, 0, 0, 0);
    acc1 = __builtin_amdgcn_mfma_f32_16x16x32_bf16(a3, b1_3, acc1, 0, 0, 0);
    acc2 = __builtin_amdgcn_mfma_f32_16x16x32_bf16(a3, b2_3, acc2, 0, 0, 0);
    acc3 = __builtin_amdgcn_mfma_f32_16x16x32_bf16(a3, b3_3, acc3, 0, 0, 0);
    #pragma unroll
    for (int rr=0;rr<4;rr++){
      int row = m0 + lq*4 + rr;
      uint2 pk;
      pk.x = pack_bf2(acc0[rr] + bias.x, acc1[rr] + bias.y);
      pk.y = pack_bf2(acc2[rr] + bias.z, acc3[rr] + bias.w);
      *(uint2*)(void*)(Out + (size_t)row*N + n0 + 4*lr) = pk;
    }
  }
}

// ---------------------------------------------------------------------------
// Node-update helpers
// ---------------------------------------------------------------------------
// sigmoid(f) * softplus(s), minimal-op form.
// softplus via ln2*log2(1+exp2(min(s,60)*log2e)) — exact in f32 for s<=60,
// overflow-safe (s>60 => softplus(s)==s to f32 precision, clamp keeps finite).
static __device__ __forceinline__ float act_msg(float f, float s){
  float sig = __builtin_amdgcn_rcpf(1.f + __builtin_amdgcn_exp2f(f * -1.44269504f));
  float e   = __builtin_amdgcn_exp2f(fminf(s, 60.f) * 1.44269504f);
  float sp  = 0.69314718f * __builtin_amdgcn_logf(1.f + e);
  return sig * sp;
}

#define BN_RSQ 0.9999950000374997f   /* 1/sqrt(1+1e-5) */

static __device__ __forceinline__ void edge_nb(uint2 g, uint2 t,
                                               f32x2 fd2, f32x2 sd2, f32x2& acc){
  f32x2 f2, s2;
  f2.x = u2f_lo(g.x) + u2f_lo(t.x);
  f2.y = u2f_lo(g.y) + u2f_lo(t.y);
  s2.x = u2f_hi(g.x) + u2f_hi(t.x);
  s2.y = u2f_hi(g.y) + u2f_hi(t.y);
  f2 += fd2; s2 += sd2;
  acc.x += act_msg(f2.x, s2.x);
  acc.y += act_msg(f2.y, s2.y);
}

static __device__ __forceinline__ void ln_stats_w(float v0, float v1, float& mu, float& var){
  float s = v0 + v1, q = v0*v0 + v1*v1;
  #pragma unroll
  for (int o=32;o>=1;o>>=1){ s += __shfl_xor(s,o,64); q += __shfl_xor(q,o,64); }
  mu = s * (1.f/128.f);
  var = q * (1.f/128.f) - mu*mu;
}

// CSR aggregation: 64-edge chunk of {src,bin} in registers; per edge
// 2 readlane (SALU) + 2 gathers. Rotation-free 3-stage modulo schedule:
// the steady loop is unrolled x3 so registers keep fixed names (no v_movs).
static __device__ __forceinline__ void aggregate(
    const int2* __restrict__ ev_arr, int e0, int e1,
    const uint2* __restrict__ G, int gstride, int goff,
    const uint2* __restrict__ Tb, int lane,
    f32x2 fd2, f32x2 sd2, f32x2& acc)
{
  for (int base = e0; base < e1; base += 64){
    int idx = base + lane;
    int2 ev = ev_arr[(idx < e1) ? idx : (e1-1)];
    float dd = __int_as_float(ev.y);
    int bnv = (int)__fmaf_rn(dd, 128.f, 0.5f);
    bnv = (bnv > 1024) ? 1024 : bnv;
    int cnt = e1 - base; cnt = (cnt > 64) ? 64 : cnt;
    uint2 gA, tA, gB, tB, gC, tC;
    #define LDJ(gX, tX, j) { \
      int s_ = __builtin_amdgcn_readlane(ev.x, (j)); \
      int b_ = __builtin_amdgcn_readlane(bnv, (j)); \
      gX = G[(size_t)s_*gstride + goff + lane]; \
      tX = Tb[(size_t)b_*64 + lane]; }
    LDJ(gA, tA, 0);
    if (cnt > 1) LDJ(gB, tB, 1);
    if (cnt > 2) LDJ(gC, tC, 2);
    int j = 0;
    for (; j+5 < cnt; j += 3){
      edge_nb(gA, tA, fd2, sd2, acc); LDJ(gA, tA, j+3);
      edge_nb(gB, tB, fd2, sd2, acc); LDJ(gB, tB, j+4);
      edge_nb(gC, tC, fd2, sd2, acc); LDJ(gC, tC, j+5);
    }
    int rem = cnt - j;              // 1..5
    edge_nb(gA, tA, fd2, sd2, acc);
    if (rem > 3) LDJ(gA, tA, j+3);
    if (rem > 1) edge_nb(gB, tB, fd2, sd2, acc);
    if (rem > 4) LDJ(gB, tB, j+4);
    if (rem > 2) edge_nb(gC, tC, fd2, sd2, acc);
    if (rem > 3) edge_nb(gA, tA, fd2, sd2, acc);
    if (rem > 4) edge_nb(gB, tB, fd2, sd2, acc);
    #undef LDJ
  }
}

// ---------------------------------------------------------------------------
// Merged node update: wave per node. Blocks [0,PB) protein, rest ligand.
// ---------------------------------------------------------------------------
__global__ void __launch_bounds__(256) node_update(
    const bf16* __restrict__ PT, const bf16* __restrict__ LT,
    const float* __restrict__ xp, const float* __restrict__ xl,
    const int* __restrict__ pp_rp, const int2* __restrict__ pp_e2,
    const int* __restrict__ lp_rp, const int2* __restrict__ lp_e2,
    const int* __restrict__ pl_rp, const int2* __restrict__ pl_e2,
    const bf16* __restrict__ T2,
    const float* __restrict__ bn_w, const float* __restrict__ bn_b,
    const float* __restrict__ ln_w, const float* __restrict__ ln_b,
    float* __restrict__ xp_out, bf16* __restrict__ xp_bf,
    float* __restrict__ xl_out, bf16* __restrict__ xl_bf,
    int layer, int NP, int NL, int PB)
{
  int wave = threadIdx.x >> 6;
  int lane = threadIdx.x & 63;
  const uint2* PTg = (const uint2*)(const void*)PT;
  if ((int)blockIdx.x < PB){
    int node = blockIdx.x*4 + wave;
    if (node >= NP) return;
    float2 x = ((const float2*)(const void*)(xp + (size_t)node*H))[lane];
    const uint32* PTu = (const uint32*)(const void*)PT;
    const uint2*  LTg = (const uint2*)(const void*)LT;
    float o1_0, o1_1, o2_0, o2_1;
    { // relation pp
      int pr = layer*3 + 0;
      uint32 fdp = PTu[(size_t)node*512 + 256 + lane];
      uint32 sdp = PTu[(size_t)node*512 + 320 + lane];
      const uint2* Tb = (const uint2*)(const void*)(T2 + (size_t)pr*1025*256);
      f32x2 fd2 = {u2f_lo(fdp), u2f_hi(fdp)};
      f32x2 sd2 = {u2f_lo(sdp), u2f_hi(sdp)};
      f32x2 acc = {0.f, 0.f};
      aggregate(pp_e2, pp_rp[node], pp_rp[node+1], PTg, 256, 0, Tb, lane, fd2, sd2, acc);
      float2 bw = ((const float2*)(const void*)(bn_w + pr*H))[lane];
      float2 bb = ((const float2*)(const void*)(bn_b + pr*H))[lane];
      float2 lw = ((const float2*)(const void*)(ln_w + pr*H))[lane];
      float2 lb = ((const float2*)(const void*)(ln_b + pr*H))[lane];
      float v0 = acc.x * (bw.x * BN_RSQ) + bb.x + x.x;
      float v1 = acc.y * (bw.y * BN_RSQ) + bb.y + x.y;
      float mu, var; ln_stats_w(v0, v1, mu, var);
      float rs = rsqrtf(var + 1e-5f);
      o1_0 = fmaxf((v0-mu)*rs*lw.x + lb.x, 0.f) + x.x;
      o1_1 = fmaxf((v1-mu)*rs*lw.y + lb.y, 0.f) + x.y;
    }
    { // relation lp
      int pr = layer*3 + 1;
      uint32 fdp = PTu[(size_t)node*512 + 384 + lane];
      uint32 sdp = PTu[(size_t)node*512 + 448 + lane];
      const uint2* Tb = (const uint2*)(const void*)(T2 + (size_t)pr*1025*256);
      f32x2 fd2 = {u2f_lo(fdp), u2f_hi(fdp)};
      f32x2 sd2 = {u2f_lo(sdp), u2f_hi(sdp)};
      f32x2 acc = {0.f, 0.f};
      aggregate(lp_e2, lp_rp[node], lp_rp[node+1], LTg, 128, 0, Tb, lane, fd2, sd2, acc);
      float2 bw = ((const float2*)(const void*)(bn_w + pr*H))[lane];
      float2 bb = ((const float2*)(const void*)(bn_b + pr*H))[lane];
      float2 lw = ((const float2*)(const void*)(ln_w + pr*H))[lane];
      float2 lb = ((const float2*)(const void*)(ln_b + pr*H))[lane];
      float v0 = acc.x * (bw.x * BN_RSQ) + bb.x + x.x;
      float v1 = acc.y * (bw.y * BN_RSQ) + bb.y + x.y;
      float mu, var; ln_stats_w(v0, v1, mu, var);
      float rs = rsqrtf(var + 1e-5f);
      o2_0 = fmaxf((v0-mu)*rs*lw.x + lb.x, 0.f) + x.x;
      o2_1 = fmaxf((v1-mu)*rs*lw.y + lb.y, 0.f) + x.y;
    }
    float out0 = o1_0 + o2_0, out1 = o1_1 + o2_1;
    ((float2*)(void*)(xp_out + (size_t)node*H))[lane] = make_float2(out0, out1);
    ((uint32*)(void*)(xp_bf + (size_t)node*H))[lane] = pack_bf2(out0, out1);
  } else {
    int node = (blockIdx.x - PB)*4 + wave;
    if (node >= NL) return;
    float2 x = ((const float2*)(const void*)(xl + (size_t)node*H))[lane];
    const uint32* LTu = (const uint32*)(const void*)LT;
    int pr = layer*3 + 2;
    uint32 fdp = LTu[(size_t)node*256 + 128 + lane];
    uint32 sdp = LTu[(size_t)node*256 + 192 + lane];
    const uint2* Tb = (const uint2*)(const void*)(T2 + (size_t)pr*1025*256);
    f32x2 fd2 = {u2f_lo(fdp), u2f_hi(fdp)};
    f32x2 sd2 = {u2f_lo(sdp), u2f_hi(sdp)};
    f32x2 acc = {0.f, 0.f};
    aggregate(pl_e2, pl_rp[node], pl_rp[node+1], PTg, 256, 64, Tb, lane, fd2, sd2, acc);
    float2 bw = ((const float2*)(const void*)(bn_w + pr*H))[lane];
    float2 bb = ((const float2*)(const void*)(bn_b + pr*H))[lane];
    float2 lw = ((const float2*)(const void*)(ln_w + pr*H))[lane];
    float2 lb = ((const float2*)(const void*)(ln_b + pr*H))[lane];
    float v0 = acc.x * (bw.x * BN_RSQ) + bb.x + x.x;
    float v1 = acc.y * (bw.y * BN_RSQ) + bb.y + x.y;
    float mu, var; ln_stats_w(v0, v1, mu, var);
    float rs = rsqrtf(var + 1e-5f);
    float out0 = fmaxf((v0-mu)*rs*lw.x + lb.x, 0.f) + x.x;
    float out1 = fmaxf((v1-mu)*rs*lw.y + lb.y, 0.f) + x.y;
    ((float2*)(void*)(xl_out + (size_t)node*H))[lane] = make_float2(out0, out1);
    ((uint32*)(void*)(xl_bf + (size_t)node*H))[lane] = pack_bf2(out0, out1);
  }
}

// ---------------------------------------------------------------------------
// Final: LN(xp) @ fc_w[128,21] + fc_b
// ---------------------------------------------------------------------------
__global__ void __launch_bounds__(128) final_k(const float* __restrict__ xp,
    const float* __restrict__ lnw, const float* __restrict__ lnb,
    const float* __restrict__ fcw, const float* __restrict__ fcb,
    float* __restrict__ out, int N){
  __shared__ float sm[4];
  __shared__ float lnv[128];
  int node = blockIdx.x, c = threadIdx.x;
  float v = xp[(size_t)node*H + c];
  float s = v, q = v*v;
  #pragma unroll
  for (int o=32;o>=1;o>>=1){ s += __shfl_xor(s,o,64); q += __shfl_xor(q,o,64); }
  __syncthreads();
  if ((c & 63) == 0){ sm[(c>>6)*2] = s; sm[(c>>6)*2+1] = q; }
  __syncthreads();
  float S = sm[0] + sm[2], Q = sm[1] + sm[3];
  float mu = S * (1.f/128.f);
  float var = Q * (1.f/128.f) - mu*mu;
  float ln = (v-mu)*rsqrtf(var+1e-5f)*lnw[c] + lnb[c];
  lnv[c] = ln;
  __syncthreads();
  if (c < 21){
    float a = fcb[c];
    #pragma unroll 4
    for (int i=0;i<128;i++) a += lnv[i]*fcw[i*21+c];
    out[(size_t)node*21 + c] = a;
  }
}

// ---------------------------------------------------------------------------
extern "C" void kernel_launch(void* const* d_in, const int* in_sizes, int n_in,
                              void* d_out, int out_size, void* d_ws, size_t ws_size,
                              hipStream_t stream){
  const float* x_protein = (const float*)d_in[0];
  const float* x_ligand  = (const float*)d_in[1];
  const int*   ei_pp = (const int*)d_in[2];
  const float* ea_pp = (const float*)d_in[3];
  const int*   ei_lp = (const int*)d_in[4];
  const float* ea_lp = (const float*)d_in[5];
  const int*   ei_pl = (const int*)d_in[6];
  const float* ea_pl = (const float*)d_in[7];
  const float* Wp  = (const float*)d_in[8];
  const float* bp  = (const float*)d_in[9];
  const float* Wl  = (const float*)d_in[10];
  const float* bl  = (const float*)d_in[11];
  const float* Wf  = (const float*)d_in[12];
  const float* bfv = (const float*)d_in[13];
  const float* Wsv = (const float*)d_in[14];
  const float* bsv = (const float*)d_in[15];
  const float* bn_w = (const float*)d_in[16];
  const float* bn_b = (const float*)d_in[17];
  const float* ln_w = (const float*)d_in[18];
  const float* ln_b = (const float*)d_in[19];
  const float* lno_w = (const float*)d_in[20];
  const float* lno_b = (const float*)d_in[21];
  const float* fc_w = (const float*)d_in[22];
  const float* fc_b = (const float*)d_in[23];

  int NP  = in_sizes[0]/6, NL = in_sizes[1]/6;
  int EPP = in_sizes[3], ELP = in_sizes[5], EPL = in_sizes[7];

  char* ws = (char*)d_ws;
  size_t off = 0;
  auto alloc = [&](size_t bytes)->void*{
    void* p = ws + off; off = (off + bytes + 255) & ~(size_t)255; return p;
  };

  float* xpA = (float*)alloc((size_t)NP*H*4);
  float* xpB = (float*)alloc((size_t)NP*H*4);
  float* xlA = (float*)alloc((size_t)NL*H*4);
  float* xlB = (float*)alloc((size_t)NL*H*4);
  bf16* xp_bf = (bf16*)alloc((size_t)NP*H*2);
  bf16* xl_bf = (bf16*)alloc((size_t)NL*H*2);
  bf16* PT    = (bf16*)alloc((size_t)NP*1024*2);
  bf16* LT    = (bf16*)alloc((size_t)NL*512*2);
  bf16* Wt_p  = (bf16*)alloc((size_t)4*1024*H*2);
  bf16* Wt_l  = (bf16*)alloc((size_t)4*512*H*2);
  float* Bias_p = (float*)alloc((size_t)4*1024*4);
  float* Bias_l = (float*)alloc((size_t)4*512*4);
  bf16* T2    = (bf16*)alloc((size_t)12*1025*256*2);
  int* counts = (int*)alloc((size_t)(2*NP+NL)*4);
  int* rp_pp  = (int*)alloc((size_t)(NP+1)*4);
  int* cur_pp = (int*)alloc((size_t)NP*4);
  int* rp_lp  = (int*)alloc((size_t)(NP+1)*4);
  int* cur_lp = (int*)alloc((size_t)NP*4);
  int* rp_pl  = (int*)alloc((size_t)(NL+1)*4);
  int* cur_pl = (int*)alloc((size_t)NL*4);
  int2* e2_pp = (int2*)alloc((size_t)EPP*8);
  int2* e2_lp = (int2*)alloc((size_t)ELP*8);
  int2* e2_pl = (int2*)alloc((size_t)EPL*8);
  int Cpp = (NP + SCH - 1) / SCH;
  int Cpl = (NL + SCH - 1) / SCH;
  int* chsum = (int*)alloc((size_t)(2*Cpp + Cpl)*4);
  (void)ws_size; (void)n_in; (void)out_size;

  // --- prep (weights + RBF table) ---
  int prep_total = PREP_WP_N + PREP_WL_N + RBF_N;
  prep_all<<<(prep_total+255)/256, 256, 0, stream>>>(Wf, Wsv, bfv, bsv,
                                                     Wt_p, Bias_p, Wt_l, Bias_l, T2);
  // --- CSR build ---
  hipMemsetAsync(counts, 0, (size_t)(2*NP+NL)*4, stream);
  int* cnt_pp = counts; int* cnt_lp = counts + NP; int* cnt_pl = counts + 2*NP;
  int Etot = EPP + ELP + EPL;
  hist3_k<<<(Etot+255)/256, 256, 0, stream>>>(ei_pp+EPP, EPP, ei_lp+ELP, ELP, ei_pl+EPL, EPL,
                                              cnt_pp, cnt_lp, cnt_pl);
  chunksum_k<<<2*Cpp + Cpl, 256, 0, stream>>>(counts, NP, NL, Cpp, Cpl, chsum);
  scanmid_k<<<1, 192, 0, stream>>>(chsum, Cpp, Cpl, NP, NL, rp_pp, rp_lp, rp_pl);
  scanfin_k<<<2*Cpp + Cpl, 1024, 0, stream>>>(counts, NP, NL, Cpp, Cpl, chsum,
                                              rp_pp, cur_pp, rp_lp, cur_lp, rp_pl, cur_pl);
  fill3_k<<<(Etot+255)/256, 256, 0, stream>>>(ei_pp, ea_pp, EPP, ei_lp, ea_lp, ELP,
                                              ei_pl, ea_pl, EPL,
                                              cur_pp, e2_pp, cur_lp, e2_lp, cur_pl, e2_pl);

  // --- embeddings ---
  embed2_k<<<(((size_t)(NP+NL)*H)+255)/256, 256, 0, stream>>>(
      x_protein, Wp, bp, xpA, xp_bf, NP, x_ligand, Wl, bl, xlA, xl_bf, NL);

  // --- layers ---
  float* xp_cur = xpA; float* xp_nxt = xpB;
  float* xl_cur = xlA; float* xl_nxt = xlB;
  int strips_p = NP >> 4, strips_l = NL >> 4;
  int tasks_p = 16 * ((strips_p + GR - 1) / GR);
  int tasks_l = 8  * ((strips_l + GR - 1) / GR);
  int tasks_total = tasks_p + tasks_l;
  int PB = (NP + 3) / 4, LB = (NL + 3) / 4;
  for (int l=0; l<4; l++){
    gemm_tables<<<(tasks_total+3)/4, 256, 0, stream>>>(
        xp_bf, Wt_p + (size_t)l*1024*H, Bias_p + l*1024, PT, strips_p, tasks_p,
        xl_bf, Wt_l + (size_t)l*512*H,  Bias_l + l*512,  LT, strips_l, tasks_total);
    node_update<<<PB + LB, 256, 0, stream>>>(PT, LT, xp_cur, xl_cur,
        rp_pp, e2_pp, rp_lp, e2_lp, rp_pl, e2_pl, T2,
        bn_w, bn_b, ln_w, ln_b, xp_nxt, xp_bf, xl_nxt, xl_bf, l, NP, NL, PB);
    float* t;
    t = xp_cur; xp_cur = xp_nxt; xp_nxt = t;
    t = xl_cur; xl_cur = xl_nxt; xl_nxt = t;
  }

  // --- output head ---
  final_k<<<NP, 128, 0, stream>>>(xp_cur, lno_w, lno_b, fc_w, fc_b, (float*)d_out, NP);
}

// Round 10
// 817.422 us; speedup vs baseline: 3.8581x; 1.0215x over previous
//
#include <hip/hip_runtime.h>
#include <hip/hip_bf16.h>
#include <math.h>

#define H 128

typedef __bf16 bf16x8 __attribute__((ext_vector_type(8)));
typedef float f32x4 __attribute__((ext_vector_type(4)));
typedef float f32x2 __attribute__((ext_vector_type(2)));
typedef __hip_bfloat16 bf16;
typedef unsigned int uint32;

static __device__ __forceinline__ float bf2f(bf16 v){ return __bfloat162float(v); }
static __device__ __forceinline__ bf16 f2bf(float v){ return __float2bfloat16(v); }
static __device__ __forceinline__ float u2f_lo(uint32 v){ return __uint_as_float(v << 16); }
static __device__ __forceinline__ float u2f_hi(uint32 v){ return __uint_as_float(v & 0xffff0000u); }

union bfpack { struct { bf16 lo, hi; } h; uint32 u; };
static __device__ __forceinline__ uint32 pack_bf2(float a, float b){
  bfpack p; p.h.lo = f2bf(a); p.h.hi = f2bf(b); return p.u;
}

// ---------------------------------------------------------------------------
// Table layouts: PT[node][1024], LT[node][512] (see earlier rounds), weights
// permuted within 64-col groups. RBF nearest-bin table now 256 bins
// (257 rows x 512 B x 12 rel-layers = 1.6 MB total -> L2-permanent).
// Bin error: h/2 * |rf'| ~ 0.0156*0.12 ~ 0.002/logit (negligible).
// CSR edge info packed as int2 {src, float_bits(d)}.
// ---------------------------------------------------------------------------
static __device__ __forceinline__ int unperm64(int r){
  int base = r & ~63; int g = r & 63; int t = g >> 4; int j = g & 15;
  return base + 4*j + t;
}

#define NBIN 256
#define PREP_WP_N (4*1024*128)
#define PREP_WL_N (4*512*128)
#define RBF_N     (12*(NBIN+1)*128)

__global__ void prep_all(const float* __restrict__ Wf, const float* __restrict__ Ws,
                         const float* __restrict__ bfv, const float* __restrict__ bsv,
                         bf16* __restrict__ Wt_p, float* __restrict__ Bias_p,
                         bf16* __restrict__ Wt_l, float* __restrict__ Bias_l,
                         bf16* __restrict__ T2,
                         const float* __restrict__ Xp, const float* __restrict__ Wp,
                         const float* __restrict__ bp, float* __restrict__ Xpo,
                         bf16* __restrict__ Xpb, int NP,
                         const float* __restrict__ Xl, const float* __restrict__ Wl,
                         const float* __restrict__ bl, float* __restrict__ Xlo,
                         bf16* __restrict__ Xlb, int NL){
  int t = blockIdx.x*blockDim.x + threadIdx.x;
  if (t < PREP_WP_N){
    int k = t & 127; int idx = t >> 7;
    int rs = idx & 1023; int l = idx >> 10;
    int r = unperm64(rs);
    int rel, c, row0; const float* W; float bias = 0.f;
    if (r < 256)      { rel=0; c=r>>1;        row0=128; W = (r&1)?Ws:Wf; }
    else if (r < 512) { rel=2; c=(r-256)>>1;  row0=128; W = (r&1)?Ws:Wf; }
    else if (r < 640) { rel=0; c=r-512; row0=0; W=Wf; bias = bfv[(l*3+rel)*H+c]; }
    else if (r < 768) { rel=0; c=r-640; row0=0; W=Ws; bias = bsv[(l*3+rel)*H+c]; }
    else if (r < 896) { rel=1; c=r-768; row0=0; W=Wf; bias = bfv[(l*3+rel)*H+c]; }
    else              { rel=1; c=r-896; row0=0; W=Ws; bias = bsv[(l*3+rel)*H+c]; }
    Wt_p[t] = f2bf(W[((size_t)(l*3+rel)*272 + row0 + k)*H + c]);
    if (k == 0) Bias_p[l*1024 + r] = bias;
    return;
  }
  t -= PREP_WP_N;
  if (t < PREP_WL_N){
    int k = t & 127; int idx = t >> 7;
    int rs = idx & 511; int l = idx >> 9;
    int r = unperm64(rs);
    int rel, c, row0; const float* W; float bias = 0.f;
    if (r < 256)      { rel=1; c=r>>1;   row0=128; W = (r&1)?Ws:Wf; }
    else if (r < 384) { rel=2; c=r-256; row0=0; W=Wf; bias = bfv[(l*3+rel)*H+c]; }
    else              { rel=2; c=r-384; row0=0; W=Ws; bias = bsv[(l*3+rel)*H+c]; }
    Wt_l[t] = f2bf(W[((size_t)(l*3+rel)*272 + row0 + k)*H + c]);
    if (k == 0) Bias_l[l*512 + r] = bias;
    return;
  }
  t -= PREP_WL_N;
  if (t < RBF_N){
    int c = t & 127;
    int b = (t >> 7) % (NBIN+1);
    int pr = t / ((NBIN+1)*128);
    float d0 = (float)b * (8.0f/(float)NBIN);
    const float* wf = Wf + ((size_t)pr*272 + 256)*H + c;
    const float* ws = Ws + ((size_t)pr*272 + 256)*H + c;
    float f0=0.f, s0=0.f;
    #pragma unroll
    for (int k=0;k<16;k++){
      float o = 0.533333333f*(float)k;
      float tt = d0 - o;
      float r0 = __expf(-1.7578125f*tt*tt);
      f0 += r0*wf[(size_t)k*H]; s0 += r0*ws[(size_t)k*H];
    }
    bf16* o = T2 + ((size_t)(pr*(NBIN+1) + b))*256 + 2*c;
    o[0]=f2bf(f0); o[1]=f2bf(s0);
    return;
  }
  t -= RBF_N;
  { // embeddings
    int idx = t;
    const float* Xin; const float* W; const float* b; float* Xout; bf16* Xbf;
    if (idx < NP*H){ Xin=Xp; W=Wp; b=bp; Xout=Xpo; Xbf=Xpb; }
    else { idx -= NP*H; if (idx >= NL*H) return; Xin=Xl; W=Wl; b=bl; Xout=Xlo; Xbf=Xlb; }
    int n = idx >> 7, c = idx & 127;
    float acc = b[c];
    #pragma unroll
    for (int k=0;k<6;k++) acc += Xin[n*6+k] * W[k*H+c];
    Xout[idx] = acc;
    Xbf[idx] = f2bf(acc);
  }
}

// ---------------------------------------------------------------------------
// CSR build: hist -> chunk sums -> mid scan -> final scan -> fill
// ---------------------------------------------------------------------------
__global__ void hist3_k(const int* __restrict__ dpp, int Epp,
                        const int* __restrict__ dlp, int Elp,
                        const int* __restrict__ dpl, int Epl,
                        int* __restrict__ cpp, int* __restrict__ clp, int* __restrict__ cpl){
  int e = blockIdx.x*blockDim.x + threadIdx.x;
  if (e < Epp) atomicAdd(&cpp[dpp[e]], 1);
  else if (e < Epp+Elp) atomicAdd(&clp[dlp[e-Epp]], 1);
  else if (e < Epp+Elp+Epl) atomicAdd(&cpl[dpl[e-Epp-Elp]], 1);
}

#define SCH 1024   // scan chunk size

__global__ void __launch_bounds__(256) chunksum_k(
    const int* __restrict__ counts, int NP, int NL, int Cpp, int Cpl,
    int* __restrict__ chsum){
  __shared__ int wred[4];
  int b = blockIdx.x;
  const int* cnt; int n; int ch;
  if (b < Cpp){ cnt = counts; n = NP; ch = b; }
  else if (b < 2*Cpp){ cnt = counts + NP; n = NP; ch = b - Cpp; }
  else { cnt = counts + 2*NP; n = NL; ch = b - 2*Cpp; }
  int base = ch * SCH;
  int tid = threadIdx.x;
  int s = 0;
  #pragma unroll
  for (int j=0;j<SCH/256;j++){
    int i = base + tid + j*256;
    if (i < n) s += cnt[i];
  }
  #pragma unroll
  for (int o=32;o>=1;o>>=1) s += __shfl_xor(s,o,64);
  if ((tid & 63) == 0) wred[tid>>6] = s;
  __syncthreads();
  if (tid == 0) chsum[b] = wred[0]+wred[1]+wred[2]+wred[3];
}

__global__ void __launch_bounds__(192) scanmid_k(
    int* __restrict__ chsum, int Cpp, int Cpl, int NP, int NL,
    int* __restrict__ rp_pp, int* __restrict__ rp_lp, int* __restrict__ rp_pl){
  int wid = threadIdx.x >> 6, lane = threadIdx.x & 63;
  int C, off; int* rp_end; int n;
  if (wid == 0){ C = Cpp; off = 0;      rp_end = rp_pp; n = NP; }
  else if (wid == 1){ C = Cpp; off = Cpp; rp_end = rp_lp; n = NP; }
  else { C = Cpl; off = 2*Cpp; rp_end = rp_pl; n = NL; }
  int v = (lane < C) ? chsum[off + lane] : 0;
  int x = v;
  #pragma unroll
  for (int o=1;o<64;o<<=1){
    int y = __shfl_up(x, o, 64);
    if (lane >= o) x += y;
  }
  if (lane < C) chsum[off + lane] = x - v;
  if (lane == 63) rp_end[n] = x;
}

__global__ void __launch_bounds__(1024) scanfin_k(
    const int* __restrict__ counts, int NP, int NL, int Cpp, int Cpl,
    const int* __restrict__ chsum,
    int* __restrict__ rp_pp, int* __restrict__ cur_pp,
    int* __restrict__ rp_lp, int* __restrict__ cur_lp,
    int* __restrict__ rp_pl, int* __restrict__ cur_pl){
  __shared__ int wsum[16];
  int b = blockIdx.x;
  const int* cnt; int n, ch; int* rp; int* cur;
  if (b < Cpp){ cnt = counts; n = NP; ch = b; rp = rp_pp; cur = cur_pp; }
  else if (b < 2*Cpp){ cnt = counts + NP; n = NP; ch = b - Cpp; rp = rp_lp; cur = cur_lp; }
  else { cnt = counts + 2*NP; n = NL; ch = b - 2*Cpp; rp = rp_pl; cur = cur_pl; }
  int tid = threadIdx.x, lane = tid & 63, wid = tid >> 6;
  int i = ch*SCH + tid;
  int v = (i < n) ? cnt[i] : 0;
  int x = v;
  #pragma unroll
  for (int o=1;o<64;o<<=1){
    int y = __shfl_up(x, o, 64);
    if (lane >= o) x += y;
  }
  if (lane == 63) wsum[wid] = x;
  __syncthreads();
  if (wid == 0 && lane < 16){
    int w = wsum[lane];
    #pragma unroll
    for (int o=1;o<16;o<<=1){
      int y = __shfl_up(w, o, 64);
      if (lane >= o) w += y;
    }
    wsum[lane] = w;
  }
  __syncthreads();
  int waveoff = (wid == 0) ? 0 : wsum[wid-1];
  int ex = chsum[b] + waveoff + x - v;
  if (i < n){ rp[i] = ex; cur[i] = ex; }
}

// fill packed int2 {src, d_bits}
__global__ void fill3_k(const int* __restrict__ ei_pp, const float* __restrict__ ea_pp, int Epp,
                        const int* __restrict__ ei_lp, const float* __restrict__ ea_lp, int Elp,
                        const int* __restrict__ ei_pl, const float* __restrict__ ea_pl, int Epl,
                        int* __restrict__ cur_pp, int2* __restrict__ e2_pp,
                        int* __restrict__ cur_lp, int2* __restrict__ e2_lp,
                        int* __restrict__ cur_pl, int2* __restrict__ e2_pl){
  int e = blockIdx.x*blockDim.x + threadIdx.x;
  if (e < Epp){
    int p = atomicAdd(&cur_pp[ei_pp[Epp + e]], 1);
    e2_pp[p] = make_int2(ei_pp[e], __float_as_int(ea_pp[e]));
  } else if (e < Epp+Elp){
    int i = e - Epp;
    int p = atomicAdd(&cur_lp[ei_lp[Elp + i]], 1);
    e2_lp[p] = make_int2(ei_lp[i], __float_as_int(ea_lp[i]));
  } else if (e < Epp+Elp+Epl){
    int i = e - Epp - Elp;
    int p = atomicAdd(&cur_pl[ei_pl[Epl + i]], 1);
    e2_pl[p] = make_int2(ei_pl[i], __float_as_int(ea_pl[i]));
  }
}

// ---------------------------------------------------------------------------
// Table GEMM v4 (B-resident): wave owns one 64-col group, iterates row strips.
// ---------------------------------------------------------------------------
#define GR 8
__global__ void __launch_bounds__(256) gemm_tables(
    const bf16* __restrict__ Xp, const bf16* __restrict__ Wtp,
    const float* __restrict__ Biasp, bf16* __restrict__ Outp,
    int strips_p, int tasks_p,
    const bf16* __restrict__ Xl, const bf16* __restrict__ Wtl,
    const float* __restrict__ Biasl, bf16* __restrict__ Outl,
    int strips_l, int tasks_total){
  int wt = blockIdx.x*4 + (threadIdx.x >> 6);
  if (wt >= tasks_total) return;
  const bf16 *X, *Wt; const float* Bias; bf16* Out; int N, strips, g, chunk;
  if (wt < tasks_p){
    X=Xp; Wt=Wtp; Bias=Biasp; Out=Outp; N=1024; strips=strips_p;
    g = wt & 15; chunk = wt >> 4;
  } else {
    int w = wt - tasks_p;
    X=Xl; Wt=Wtl; Bias=Biasl; Out=Outl; N=512; strips=strips_l;
    g = w & 7; chunk = w >> 3;
  }
  int n0 = g << 6;
  int lane = threadIdx.x & 63;
  int lr = lane & 15, lq = lane >> 4;
  const bf16x8* B0 = (const bf16x8*)(const void*)(Wt + (size_t)(n0      + lr)*H);
  const bf16x8* B1 = (const bf16x8*)(const void*)(Wt + (size_t)(n0 + 16 + lr)*H);
  const bf16x8* B2 = (const bf16x8*)(const void*)(Wt + (size_t)(n0 + 32 + lr)*H);
  const bf16x8* B3 = (const bf16x8*)(const void*)(Wt + (size_t)(n0 + 48 + lr)*H);
  bf16x8 b0_0=B0[lq], b0_1=B0[4+lq], b0_2=B0[8+lq], b0_3=B0[12+lq];
  bf16x8 b1_0=B1[lq], b1_1=B1[4+lq], b1_2=B1[8+lq], b1_3=B1[12+lq];
  bf16x8 b2_0=B2[lq], b2_1=B2[4+lq], b2_2=B2[8+lq], b2_3=B2[12+lq];
  bf16x8 b3_0=B3[lq], b3_1=B3[4+lq], b3_2=B3[8+lq], b3_3=B3[12+lq];
  float4 bias = ((const float4*)(const void*)(Bias + n0))[lr];
  #pragma unroll 2
  for (int r=0;r<GR;r++){
    int strip = chunk*GR + r;
    if (strip >= strips) break;
    int m0 = strip << 4;
    const bf16x8* A = (const bf16x8*)(const void*)(X + (size_t)(m0+lr)*H);
    bf16x8 a0 = A[lq], a1 = A[4+lq], a2 = A[8+lq], a3 = A[12+lq];
    f32x4 acc0 = {0.f,0.f,0.f,0.f}, acc1 = acc0, acc2 = acc0, acc3 = acc0;
    acc0 = __builtin_amdgcn_mfma_f32_16x16x32_bf16(a0, b0_0, acc0, 0, 0, 0);
    acc1 = __builtin_amdgcn_mfma_f32_16x16x32_bf16(a0, b1_0, acc1, 0, 0, 0);
    acc2 = __builtin_amdgcn_mfma_f32_16x16x32_bf16(a0, b2_0, acc2, 0, 0, 0);
    acc3 = __builtin_amdgcn_mfma_f32_16x16x32_bf16(a0, b3_0, acc3, 0, 0, 0);
    acc0 = __builtin_amdgcn_mfma_f32_16x16x32_bf16(a1, b0_1, acc0, 0, 0, 0);
    acc1 = __builtin_amdgcn_mfma_f32_16x16x32_bf16(a1, b1_1, acc1, 0, 0, 0);
    acc2 = __builtin_amdgcn_mfma_f32_16x16x32_bf16(a1, b2_1, acc2, 0, 0, 0);
    acc3 = __builtin_amdgcn_mfma_f32_16x16x32_bf16(a1, b3_1, acc3, 0, 0, 0);
    acc0 = __builtin_amdgcn_mfma_f32_16x16x32_bf16(a2, b0_2, acc0, 0, 0, 0);
    acc1 = __builtin_amdgcn_mfma_f32_16x16x32_bf16(a2, b1_2, acc1, 0, 0, 0);
    acc2 = __builtin_amdgcn_mfma_f32_16x16x32_bf16(a2, b2_2, acc2, 0, 0, 0);
    acc3 = __builtin_amdgcn_mfma_f32_16x16x32_bf16(a2, b3_2, acc3, 0, 0, 0);
    acc0 = __builtin_amdgcn_mfma_f32_16x16x32_bf16(a3, b0_3, acc0, 0, 0, 0);
    acc1 = __builtin_amdgcn_mfma_f32_16x16x32_bf16(a3, b1_3, acc1, 0, 0, 0);
    acc2 = __builtin_amdgcn_mfma_f32_16x16x32_bf16(a3, b2_3, acc2, 0, 0, 0);
    acc3 = __builtin_amdgcn_mfma_f32_16x16x32_bf16(a3, b3_3, acc3, 0, 0, 0);
    #pragma unroll
    for (int rr=0;rr<4;rr++){
      int row = m0 + lq*4 + rr;
      uint2 pk;
      pk.x = pack_bf2(acc0[rr] + bias.x, acc1[rr] + bias.y);
      pk.y = pack_bf2(acc2[rr] + bias.z, acc3[rr] + bias.w);
      *(uint2*)(void*)(Out + (size_t)row*N + n0 + 4*lr) = pk;
    }
  }
}

// ---------------------------------------------------------------------------
// Node-update helpers
// ---------------------------------------------------------------------------
static __device__ __forceinline__ float act_msg(float f, float s){
  float sig = __builtin_amdgcn_rcpf(1.f + __builtin_amdgcn_exp2f(f * -1.44269504f));
  float e   = __builtin_amdgcn_exp2f(fminf(s, 60.f) * 1.44269504f);
  float sp  = 0.69314718f * __builtin_amdgcn_logf(1.f + e);
  return sig * sp;
}

#define BN_RSQ 0.9999950000374997f   /* 1/sqrt(1+1e-5) */

static __device__ __forceinline__ void edge_nb(uint2 g, uint2 t,
                                               f32x2 fd2, f32x2 sd2, f32x2& acc){
  f32x2 f2, s2;
  f2.x = u2f_lo(g.x) + u2f_lo(t.x);
  f2.y = u2f_lo(g.y) + u2f_lo(t.y);
  s2.x = u2f_hi(g.x) + u2f_hi(t.x);
  s2.y = u2f_hi(g.y) + u2f_hi(t.y);
  f2 += fd2; s2 += sd2;
  acc.x += act_msg(f2.x, s2.x);
  acc.y += act_msg(f2.y, s2.y);
}

static __device__ __forceinline__ void ln_stats_w(float v0, float v1, float& mu, float& var){
  float s = v0 + v1, q = v0*v0 + v1*v1;
  #pragma unroll
  for (int o=32;o>=1;o>>=1){ s += __shfl_xor(s,o,64); q += __shfl_xor(q,o,64); }
  mu = s * (1.f/128.f);
  var = q * (1.f/128.f) - mu*mu;
}

// CSR aggregation: 64-edge chunk of {src,bin} in registers; per edge
// 2 readlane (SALU) + 2 gathers. Rotation-free 3-stage modulo schedule.
static __device__ __forceinline__ void aggregate(
    const int2* __restrict__ ev_arr, int e0, int e1,
    const uint2* __restrict__ G, int gstride, int goff,
    const uint2* __restrict__ Tb, int lane,
    f32x2 fd2, f32x2 sd2, f32x2& acc)
{
  for (int base = e0; base < e1; base += 64){
    int idx = base + lane;
    int2 ev = ev_arr[(idx < e1) ? idx : (e1-1)];
    float dd = __int_as_float(ev.y);
    int bnv = (int)__fmaf_rn(dd, (float)NBIN/8.0f, 0.5f);
    bnv = (bnv > NBIN) ? NBIN : bnv;
    int cnt = e1 - base; cnt = (cnt > 64) ? 64 : cnt;
    uint2 gA, tA, gB, tB, gC, tC;
    #define LDJ(gX, tX, j) { \
      int s_ = __builtin_amdgcn_readlane(ev.x, (j)); \
      int b_ = __builtin_amdgcn_readlane(bnv, (j)); \
      gX = G[(size_t)s_*gstride + goff + lane]; \
      tX = Tb[(size_t)b_*64 + lane]; }
    LDJ(gA, tA, 0);
    if (cnt > 1) LDJ(gB, tB, 1);
    if (cnt > 2) LDJ(gC, tC, 2);
    int j = 0;
    for (; j+5 < cnt; j += 3){
      edge_nb(gA, tA, fd2, sd2, acc); LDJ(gA, tA, j+3);
      edge_nb(gB, tB, fd2, sd2, acc); LDJ(gB, tB, j+4);
      edge_nb(gC, tC, fd2, sd2, acc); LDJ(gC, tC, j+5);
    }
    int rem = cnt - j;              // 1..5
    edge_nb(gA, tA, fd2, sd2, acc);
    if (rem > 3) LDJ(gA, tA, j+3);
    if (rem > 1) edge_nb(gB, tB, fd2, sd2, acc);
    if (rem > 4) LDJ(gB, tB, j+4);
    if (rem > 2) edge_nb(gC, tC, fd2, sd2, acc);
    if (rem > 3) edge_nb(gA, tA, fd2, sd2, acc);
    if (rem > 4) edge_nb(gB, tB, fd2, sd2, acc);
    #undef LDJ
  }
}

// ---------------------------------------------------------------------------
// Merged node update: wave per node. Blocks [0,PB) protein, rest ligand.
// ---------------------------------------------------------------------------
__global__ void __launch_bounds__(256) node_update(
    const bf16* __restrict__ PT, const bf16* __restrict__ LT,
    const float* __restrict__ xp, const float* __restrict__ xl,
    const int* __restrict__ pp_rp, const int2* __restrict__ pp_e2,
    const int* __restrict__ lp_rp, const int2* __restrict__ lp_e2,
    const int* __restrict__ pl_rp, const int2* __restrict__ pl_e2,
    const bf16* __restrict__ T2,
    const float* __restrict__ bn_w, const float* __restrict__ bn_b,
    const float* __restrict__ ln_w, const float* __restrict__ ln_b,
    float* __restrict__ xp_out, bf16* __restrict__ xp_bf,
    float* __restrict__ xl_out, bf16* __restrict__ xl_bf,
    int layer, int NP, int NL, int PB)
{
  int wave = threadIdx.x >> 6;
  int lane = threadIdx.x & 63;
  const uint2* PTg = (const uint2*)(const void*)PT;
  if ((int)blockIdx.x < PB){
    int node = blockIdx.x*4 + wave;
    if (node >= NP) return;
    float2 x = ((const float2*)(const void*)(xp + (size_t)node*H))[lane];
    const uint32* PTu = (const uint32*)(const void*)PT;
    const uint2*  LTg = (const uint2*)(const void*)LT;
    float o1_0, o1_1, o2_0, o2_1;
    { // relation pp
      int pr = layer*3 + 0;
      uint32 fdp = PTu[(size_t)node*512 + 256 + lane];
      uint32 sdp = PTu[(size_t)node*512 + 320 + lane];
      const uint2* Tb = (const uint2*)(const void*)(T2 + (size_t)pr*(NBIN+1)*256);
      f32x2 fd2 = {u2f_lo(fdp), u2f_hi(fdp)};
      f32x2 sd2 = {u2f_lo(sdp), u2f_hi(sdp)};
      f32x2 acc = {0.f, 0.f};
      aggregate(pp_e2, pp_rp[node], pp_rp[node+1], PTg, 256, 0, Tb, lane, fd2, sd2, acc);
      float2 bw = ((const float2*)(const void*)(bn_w + pr*H))[lane];
      float2 bb = ((const float2*)(const void*)(bn_b + pr*H))[lane];
      float2 lw = ((const float2*)(const void*)(ln_w + pr*H))[lane];
      float2 lb = ((const float2*)(const void*)(ln_b + pr*H))[lane];
      float v0 = acc.x * (bw.x * BN_RSQ) + bb.x + x.x;
      float v1 = acc.y * (bw.y * BN_RSQ) + bb.y + x.y;
      float mu, var; ln_stats_w(v0, v1, mu, var);
      float rs = rsqrtf(var + 1e-5f);
      o1_0 = fmaxf((v0-mu)*rs*lw.x + lb.x, 0.f) + x.x;
      o1_1 = fmaxf((v1-mu)*rs*lw.y + lb.y, 0.f) + x.y;
    }
    { // relation lp
      int pr = layer*3 + 1;
      uint32 fdp = PTu[(size_t)node*512 + 384 + lane];
      uint32 sdp = PTu[(size_t)node*512 + 448 + lane];
      const uint2* Tb = (const uint2*)(const void*)(T2 + (size_t)pr*(NBIN+1)*256);
      f32x2 fd2 = {u2f_lo(fdp), u2f_hi(fdp)};
      f32x2 sd2 = {u2f_lo(sdp), u2f_hi(sdp)};
      f32x2 acc = {0.f, 0.f};
      aggregate(lp_e2, lp_rp[node], lp_rp[node+1], LTg, 128, 0, Tb, lane, fd2, sd2, acc);
      float2 bw = ((const float2*)(const void*)(bn_w + pr*H))[lane];
      float2 bb = ((const float2*)(const void*)(bn_b + pr*H))[lane];
      float2 lw = ((const float2*)(const void*)(ln_w + pr*H))[lane];
      float2 lb = ((const float2*)(const void*)(ln_b + pr*H))[lane];
      float v0 = acc.x * (bw.x * BN_RSQ) + bb.x + x.x;
      float v1 = acc.y * (bw.y * BN_RSQ) + bb.y + x.y;
      float mu, var; ln_stats_w(v0, v1, mu, var);
      float rs = rsqrtf(var + 1e-5f);
      o2_0 = fmaxf((v0-mu)*rs*lw.x + lb.x, 0.f) + x.x;
      o2_1 = fmaxf((v1-mu)*rs*lw.y + lb.y, 0.f) + x.y;
    }
    float out0 = o1_0 + o2_0, out1 = o1_1 + o2_1;
    ((float2*)(void*)(xp_out + (size_t)node*H))[lane] = make_float2(out0, out1);
    ((uint32*)(void*)(xp_bf + (size_t)node*H))[lane] = pack_bf2(out0, out1);
  } else {
    int node = (blockIdx.x - PB)*4 + wave;
    if (node >= NL) return;
    float2 x = ((const float2*)(const void*)(xl + (size_t)node*H))[lane];
    const uint32* LTu = (const uint32*)(const void*)LT;
    int pr = layer*3 + 2;
    uint32 fdp = LTu[(size_t)node*256 + 128 + lane];
    uint32 sdp = LTu[(size_t)node*256 + 192 + lane];
    const uint2* Tb = (const uint2*)(const void*)(T2 + (size_t)pr*(NBIN+1)*256);
    f32x2 fd2 = {u2f_lo(fdp), u2f_hi(fdp)};
    f32x2 sd2 = {u2f_lo(sdp), u2f_hi(sdp)};
    f32x2 acc = {0.f, 0.f};
    aggregate(pl_e2, pl_rp[node], pl_rp[node+1], PTg, 256, 64, Tb, lane, fd2, sd2, acc);
    float2 bw = ((const float2*)(const void*)(bn_w + pr*H))[lane];
    float2 bb = ((const float2*)(const void*)(bn_b + pr*H))[lane];
    float2 lw = ((const float2*)(const void*)(ln_w + pr*H))[lane];
    float2 lb = ((const float2*)(const void*)(ln_b + pr*H))[lane];
    float v0 = acc.x * (bw.x * BN_RSQ) + bb.x + x.x;
    float v1 = acc.y * (bw.y * BN_RSQ) + bb.y + x.y;
    float mu, var; ln_stats_w(v0, v1, mu, var);
    float rs = rsqrtf(var + 1e-5f);
    float out0 = fmaxf((v0-mu)*rs*lw.x + lb.x, 0.f) + x.x;
    float out1 = fmaxf((v1-mu)*rs*lw.y + lb.y, 0.f) + x.y;
    ((float2*)(void*)(xl_out + (size_t)node*H))[lane] = make_float2(out0, out1);
    ((uint32*)(void*)(xl_bf + (size_t)node*H))[lane] = pack_bf2(out0, out1);
  }
}

// ---------------------------------------------------------------------------
// Final: LN(xp) @ fc_w[128,21] + fc_b
// ---------------------------------------------------------------------------
__global__ void __launch_bounds__(128) final_k(const float* __restrict__ xp,
    const float* __restrict__ lnw, const float* __restrict__ lnb,
    const float* __restrict__ fcw, const float* __restrict__ fcb,
    float* __restrict__ out, int N){
  __shared__ float sm[4];
  __shared__ float lnv[128];
  int node = blockIdx.x, c = threadIdx.x;
  float v = xp[(size_t)node*H + c];
  float s = v, q = v*v;
  #pragma unroll
  for (int o=32;o>=1;o>>=1){ s += __shfl_xor(s,o,64); q += __shfl_xor(q,o,64); }
  __syncthreads();
  if ((c & 63) == 0){ sm[(c>>6)*2] = s; sm[(c>>6)*2+1] = q; }
  __syncthreads();
  float S = sm[0] + sm[2], Q = sm[1] + sm[3];
  float mu = S * (1.f/128.f);
  float var = Q * (1.f/128.f) - mu*mu;
  float ln = (v-mu)*rsqrtf(var+1e-5f)*lnw[c] + lnb[c];
  lnv[c] = ln;
  __syncthreads();
  if (c < 21){
    float a = fcb[c];
    #pragma unroll 4
    for (int i=0;i<128;i++) a += lnv[i]*fcw[i*21+c];
    out[(size_t)node*21 + c] = a;
  }
}

// ---------------------------------------------------------------------------
extern "C" void kernel_launch(void* const* d_in, const int* in_sizes, int n_in,
                              void* d_out, int out_size, void* d_ws, size_t ws_size,
                              hipStream_t stream){
  const float* x_protein = (const float*)d_in[0];
  const float* x_ligand  = (const float*)d_in[1];
  const int*   ei_pp = (const int*)d_in[2];
  const float* ea_pp = (const float*)d_in[3];
  const int*   ei_lp = (const int*)d_in[4];
  const float* ea_lp = (const float*)d_in[5];
  const int*   ei_pl = (const int*)d_in[6];
  const float* ea_pl = (const float*)d_in[7];
  const float* Wp  = (const float*)d_in[8];
  const float* bp  = (const float*)d_in[9];
  const float* Wl  = (const float*)d_in[10];
  const float* bl  = (const float*)d_in[11];
  const float* Wf  = (const float*)d_in[12];
  const float* bfv = (const float*)d_in[13];
  const float* Wsv = (const float*)d_in[14];
  const float* bsv = (const float*)d_in[15];
  const float* bn_w = (const float*)d_in[16];
  const float* bn_b = (const float*)d_in[17];
  const float* ln_w = (const float*)d_in[18];
  const float* ln_b = (const float*)d_in[19];
  const float* lno_w = (const float*)d_in[20];
  const float* lno_b = (const float*)d_in[21];
  const float* fc_w = (const float*)d_in[22];
  const float* fc_b = (const float*)d_in[23];

  int NP  = in_sizes[0]/6, NL = in_sizes[1]/6;
  int EPP = in_sizes[3], ELP = in_sizes[5], EPL = in_sizes[7];

  char* ws = (char*)d_ws;
  size_t off = 0;
  auto alloc = [&](size_t bytes)->void*{
    void* p = ws + off; off = (off + bytes + 255) & ~(size_t)255; return p;
  };

  float* xpA = (float*)alloc((size_t)NP*H*4);
  float* xpB = (float*)alloc((size_t)NP*H*4);
  float* xlA = (float*)alloc((size_t)NL*H*4);
  float* xlB = (float*)alloc((size_t)NL*H*4);
  bf16* xp_bf = (bf16*)alloc((size_t)NP*H*2);
  bf16* xl_bf = (bf16*)alloc((size_t)NL*H*2);
  bf16* PT    = (bf16*)alloc((size_t)NP*1024*2);
  bf16* LT    = (bf16*)alloc((size_t)NL*512*2);
  bf16* Wt_p  = (bf16*)alloc((size_t)4*1024*H*2);
  bf16* Wt_l  = (bf16*)alloc((size_t)4*512*H*2);
  float* Bias_p = (float*)alloc((size_t)4*1024*4);
  float* Bias_l = (float*)alloc((size_t)4*512*4);
  bf16* T2    = (bf16*)alloc((size_t)12*(NBIN+1)*256*2);
  int* counts = (int*)alloc((size_t)(2*NP+NL)*4);
  int* rp_pp  = (int*)alloc((size_t)(NP+1)*4);
  int* cur_pp = (int*)alloc((size_t)NP*4);
  int* rp_lp  = (int*)alloc((size_t)(NP+1)*4);
  int* cur_lp = (int*)alloc((size_t)NP*4);
  int* rp_pl  = (int*)alloc((size_t)(NL+1)*4);
  int* cur_pl = (int*)alloc((size_t)NL*4);
  int2* e2_pp = (int2*)alloc((size_t)EPP*8);
  int2* e2_lp = (int2*)alloc((size_t)ELP*8);
  int2* e2_pl = (int2*)alloc((size_t)EPL*8);
  int Cpp = (NP + SCH - 1) / SCH;
  int Cpl = (NL + SCH - 1) / SCH;
  int* chsum = (int*)alloc((size_t)(2*Cpp + Cpl)*4);
  (void)ws_size; (void)n_in; (void)out_size;

  // --- prep (weights + RBF table + embeddings, one launch) ---
  size_t prep_total = (size_t)PREP_WP_N + PREP_WL_N + RBF_N + (size_t)(NP+NL)*H;
  prep_all<<<(prep_total+255)/256, 256, 0, stream>>>(Wf, Wsv, bfv, bsv,
      Wt_p, Bias_p, Wt_l, Bias_l, T2,
      x_protein, Wp, bp, xpA, xp_bf, NP,
      x_ligand,  Wl, bl, xlA, xl_bf, NL);
  // --- CSR build ---
  hipMemsetAsync(counts, 0, (size_t)(2*NP+NL)*4, stream);
  int* cnt_pp = counts; int* cnt_lp = counts + NP; int* cnt_pl = counts + 2*NP;
  int Etot = EPP + ELP + EPL;
  hist3_k<<<(Etot+255)/256, 256, 0, stream>>>(ei_pp+EPP, EPP, ei_lp+ELP, ELP, ei_pl+EPL, EPL,
                                              cnt_pp, cnt_lp, cnt_pl);
  chunksum_k<<<2*Cpp + Cpl, 256, 0, stream>>>(counts, NP, NL, Cpp, Cpl, chsum);
  scanmid_k<<<1, 192, 0, stream>>>(chsum, Cpp, Cpl, NP, NL, rp_pp, rp_lp, rp_pl);
  scanfin_k<<<2*Cpp + Cpl, 1024, 0, stream>>>(counts, NP, NL, Cpp, Cpl, chsum,
                                              rp_pp, cur_pp, rp_lp, cur_lp, rp_pl, cur_pl);
  fill3_k<<<(Etot+255)/256, 256, 0, stream>>>(ei_pp, ea_pp, EPP, ei_lp, ea_lp, ELP,
                                              ei_pl, ea_pl, EPL,
                                              cur_pp, e2_pp, cur_lp, e2_lp, cur_pl, e2_pl);

  // --- layers ---
  float* xp_cur = xpA; float* xp_nxt = xpB;
  float* xl_cur = xlA; float* xl_nxt = xlB;
  int strips_p = NP >> 4, strips_l = NL >> 4;
  int tasks_p = 16 * ((strips_p + GR - 1) / GR);
  int tasks_l = 8  * ((strips_l + GR - 1) / GR);
  int tasks_total = tasks_p + tasks_l;
  int PB = (NP + 3) / 4, LB = (NL + 3) / 4;
  for (int l=0; l<4; l++){
    gemm_tables<<<(tasks_total+3)/4, 256, 0, stream>>>(
        xp_bf, Wt_p + (size_t)l*1024*H, Bias_p + l*1024, PT, strips_p, tasks_p,
        xl_bf, Wt_l + (size_t)l*512*H,  Bias_l + l*512,  LT, strips_l, tasks_total);
    node_update<<<PB + LB, 256, 0, stream>>>(PT, LT, xp_cur, xl_cur,
        rp_pp, e2_pp, rp_lp, e2_lp, rp_pl, e2_pl, T2,
        bn_w, bn_b, ln_w, ln_b, xp_nxt, xp_bf, xl_nxt, xl_bf, l, NP, NL, PB);
    float* t;
    t = xp_cur; xp_cur = xp_nxt; xp_nxt = t;
    t = xl_cur; xl_cur = xl_nxt; xl_nxt = t;
  }

  // --- output head ---
  final_k<<<NP, 128, 0, stream>>>(xp_cur, lno_w, lno_b, fc_w, fc_b, (float*)d_out, NP);
}